// Round 2
// baseline (730.379 us; speedup 1.0000x reference)
//
#include <hip/hip_runtime.h>
#include <math.h>

// ---- problem constants ----
static const int kN     = 16384;    // nodes
static const int kEdges = 262144;
static const int kD     = 256;      // d_model (= D_IN)
static const int kH     = 512;      // d_inner
static const int kE     = 64;       // experts
static const int kCap   = 1024;
static const int kPairs = kN * 2;   // top-2

// ---- workspace layout (bytes) ----
// zeroed region first (one memset)
static const size_t OFF_DEGO    = 0;                        // int[16384]
static const size_t OFF_DEGI    = OFF_DEGO + 65536;         // int[16384]
static const size_t OFF_CURSOR  = OFF_DEGI + 65536;         // int[16384]
static const size_t OFF_ECOUNT  = OFF_CURSOR + 65536;       // int[64]
static const size_t OFF_ECUR    = OFF_ECOUNT + 256;         // int[64]
static const size_t OFF_COLSUM  = OFF_ECUR + 256;           // f32[256]
static const size_t OFF_COLSUM2 = OFF_COLSUM + 1024;        // f32[256]
static const size_t ZERO_BYTES  = OFF_COLSUM2 + 1024;       // = 199168
// non-zeroed scratch
static const size_t OFF_EOFFS   = ZERO_BYTES;               // int[65]
static const size_t OFF_CSROFF  = OFF_EOFFS + 512;          // int[16385]
static const size_t OFF_CSRSRC  = OFF_CSROFF + 65792;       // int[262144]
static const size_t OFF_PLIST   = OFF_CSRSRC + 1048576;     // int[32768]
static const size_t OFF_EIDX    = OFF_PLIST + 131072;       // int[32768]
static const size_t OFF_EGATE   = OFF_EIDX + 131072;        // f32[32768]
static const size_t OFF_SCALE   = OFF_EGATE + 131072;       // f32[256]
static const size_t OFF_SHIFT   = OFF_SCALE + 1024;         // f32[256]
static const size_t OFF_M       = OFF_SHIFT + 1024;         // f32[16384*256]  (reused as y)
static const size_t OFF_X       = OFF_M + 16777216;         // f32[16384*256]
static const size_t OFF_LOGITS  = OFF_X + 16777216;         // f32[16384*64]
static const size_t OFF_POUT    = OFF_LOGITS + 4194304;     // f32[32768*256]
static const size_t OFF_H1      = OFF_POUT + 33554432;      // f32[32768*512]
// total ~134 MB

__device__ __forceinline__ float gelu_f(float v) {
    return 0.5f * v * (1.0f + erff(v * 0.70710678118654752f));
}

// ---------- graph preprocessing ----------
__global__ __launch_bounds__(256) void k_count_deg(const int* __restrict__ src,
                                                   const int* __restrict__ dst,
                                                   int* __restrict__ dego,
                                                   int* __restrict__ degi) {
    int i = blockIdx.x * 256 + threadIdx.x;
    if (i < kEdges) {
        atomicAdd(&dego[src[i]], 1);
        atomicAdd(&degi[dst[i]], 1);
    }
}

__global__ __launch_bounds__(1024) void k_scan_nodes(const int* __restrict__ degi,
                                                     int* __restrict__ offs) {
    __shared__ int sums[1024];
    int t = threadIdx.x;
    int base = t * 16;
    int loc[16];
    int s = 0;
#pragma unroll
    for (int i = 0; i < 16; ++i) { loc[i] = degi[base + i]; s += loc[i]; }
    sums[t] = s;
    __syncthreads();
    for (int off = 1; off < 1024; off <<= 1) {
        int v = (t >= off) ? sums[t - off] : 0;
        __syncthreads();
        sums[t] += v;
        __syncthreads();
    }
    int run = sums[t] - s;  // exclusive prefix
#pragma unroll
    for (int i = 0; i < 16; ++i) { offs[base + i] = run; run += loc[i]; }
    if (t == 1023) offs[kN] = run;
}

__global__ __launch_bounds__(256) void k_build_csr(const int* __restrict__ src,
                                                   const int* __restrict__ dst,
                                                   const int* __restrict__ offs,
                                                   int* __restrict__ cursor,
                                                   int* __restrict__ csr_src) {
    int i = blockIdx.x * 256 + threadIdx.x;
    if (i < kEdges) {
        int d = dst[i];
        int pos = atomicAdd(&cursor[d], 1);
        csr_src[offs[d] + pos] = src[i];
    }
}

// m[n] = rsqrt(deg_in[n]) * sum_{e: dst=n} feats[src(e)] * rsqrt(deg_out[src(e)])
__global__ __launch_bounds__(256) void k_aggregate(const float* __restrict__ feats,
                                                   const int* __restrict__ dego,
                                                   const int* __restrict__ degi,
                                                   const int* __restrict__ offs,
                                                   const int* __restrict__ csr_src,
                                                   float* __restrict__ m) {
    int n = blockIdx.x;
    int d = threadIdx.x;
    int beg = offs[n], end = offs[n + 1];
    float acc = 0.f;
    for (int i = beg; i < end; ++i) {
        int s = csr_src[i];
        int dg = dego[s]; if (dg < 1) dg = 1;
        float sc = rsqrtf((float)dg);
        acc += feats[(size_t)s * kD + d] * sc;
    }
    int dgi = degi[n]; if (dgi < 1) dgi = 1;
    m[(size_t)n * kD + d] = acc * rsqrtf((float)dgi);
}

// ---------- tiled f32 GEMMs (BM=BN=64, BK=32, 4x4 per thread) ----------
#define FMA16()                                                                         \
    acc[0][0]=fmaf(a.x,b.x,acc[0][0]); acc[0][1]=fmaf(a.x,b.y,acc[0][1]);               \
    acc[0][2]=fmaf(a.x,b.z,acc[0][2]); acc[0][3]=fmaf(a.x,b.w,acc[0][3]);               \
    acc[1][0]=fmaf(a.y,b.x,acc[1][0]); acc[1][1]=fmaf(a.y,b.y,acc[1][1]);               \
    acc[1][2]=fmaf(a.y,b.z,acc[1][2]); acc[1][3]=fmaf(a.y,b.w,acc[1][3]);               \
    acc[2][0]=fmaf(a.z,b.x,acc[2][0]); acc[2][1]=fmaf(a.z,b.y,acc[2][1]);               \
    acc[2][2]=fmaf(a.z,b.z,acc[2][2]); acc[2][3]=fmaf(a.z,b.w,acc[2][3]);               \
    acc[3][0]=fmaf(a.w,b.x,acc[3][0]); acc[3][1]=fmaf(a.w,b.y,acc[3][1]);               \
    acc[3][2]=fmaf(a.w,b.z,acc[3][2]); acc[3][3]=fmaf(a.w,b.w,acc[3][3]);

// x = m @ W_gc + feats @ W_res + b_gc + b_res
__global__ __launch_bounds__(256) void k_xgemm(const float* __restrict__ m,
                                               const float* __restrict__ feats,
                                               const float* __restrict__ Wgc,
                                               const float* __restrict__ Wres,
                                               const float* __restrict__ bgc,
                                               const float* __restrict__ bres,
                                               float* __restrict__ x) {
    __shared__ float As[32][68];  // transposed: As[k][row]
    __shared__ float Bs[32][68];
    const int t = threadIdx.x;
    const int tx = t & 15, ty = t >> 4;
    const int m0 = blockIdx.y * 64;
    const int n0 = blockIdx.x * 64;
    float acc[4][4] = {};
    for (int pass = 0; pass < 2; ++pass) {
        const float* A = pass ? feats : m;
        const float* B = pass ? Wres : Wgc;
        for (int kb = 0; kb < kD; kb += 32) {
            __syncthreads();
#pragma unroll
            for (int i = 0; i < 2; ++i) {
                int fidx = i * 256 + t;
                int r = fidx >> 3, k4 = fidx & 7;
                float4 v = *(const float4*)(A + (size_t)(m0 + r) * kD + kb + k4 * 4);
                As[k4 * 4 + 0][r] = v.x; As[k4 * 4 + 1][r] = v.y;
                As[k4 * 4 + 2][r] = v.z; As[k4 * 4 + 3][r] = v.w;
            }
#pragma unroll
            for (int i = 0; i < 2; ++i) {
                int fidx = i * 256 + t;
                int kk = fidx >> 4, c4 = fidx & 15;
                float4 v = *(const float4*)(B + (size_t)(kb + kk) * kD + n0 + c4 * 4);
                *(float4*)&Bs[kk][c4 * 4] = v;
            }
            __syncthreads();
#pragma unroll
            for (int kk = 0; kk < 32; ++kk) {
                float4 a = *(const float4*)&As[kk][ty * 4];
                float4 b = *(const float4*)&Bs[kk][tx * 4];
                FMA16();
            }
        }
    }
    int col0 = n0 + tx * 4;
    float4 bb1 = *(const float4*)(bgc + col0);
    float4 bb2 = *(const float4*)(bres + col0);
#pragma unroll
    for (int i = 0; i < 4; ++i) {
        int row = m0 + ty * 4 + i;
        float4 o;
        o.x = acc[i][0] + bb1.x + bb2.x;
        o.y = acc[i][1] + bb1.y + bb2.y;
        o.z = acc[i][2] + bb1.z + bb2.z;
        o.w = acc[i][3] + bb1.w + bb2.w;
        *(float4*)(x + (size_t)row * kD + col0) = o;
    }
}

// logits = x @ Wg + bg   (N x 64, K=256)
__global__ __launch_bounds__(256) void k_gate(const float* __restrict__ x,
                                              const float* __restrict__ Wg,
                                              const float* __restrict__ bg,
                                              float* __restrict__ logits) {
    __shared__ float As[32][68];
    __shared__ float Bs[32][68];
    const int t = threadIdx.x;
    const int tx = t & 15, ty = t >> 4;
    const int m0 = blockIdx.y * 64;
    float acc[4][4] = {};
    for (int kb = 0; kb < kD; kb += 32) {
        __syncthreads();
#pragma unroll
        for (int i = 0; i < 2; ++i) {
            int fidx = i * 256 + t;
            int r = fidx >> 3, k4 = fidx & 7;
            float4 v = *(const float4*)(x + (size_t)(m0 + r) * kD + kb + k4 * 4);
            As[k4 * 4 + 0][r] = v.x; As[k4 * 4 + 1][r] = v.y;
            As[k4 * 4 + 2][r] = v.z; As[k4 * 4 + 3][r] = v.w;
        }
        // B tile is 32x64 = 2048 floats = 512 float4 -> 2 iterations of 256 threads
        // (round-1 bug: only 128 float4 were loaded -> experts 16..63 got garbage)
#pragma unroll
        for (int i = 0; i < 2; ++i) {
            int fidx = i * 256 + t;
            int kk = fidx >> 4, c4 = fidx & 15;
            float4 v = *(const float4*)(Wg + (size_t)(kb + kk) * kE + c4 * 4);
            *(float4*)&Bs[kk][c4 * 4] = v;
        }
        __syncthreads();
#pragma unroll
        for (int kk = 0; kk < 32; ++kk) {
            float4 a = *(const float4*)&As[kk][ty * 4];
            float4 b = *(const float4*)&Bs[kk][tx * 4];
            FMA16();
        }
    }
    int col0 = tx * 4;
    float4 bb = *(const float4*)(bg + col0);
#pragma unroll
    for (int i = 0; i < 4; ++i) {
        int row = m0 + ty * 4 + i;
        float4 o;
        o.x = acc[i][0] + bb.x; o.y = acc[i][1] + bb.y;
        o.z = acc[i][2] + bb.z; o.w = acc[i][3] + bb.w;
        *(float4*)(logits + (size_t)row * kE + col0) = o;
    }
}

// ---------- gating: top-2 + softmax + bucket ----------
__global__ __launch_bounds__(256) void k_topk(const float* __restrict__ logits,
                                              int* __restrict__ eidx,
                                              float* __restrict__ egate,
                                              int* __restrict__ ecount) {
    int n = blockIdx.x * 256 + threadIdx.x;
    if (n >= kN) return;
    const float* row = logits + (size_t)n * kE;
    float v0 = -3.4e38f, v1 = -3.4e38f;
    int i0 = 0, i1 = 0;
    for (int e = 0; e < kE; ++e) {
        float v = row[e];
        if (v > v0) { v1 = v0; i1 = i0; v0 = v; i0 = e; }
        else if (v > v1) { v1 = v; i1 = e; }
    }
    float ex = expf(v1 - v0);       // <= 1, stable
    float g0 = 1.0f / (1.0f + ex);
    float g1 = ex * g0;
    eidx[2 * n] = i0; eidx[2 * n + 1] = i1;
    egate[2 * n] = g0; egate[2 * n + 1] = g1;
    atomicAdd(&ecount[i0], 1);
    atomicAdd(&ecount[i1], 1);
}

__global__ void k_scan_experts(const int* __restrict__ ecount, int* __restrict__ eoffs) {
    if (threadIdx.x == 0) {
        int s = 0;
        for (int e = 0; e < kE; ++e) { eoffs[e] = s; s += ecount[e]; }
        eoffs[kE] = s;
    }
}

__global__ __launch_bounds__(256) void k_scatter(const int* __restrict__ eidx,
                                                 const int* __restrict__ eoffs,
                                                 int* __restrict__ ecur,
                                                 int* __restrict__ plist) {
    int p = blockIdx.x * 256 + threadIdx.x;
    if (p < kPairs) {
        int e = eidx[p];
        int pos = atomicAdd(&ecur[e], 1);
        plist[eoffs[e] + pos] = p;
    }
}

// ---------- MoE expert GEMMs ----------
// h1[slot] = gelu(x[tok] @ w1[e] + b1[e]);  grid (ntile=8, mtile=16, expert=64)
__global__ __launch_bounds__(256) void k_moe1(const float* __restrict__ x,
                                              const float* __restrict__ w1,
                                              const float* __restrict__ b1,
                                              const int* __restrict__ plist,
                                              const int* __restrict__ eoffs,
                                              const int* __restrict__ ecount,
                                              float* __restrict__ h1) {
    __shared__ float As[32][68];
    __shared__ float Bs[32][68];
    __shared__ int rowtok[64];
    const int e = blockIdx.z;
    int cnt = ecount[e]; if (cnt > kCap) cnt = kCap;
    const int m0 = blockIdx.y * 64;
    if (m0 >= cnt) return;
    const int n0 = blockIdx.x * 64;
    const int base = eoffs[e];
    const int t = threadIdx.x;
    if (t < 64) {
        int slot = m0 + t;
        rowtok[t] = (slot < cnt) ? (plist[base + slot] >> 1) : -1;
    }
    const int tx = t & 15, ty = t >> 4;
    const float* B = w1 + (size_t)e * kD * kH;
    float acc[4][4] = {};
    for (int kb = 0; kb < kD; kb += 32) {
        __syncthreads();
#pragma unroll
        for (int i = 0; i < 2; ++i) {
            int fidx = i * 256 + t;
            int r = fidx >> 3, k4 = fidx & 7;
            int tok = rowtok[r];
            float4 v = make_float4(0.f, 0.f, 0.f, 0.f);
            if (tok >= 0) v = *(const float4*)(x + (size_t)tok * kD + kb + k4 * 4);
            As[k4 * 4 + 0][r] = v.x; As[k4 * 4 + 1][r] = v.y;
            As[k4 * 4 + 2][r] = v.z; As[k4 * 4 + 3][r] = v.w;
        }
#pragma unroll
        for (int i = 0; i < 2; ++i) {
            int fidx = i * 256 + t;
            int kk = fidx >> 4, c4 = fidx & 15;
            float4 v = *(const float4*)(B + (size_t)(kb + kk) * kH + n0 + c4 * 4);
            *(float4*)&Bs[kk][c4 * 4] = v;
        }
        __syncthreads();
#pragma unroll
        for (int kk = 0; kk < 32; ++kk) {
            float4 a = *(const float4*)&As[kk][ty * 4];
            float4 b = *(const float4*)&Bs[kk][tx * 4];
            FMA16();
        }
    }
    int col0 = n0 + tx * 4;
    float4 bb = *(const float4*)(b1 + (size_t)e * kH + col0);
#pragma unroll
    for (int i = 0; i < 4; ++i) {
        int slot = m0 + ty * 4 + i;
        if (slot < cnt) {
            float4 o;
            o.x = gelu_f(acc[i][0] + bb.x);
            o.y = gelu_f(acc[i][1] + bb.y);
            o.z = gelu_f(acc[i][2] + bb.z);
            o.w = gelu_f(acc[i][3] + bb.w);
            *(float4*)(h1 + (size_t)(base + slot) * kH + col0) = o;
        }
    }
}

// pout[p] = gate[p] * (h1[slot] @ w2[e] + b2[e]);  grid (ntile=4, mtile=16, expert=64)
__global__ __launch_bounds__(256) void k_moe2(const float* __restrict__ h1,
                                              const float* __restrict__ w2,
                                              const float* __restrict__ b2,
                                              const int* __restrict__ plist,
                                              const int* __restrict__ eoffs,
                                              const int* __restrict__ ecount,
                                              const float* __restrict__ egate,
                                              float* __restrict__ pout) {
    __shared__ float As[32][68];
    __shared__ float Bs[32][68];
    __shared__ int prow[64];
    const int e = blockIdx.z;
    int cnt = ecount[e]; if (cnt > kCap) cnt = kCap;
    const int m0 = blockIdx.y * 64;
    if (m0 >= cnt) return;
    const int n0 = blockIdx.x * 64;
    const int base = eoffs[e];
    const int t = threadIdx.x;
    if (t < 64) {
        int slot = m0 + t;
        prow[t] = (slot < cnt) ? plist[base + slot] : -1;
    }
    const int tx = t & 15, ty = t >> 4;
    const float* B = w2 + (size_t)e * kH * kD;
    float acc[4][4] = {};
    for (int kb = 0; kb < kH; kb += 32) {
        __syncthreads();
#pragma unroll
        for (int i = 0; i < 2; ++i) {
            int fidx = i * 256 + t;
            int r = fidx >> 3, k4 = fidx & 7;
            float4 v = make_float4(0.f, 0.f, 0.f, 0.f);
            if (prow[r] >= 0)
                v = *(const float4*)(h1 + (size_t)(base + m0 + r) * kH + kb + k4 * 4);
            As[k4 * 4 + 0][r] = v.x; As[k4 * 4 + 1][r] = v.y;
            As[k4 * 4 + 2][r] = v.z; As[k4 * 4 + 3][r] = v.w;
        }
#pragma unroll
        for (int i = 0; i < 2; ++i) {
            int fidx = i * 256 + t;
            int kk = fidx >> 4, c4 = fidx & 15;
            float4 v = *(const float4*)(B + (size_t)(kb + kk) * kD + n0 + c4 * 4);
            *(float4*)&Bs[kk][c4 * 4] = v;
        }
        __syncthreads();
#pragma unroll
        for (int kk = 0; kk < 32; ++kk) {
            float4 a = *(const float4*)&As[kk][ty * 4];
            float4 b = *(const float4*)&Bs[kk][tx * 4];
            FMA16();
        }
    }
    int col0 = n0 + tx * 4;
    float4 bb = *(const float4*)(b2 + (size_t)e * kD + col0);
#pragma unroll
    for (int i = 0; i < 4; ++i) {
        int p = prow[ty * 4 + i];
        if (p >= 0) {
            float g = egate[p];
            float4 o;
            o.x = g * (acc[i][0] + bb.x);
            o.y = g * (acc[i][1] + bb.y);
            o.z = g * (acc[i][2] + bb.z);
            o.w = g * (acc[i][3] + bb.w);
            *(float4*)(pout + (size_t)p * kD + col0) = o;
        }
    }
}

// ---------- BN: y = x + core, column sums ----------
__global__ __launch_bounds__(256) void k_ybn(const float* __restrict__ x,
                                             const float* __restrict__ pout,
                                             float* __restrict__ y,
                                             float* __restrict__ colsum,
                                             float* __restrict__ colsum2) {
    int d = threadIdx.x;
    int r0 = blockIdx.x * 64;
    float s = 0.f, s2 = 0.f;
    for (int i = 0; i < 64; ++i) {
        int row = r0 + i;
        float v = x[(size_t)row * kD + d]
                + pout[(size_t)(2 * row) * kD + d]
                + pout[(size_t)(2 * row + 1) * kD + d];
        y[(size_t)row * kD + d] = v;
        s += v; s2 += v * v;
    }
    atomicAdd(&colsum[d], s);
    atomicAdd(&colsum2[d], s2);
}

__global__ void k_bnparams(const float* __restrict__ colsum,
                           const float* __restrict__ colsum2,
                           const float* __restrict__ gamma,
                           const float* __restrict__ beta,
                           float* __restrict__ scale,
                           float* __restrict__ shift) {
    int d = threadIdx.x;
    float mean = colsum[d] * (1.0f / kN);
    float var = colsum2[d] * (1.0f / kN) - mean * mean;
    float inv = rsqrtf(var + 1e-5f);
    float sc = inv * gamma[d];
    scale[d] = sc;
    shift[d] = beta[d] - mean * sc;
}

__global__ __launch_bounds__(256) void k_apply(const float* __restrict__ y,
                                               const float* __restrict__ scale,
                                               const float* __restrict__ shift,
                                               float* __restrict__ out) {
    int i = blockIdx.x * 256 + threadIdx.x;  // float4 index
    float4 v = ((const float4*)y)[i];
    int d = (i * 4) & (kD - 1);
    float4 sc = *(const float4*)(scale + d);
    float4 sh = *(const float4*)(shift + d);
    v.x = v.x * sc.x + sh.x;
    v.y = v.y * sc.y + sh.y;
    v.z = v.z * sc.z + sh.z;
    v.w = v.w * sc.w + sh.w;
    ((float4*)out)[i] = v;
}

extern "C" void kernel_launch(void* const* d_in, const int* in_sizes, int n_in,
                              void* d_out, int out_size, void* d_ws, size_t ws_size,
                              hipStream_t stream) {
    const float* feats = (const float*)d_in[0];
    const float* Wgc   = (const float*)d_in[1];
    const float* bgc   = (const float*)d_in[2];
    const float* Wres  = (const float*)d_in[3];
    const float* bres  = (const float*)d_in[4];
    const float* Wg    = (const float*)d_in[5];
    const float* bg    = (const float*)d_in[6];
    const float* w1    = (const float*)d_in[7];
    const float* b1    = (const float*)d_in[8];
    const float* w2    = (const float*)d_in[9];
    const float* b2    = (const float*)d_in[10];
    const float* gamma = (const float*)d_in[11];
    const float* beta  = (const float*)d_in[12];
    const int*   src   = (const int*)d_in[13];
    const int*   dst   = (const int*)d_in[14];

    char* ws = (char*)d_ws;
    int*   dego    = (int*)(ws + OFF_DEGO);
    int*   degi    = (int*)(ws + OFF_DEGI);
    int*   cursor  = (int*)(ws + OFF_CURSOR);
    int*   ecount  = (int*)(ws + OFF_ECOUNT);
    int*   ecur    = (int*)(ws + OFF_ECUR);
    float* colsum  = (float*)(ws + OFF_COLSUM);
    float* colsum2 = (float*)(ws + OFF_COLSUM2);
    int*   eoffs   = (int*)(ws + OFF_EOFFS);
    int*   csroff  = (int*)(ws + OFF_CSROFF);
    int*   csrsrc  = (int*)(ws + OFF_CSRSRC);
    int*   plist   = (int*)(ws + OFF_PLIST);
    int*   eidx    = (int*)(ws + OFF_EIDX);
    float* egate   = (float*)(ws + OFF_EGATE);
    float* scale   = (float*)(ws + OFF_SCALE);
    float* shift   = (float*)(ws + OFF_SHIFT);
    float* mbuf    = (float*)(ws + OFF_M);      // reused as y later
    float* xbuf    = (float*)(ws + OFF_X);
    float* logits  = (float*)(ws + OFF_LOGITS);
    float* pout    = (float*)(ws + OFF_POUT);
    float* h1      = (float*)(ws + OFF_H1);
    float* ybuf    = mbuf;

    hipMemsetAsync(ws, 0, ZERO_BYTES, stream);

    k_count_deg<<<kEdges / 256, 256, 0, stream>>>(src, dst, dego, degi);
    k_scan_nodes<<<1, 1024, 0, stream>>>(degi, csroff);
    k_build_csr<<<kEdges / 256, 256, 0, stream>>>(src, dst, csroff, cursor, csrsrc);
    k_aggregate<<<kN, 256, 0, stream>>>(feats, dego, degi, csroff, csrsrc, mbuf);
    k_xgemm<<<dim3(kD / 64, kN / 64), 256, 0, stream>>>(mbuf, feats, Wgc, Wres, bgc, bres, xbuf);
    k_gate<<<dim3(1, kN / 64), 256, 0, stream>>>(xbuf, Wg, bg, logits);
    k_topk<<<kN / 256, 256, 0, stream>>>(logits, eidx, egate, ecount);
    k_scan_experts<<<1, 64, 0, stream>>>(ecount, eoffs);
    k_scatter<<<kPairs / 256, 256, 0, stream>>>(eidx, eoffs, ecur, plist);
    k_moe1<<<dim3(kH / 64, kCap / 64, kE), 256, 0, stream>>>(xbuf, w1, b1, plist, eoffs, ecount, h1);
    k_moe2<<<dim3(kD / 64, kCap / 64, kE), 256, 0, stream>>>(h1, w2, b2, plist, eoffs, ecount, egate, pout);
    k_ybn<<<kN / 64, 256, 0, stream>>>(xbuf, pout, ybuf, colsum, colsum2);
    k_bnparams<<<1, 256, 0, stream>>>(colsum, colsum2, gamma, beta, scale, shift);
    k_apply<<<(kN * kD / 4) / 256, 256, 0, stream>>>(ybuf, scale, shift, (float*)d_out);
}

// Round 3
// 585.081 us; speedup vs baseline: 1.2483x; 1.2483x over previous
//
#include <hip/hip_runtime.h>
#include <math.h>

// ---- problem constants ----
static const int kN     = 16384;    // nodes
static const int kEdges = 262144;
static const int kD     = 256;      // d_model (= D_IN)
static const int kH     = 512;      // d_inner
static const int kE     = 64;       // experts
static const int kCap   = 1024;
static const int kPairs = kN * 2;   // top-2

// ---- workspace layout (bytes) ----
static const size_t OFF_DEGO    = 0;                        // int[16384]
static const size_t OFF_DEGI    = OFF_DEGO + 65536;
static const size_t OFF_CURSOR  = OFF_DEGI + 65536;
static const size_t OFF_ECOUNT  = OFF_CURSOR + 65536;       // int[64]
static const size_t OFF_ECUR    = OFF_ECOUNT + 256;
static const size_t OFF_COLSUM  = OFF_ECUR + 256;           // f32[256]
static const size_t OFF_COLSUM2 = OFF_COLSUM + 1024;
static const size_t ZERO_BYTES  = OFF_COLSUM2 + 1024;       // 199168
static const size_t OFF_EOFFS   = ZERO_BYTES;               // int[65]
static const size_t OFF_CSROFF  = OFF_EOFFS + 512;          // int[16385]
static const size_t OFF_CSRSRC  = OFF_CSROFF + 65792;       // int[262144]
static const size_t OFF_PLIST   = OFF_CSRSRC + 1048576;     // int[32768]
static const size_t OFF_EIDX    = OFF_PLIST + 131072;       // int[32768]
static const size_t OFF_EGATE   = OFF_EIDX + 131072;        // f32[32768]
static const size_t OFF_SCALE   = OFF_EGATE + 131072;       // f32[256]
static const size_t OFF_SHIFT   = OFF_SCALE + 1024;         // f32[256]
static const size_t OFF_M       = OFF_SHIFT + 1024;         // f32[16384*256]; xb (bf16) aliases; y aliases
static const size_t OFF_X       = OFF_M + 16777216;         // f32[16384*256]
static const size_t OFF_LOGITS  = OFF_X + 16777216;         // f32[16384*64]
static const size_t OFF_POUT    = OFF_LOGITS + 4194304;     // bf16[32768*256]
static const size_t OFF_W1T     = OFF_POUT + 16777216;      // bf16[64*512*256]  [e][n][k]
static const size_t OFF_W2T     = OFF_W1T + 16777216;       // bf16[64*256*512]  [e][n][k]
static const size_t OFF_H1B     = OFF_W2T + 16777216;       // bf16[32768*512]
// end ~117.6 MB (< round-2's 137.7 MB footprint)

typedef __bf16 bfrag __attribute__((ext_vector_type(8)));
typedef float f32x4 __attribute__((ext_vector_type(4)));

__device__ __forceinline__ float gelu_f(float v) {
    return 0.5f * v * (1.0f + erff(v * 0.70710678118654752f));
}
__device__ __forceinline__ unsigned short f2bf(float f) {
    union { float f; unsigned int u; } v; v.f = f;
    unsigned int u = v.u;
    unsigned int r = (u + 0x7FFFu + ((u >> 16) & 1u)) >> 16;   // RNE
    return (unsigned short)r;
}
__device__ __forceinline__ float bf2f(unsigned short s) {
    union { unsigned int u; float f; } v; v.u = ((unsigned int)s) << 16;
    return v.f;
}

// ---------- graph preprocessing ----------
__global__ __launch_bounds__(256) void k_count_deg(const int* __restrict__ src,
                                                   const int* __restrict__ dst,
                                                   int* __restrict__ dego,
                                                   int* __restrict__ degi) {
    int i = blockIdx.x * 256 + threadIdx.x;
    if (i < kEdges) {
        atomicAdd(&dego[src[i]], 1);
        atomicAdd(&degi[dst[i]], 1);
    }
}

__global__ __launch_bounds__(1024) void k_scan_nodes(const int* __restrict__ degi,
                                                     int* __restrict__ offs) {
    __shared__ int sums[1024];
    int t = threadIdx.x;
    int base = t * 16;
    int loc[16];
    int s = 0;
#pragma unroll
    for (int i = 0; i < 16; ++i) { loc[i] = degi[base + i]; s += loc[i]; }
    sums[t] = s;
    __syncthreads();
    for (int off = 1; off < 1024; off <<= 1) {
        int v = (t >= off) ? sums[t - off] : 0;
        __syncthreads();
        sums[t] += v;
        __syncthreads();
    }
    int run = sums[t] - s;
#pragma unroll
    for (int i = 0; i < 16; ++i) { offs[base + i] = run; run += loc[i]; }
    if (t == 1023) offs[kN] = run;
}

__global__ __launch_bounds__(256) void k_build_csr(const int* __restrict__ src,
                                                   const int* __restrict__ dst,
                                                   const int* __restrict__ offs,
                                                   int* __restrict__ cursor,
                                                   int* __restrict__ csr_src) {
    int i = blockIdx.x * 256 + threadIdx.x;
    if (i < kEdges) {
        int d = dst[i];
        int pos = atomicAdd(&cursor[d], 1);
        csr_src[offs[d] + pos] = src[i];
    }
}

__global__ __launch_bounds__(256) void k_aggregate(const float* __restrict__ feats,
                                                   const int* __restrict__ dego,
                                                   const int* __restrict__ degi,
                                                   const int* __restrict__ offs,
                                                   const int* __restrict__ csr_src,
                                                   float* __restrict__ m) {
    int n = blockIdx.x;
    int d = threadIdx.x;
    int beg = offs[n], end = offs[n + 1];
    float acc = 0.f;
    for (int i = beg; i < end; ++i) {
        int s = csr_src[i];
        int dg = dego[s]; if (dg < 1) dg = 1;
        float sc = rsqrtf((float)dg);
        acc += feats[(size_t)s * kD + d] * sc;
    }
    int dgi = degi[n]; if (dgi < 1) dgi = 1;
    m[(size_t)n * kD + d] = acc * rsqrtf((float)dgi);
}

// ---------- f32 tiled GEMM for x and gating (precision-critical path) ----------
#define FMA16()                                                                         \
    acc[0][0]=fmaf(a.x,b.x,acc[0][0]); acc[0][1]=fmaf(a.x,b.y,acc[0][1]);               \
    acc[0][2]=fmaf(a.x,b.z,acc[0][2]); acc[0][3]=fmaf(a.x,b.w,acc[0][3]);               \
    acc[1][0]=fmaf(a.y,b.x,acc[1][0]); acc[1][1]=fmaf(a.y,b.y,acc[1][1]);               \
    acc[1][2]=fmaf(a.y,b.z,acc[1][2]); acc[1][3]=fmaf(a.y,b.w,acc[1][3]);               \
    acc[2][0]=fmaf(a.z,b.x,acc[2][0]); acc[2][1]=fmaf(a.z,b.y,acc[2][1]);               \
    acc[2][2]=fmaf(a.z,b.z,acc[2][2]); acc[2][3]=fmaf(a.z,b.w,acc[2][3]);               \
    acc[3][0]=fmaf(a.w,b.x,acc[3][0]); acc[3][1]=fmaf(a.w,b.y,acc[3][1]);               \
    acc[3][2]=fmaf(a.w,b.z,acc[3][2]); acc[3][3]=fmaf(a.w,b.w,acc[3][3]);

__global__ __launch_bounds__(256) void k_xgemm(const float* __restrict__ m,
                                               const float* __restrict__ feats,
                                               const float* __restrict__ Wgc,
                                               const float* __restrict__ Wres,
                                               const float* __restrict__ bgc,
                                               const float* __restrict__ bres,
                                               float* __restrict__ x) {
    __shared__ float As[32][68];
    __shared__ float Bs[32][68];
    const int t = threadIdx.x;
    const int tx = t & 15, ty = t >> 4;
    const int m0 = blockIdx.y * 64;
    const int n0 = blockIdx.x * 64;
    float acc[4][4] = {};
    for (int pass = 0; pass < 2; ++pass) {
        const float* A = pass ? feats : m;
        const float* B = pass ? Wres : Wgc;
        for (int kb = 0; kb < kD; kb += 32) {
            __syncthreads();
#pragma unroll
            for (int i = 0; i < 2; ++i) {
                int fidx = i * 256 + t;
                int r = fidx >> 3, k4 = fidx & 7;
                float4 v = *(const float4*)(A + (size_t)(m0 + r) * kD + kb + k4 * 4);
                As[k4 * 4 + 0][r] = v.x; As[k4 * 4 + 1][r] = v.y;
                As[k4 * 4 + 2][r] = v.z; As[k4 * 4 + 3][r] = v.w;
            }
#pragma unroll
            for (int i = 0; i < 2; ++i) {
                int fidx = i * 256 + t;
                int kk = fidx >> 4, c4 = fidx & 15;
                float4 v = *(const float4*)(B + (size_t)(kb + kk) * kD + n0 + c4 * 4);
                *(float4*)&Bs[kk][c4 * 4] = v;
            }
            __syncthreads();
#pragma unroll
            for (int kk = 0; kk < 32; ++kk) {
                float4 a = *(const float4*)&As[kk][ty * 4];
                float4 b = *(const float4*)&Bs[kk][tx * 4];
                FMA16();
            }
        }
    }
    int col0 = n0 + tx * 4;
    float4 bb1 = *(const float4*)(bgc + col0);
    float4 bb2 = *(const float4*)(bres + col0);
#pragma unroll
    for (int i = 0; i < 4; ++i) {
        int row = m0 + ty * 4 + i;
        float4 o;
        o.x = acc[i][0] + bb1.x + bb2.x;
        o.y = acc[i][1] + bb1.y + bb2.y;
        o.z = acc[i][2] + bb1.z + bb2.z;
        o.w = acc[i][3] + bb1.w + bb2.w;
        *(float4*)(x + (size_t)row * kD + col0) = o;
    }
}

__global__ __launch_bounds__(256) void k_gate(const float* __restrict__ x,
                                              const float* __restrict__ Wg,
                                              const float* __restrict__ bg,
                                              float* __restrict__ logits) {
    __shared__ float As[32][68];
    __shared__ float Bs[32][68];
    const int t = threadIdx.x;
    const int tx = t & 15, ty = t >> 4;
    const int m0 = blockIdx.y * 64;
    float acc[4][4] = {};
    for (int kb = 0; kb < kD; kb += 32) {
        __syncthreads();
#pragma unroll
        for (int i = 0; i < 2; ++i) {
            int fidx = i * 256 + t;
            int r = fidx >> 3, k4 = fidx & 7;
            float4 v = *(const float4*)(x + (size_t)(m0 + r) * kD + kb + k4 * 4);
            As[k4 * 4 + 0][r] = v.x; As[k4 * 4 + 1][r] = v.y;
            As[k4 * 4 + 2][r] = v.z; As[k4 * 4 + 3][r] = v.w;
        }
#pragma unroll
        for (int i = 0; i < 2; ++i) {
            int fidx = i * 256 + t;
            int kk = fidx >> 4, c4 = fidx & 15;
            float4 v = *(const float4*)(Wg + (size_t)(kb + kk) * kE + c4 * 4);
            *(float4*)&Bs[kk][c4 * 4] = v;
        }
        __syncthreads();
#pragma unroll
        for (int kk = 0; kk < 32; ++kk) {
            float4 a = *(const float4*)&As[kk][ty * 4];
            float4 b = *(const float4*)&Bs[kk][tx * 4];
            FMA16();
        }
    }
    int col0 = tx * 4;
    float4 bb = *(const float4*)(bg + col0);
#pragma unroll
    for (int i = 0; i < 4; ++i) {
        int row = m0 + ty * 4 + i;
        float4 o;
        o.x = acc[i][0] + bb.x; o.y = acc[i][1] + bb.y;
        o.z = acc[i][2] + bb.z; o.w = acc[i][3] + bb.w;
        *(float4*)(logits + (size_t)row * kE + col0) = o;
    }
}

// ---------- gating: top-2 + softmax + bucket ----------
__global__ __launch_bounds__(256) void k_topk(const float* __restrict__ logits,
                                              int* __restrict__ eidx,
                                              float* __restrict__ egate,
                                              int* __restrict__ ecount) {
    int n = blockIdx.x * 256 + threadIdx.x;
    if (n >= kN) return;
    const float* row = logits + (size_t)n * kE;
    float v0 = -3.4e38f, v1 = -3.4e38f;
    int i0 = 0, i1 = 0;
    for (int e = 0; e < kE; ++e) {
        float v = row[e];
        if (v > v0) { v1 = v0; i1 = i0; v0 = v; i0 = e; }
        else if (v > v1) { v1 = v; i1 = e; }
    }
    float ex = expf(v1 - v0);
    float g0 = 1.0f / (1.0f + ex);
    float g1 = ex * g0;
    eidx[2 * n] = i0; eidx[2 * n + 1] = i1;
    egate[2 * n] = g0; egate[2 * n + 1] = g1;
    atomicAdd(&ecount[i0], 1);
    atomicAdd(&ecount[i1], 1);
}

__global__ void k_scan_experts(const int* __restrict__ ecount, int* __restrict__ eoffs) {
    if (threadIdx.x == 0) {
        int s = 0;
        for (int e = 0; e < kE; ++e) { eoffs[e] = s; s += ecount[e]; }
        eoffs[kE] = s;
    }
}

__global__ __launch_bounds__(256) void k_scatter(const int* __restrict__ eidx,
                                                 const int* __restrict__ eoffs,
                                                 int* __restrict__ ecur,
                                                 int* __restrict__ plist) {
    int p = blockIdx.x * 256 + threadIdx.x;
    if (p < kPairs) {
        int e = eidx[p];
        int pos = atomicAdd(&ecur[e], 1);
        plist[eoffs[e] + pos] = p;
    }
}

// ---------- bf16 conversions ----------
__global__ __launch_bounds__(256) void k_cast_x(const float* __restrict__ x,
                                                unsigned short* __restrict__ xb) {
    int i = blockIdx.x * 256 + threadIdx.x;          // 8 elems/thread
    float4 a = *(const float4*)(x + (size_t)i * 8);
    float4 b = *(const float4*)(x + (size_t)i * 8 + 4);
    ushort4 o0, o1;
    o0.x = f2bf(a.x); o0.y = f2bf(a.y); o0.z = f2bf(a.z); o0.w = f2bf(a.w);
    o1.x = f2bf(b.x); o1.y = f2bf(b.y); o1.z = f2bf(b.z); o1.w = f2bf(b.w);
    *(ushort4*)(xb + (size_t)i * 8) = o0;
    *(ushort4*)(xb + (size_t)i * 8 + 4) = o1;
}

// per-expert transpose+cast: w [e][R][C] f32 -> wt [e][C][R] bf16
__global__ __launch_bounds__(256) void k_transpose_cast(const float* __restrict__ w,
                                                        unsigned short* __restrict__ wt,
                                                        int R, int C) {
    __shared__ unsigned short tile[64][65];
    int e = blockIdx.z;
    const float* W = w + (size_t)e * R * C;
    unsigned short* WT = wt + (size_t)e * R * C;
    int r0 = blockIdx.y * 64, c0 = blockIdx.x * 64;
    int t = threadIdx.x;
#pragma unroll
    for (int i = 0; i < 4; ++i) {
        int idx = i * 256 + t;
        int r = idx >> 4, c4 = idx & 15;
        float4 v = *(const float4*)(W + (size_t)(r0 + r) * C + c0 + c4 * 4);
        tile[r][c4 * 4 + 0] = f2bf(v.x); tile[r][c4 * 4 + 1] = f2bf(v.y);
        tile[r][c4 * 4 + 2] = f2bf(v.z); tile[r][c4 * 4 + 3] = f2bf(v.w);
    }
    __syncthreads();
#pragma unroll
    for (int i = 0; i < 4; ++i) {
        int idx = i * 256 + t;
        int c = idx >> 4, r4 = idx & 15;
        ushort4 o;
        o.x = tile[r4 * 4 + 0][c]; o.y = tile[r4 * 4 + 1][c];
        o.z = tile[r4 * 4 + 2][c]; o.w = tile[r4 * 4 + 3][c];
        *(ushort4*)(WT + (size_t)(c0 + c) * R + r0 + r4 * 4) = o;
    }
}

// ---------- MoE MFMA GEMMs: 128x128 tile, BK=32, 4 waves x (4x4) 16x16x32 ----------
// A[m][k] bf16 LDS, B[n][k] bf16 LDS; D: col=lane&15, row=quad*4+reg (verified layout)
__global__ __launch_bounds__(256) void k_moe1_mfma(const unsigned short* __restrict__ xb,
                                                   const unsigned short* __restrict__ w1t,
                                                   const float* __restrict__ b1,
                                                   const int* __restrict__ plist,
                                                   const int* __restrict__ eoffs,
                                                   const int* __restrict__ ecount,
                                                   unsigned short* __restrict__ h1b) {
    __shared__ unsigned short As[128 * 32];
    __shared__ unsigned short Bs[128 * 32];
    __shared__ int rowtok[128];
    const int e = blockIdx.z;
    int cnt = ecount[e]; if (cnt > kCap) cnt = kCap;
    const int m0 = blockIdx.y * 128;
    if (m0 >= cnt) return;
    const int n0 = blockIdx.x * 128;
    const int base = eoffs[e];
    const int t = threadIdx.x;
    if (t < 128) {
        int slot = m0 + t;
        rowtok[t] = (slot < cnt) ? (plist[base + slot] >> 1) : -1;
    }
    const int lane = t & 63, w = t >> 6;
    const int m_off = (w & 1) * 64, n_off = (w >> 1) * 64;
    const int quad = lane >> 4, lr = lane & 15;
    const unsigned short* Bbase = w1t + (size_t)e * kH * kD;   // [512][256]
    f32x4 acc[4][4] = {};
    for (int kb = 0; kb < kD; kb += 32) {
        __syncthreads();
#pragma unroll
        for (int i = 0; i < 2; ++i) {
            int fidx = i * 256 + t;
            int row = fidx >> 2, kseg = fidx & 3;
            int tok = rowtok[row];
            uint4 v = make_uint4(0, 0, 0, 0);
            if (tok >= 0) v = *(const uint4*)(xb + (size_t)tok * kD + kb + kseg * 8);
            *(uint4*)&As[row * 32 + kseg * 8] = v;
        }
#pragma unroll
        for (int i = 0; i < 2; ++i) {
            int fidx = i * 256 + t;
            int row = fidx >> 2, kseg = fidx & 3;
            uint4 v = *(const uint4*)(Bbase + (size_t)(n0 + row) * kD + kb + kseg * 8);
            *(uint4*)&Bs[row * 32 + kseg * 8] = v;
        }
        __syncthreads();
        bfrag af[4], bf[4];
#pragma unroll
        for (int mi = 0; mi < 4; ++mi)
            af[mi] = *(const bfrag*)&As[(m_off + mi * 16 + lr) * 32 + quad * 8];
#pragma unroll
        for (int ni = 0; ni < 4; ++ni)
            bf[ni] = *(const bfrag*)&Bs[(n_off + ni * 16 + lr) * 32 + quad * 8];
#pragma unroll
        for (int mi = 0; mi < 4; ++mi)
#pragma unroll
            for (int ni = 0; ni < 4; ++ni)
                acc[mi][ni] = __builtin_amdgcn_mfma_f32_16x16x32_bf16(af[mi], bf[ni], acc[mi][ni], 0, 0, 0);
    }
#pragma unroll
    for (int mi = 0; mi < 4; ++mi) {
#pragma unroll
        for (int r = 0; r < 4; ++r) {
            int slot = m0 + m_off + mi * 16 + quad * 4 + r;
            if (slot < cnt) {
#pragma unroll
                for (int ni = 0; ni < 4; ++ni) {
                    int col = n0 + n_off + ni * 16 + lr;
                    float v = acc[mi][ni][r] + b1[e * kH + col];
                    h1b[(size_t)(base + slot) * kH + col] = f2bf(gelu_f(v));
                }
            }
        }
    }
}

__global__ __launch_bounds__(256) void k_moe2_mfma(const unsigned short* __restrict__ h1b,
                                                   const unsigned short* __restrict__ w2t,
                                                   const float* __restrict__ b2,
                                                   const int* __restrict__ plist,
                                                   const int* __restrict__ eoffs,
                                                   const int* __restrict__ ecount,
                                                   const float* __restrict__ egate,
                                                   unsigned short* __restrict__ pout) {
    __shared__ unsigned short As[128 * 32];
    __shared__ unsigned short Bs[128 * 32];
    __shared__ int prow[128];
    const int e = blockIdx.z;
    int cnt = ecount[e]; if (cnt > kCap) cnt = kCap;
    const int m0 = blockIdx.y * 128;
    if (m0 >= cnt) return;
    const int n0 = blockIdx.x * 128;
    const int base = eoffs[e];
    const int t = threadIdx.x;
    if (t < 128) {
        int slot = m0 + t;
        prow[t] = (slot < cnt) ? plist[base + slot] : -1;
    }
    const int lane = t & 63, w = t >> 6;
    const int m_off = (w & 1) * 64, n_off = (w >> 1) * 64;
    const int quad = lane >> 4, lr = lane & 15;
    const unsigned short* Bbase = w2t + (size_t)e * kD * kH;   // [256][512]
    f32x4 acc[4][4] = {};
    for (int kb = 0; kb < kH; kb += 32) {
        __syncthreads();
#pragma unroll
        for (int i = 0; i < 2; ++i) {
            int fidx = i * 256 + t;
            int row = fidx >> 2, kseg = fidx & 3;
            int slot = m0 + row;
            uint4 v = make_uint4(0, 0, 0, 0);
            if (slot < cnt) v = *(const uint4*)(h1b + (size_t)(base + slot) * kH + kb + kseg * 8);
            *(uint4*)&As[row * 32 + kseg * 8] = v;
        }
#pragma unroll
        for (int i = 0; i < 2; ++i) {
            int fidx = i * 256 + t;
            int row = fidx >> 2, kseg = fidx & 3;
            uint4 v = *(const uint4*)(Bbase + (size_t)(n0 + row) * kH + kb + kseg * 8);
            *(uint4*)&Bs[row * 32 + kseg * 8] = v;
        }
        __syncthreads();
        bfrag af[4], bf[4];
#pragma unroll
        for (int mi = 0; mi < 4; ++mi)
            af[mi] = *(const bfrag*)&As[(m_off + mi * 16 + lr) * 32 + quad * 8];
#pragma unroll
        for (int ni = 0; ni < 4; ++ni)
            bf[ni] = *(const bfrag*)&Bs[(n_off + ni * 16 + lr) * 32 + quad * 8];
#pragma unroll
        for (int mi = 0; mi < 4; ++mi)
#pragma unroll
            for (int ni = 0; ni < 4; ++ni)
                acc[mi][ni] = __builtin_amdgcn_mfma_f32_16x16x32_bf16(af[mi], bf[ni], acc[mi][ni], 0, 0, 0);
    }
#pragma unroll
    for (int mi = 0; mi < 4; ++mi) {
#pragma unroll
        for (int r = 0; r < 4; ++r) {
            int lslot = m_off + mi * 16 + quad * 4 + r;
            int p = prow[lslot];
            if (p >= 0) {
                float g = egate[p];
#pragma unroll
                for (int ni = 0; ni < 4; ++ni) {
                    int col = n0 + n_off + ni * 16 + lr;
                    float v = g * (acc[mi][ni][r] + b2[e * kD + col]);
                    pout[(size_t)p * kD + col] = f2bf(v);
                }
            }
        }
    }
}

// ---------- BN ----------
__global__ __launch_bounds__(256) void k_ybn(const float* __restrict__ x,
                                             const unsigned short* __restrict__ pout,
                                             float* __restrict__ y,
                                             float* __restrict__ colsum,
                                             float* __restrict__ colsum2) {
    int d = threadIdx.x;
    int r0 = blockIdx.x * 64;
    float s = 0.f, s2 = 0.f;
    for (int i = 0; i < 64; ++i) {
        int row = r0 + i;
        float v = x[(size_t)row * kD + d]
                + bf2f(pout[(size_t)(2 * row) * kD + d])
                + bf2f(pout[(size_t)(2 * row + 1) * kD + d]);
        y[(size_t)row * kD + d] = v;
        s += v; s2 += v * v;
    }
    atomicAdd(&colsum[d], s);
    atomicAdd(&colsum2[d], s2);
}

__global__ void k_bnparams(const float* __restrict__ colsum,
                           const float* __restrict__ colsum2,
                           const float* __restrict__ gamma,
                           const float* __restrict__ beta,
                           float* __restrict__ scale,
                           float* __restrict__ shift) {
    int d = threadIdx.x;
    float mean = colsum[d] * (1.0f / kN);
    float var = colsum2[d] * (1.0f / kN) - mean * mean;
    float inv = rsqrtf(var + 1e-5f);
    float sc = inv * gamma[d];
    scale[d] = sc;
    shift[d] = beta[d] - mean * sc;
}

__global__ __launch_bounds__(256) void k_apply(const float* __restrict__ y,
                                               const float* __restrict__ scale,
                                               const float* __restrict__ shift,
                                               float* __restrict__ out) {
    int i = blockIdx.x * 256 + threadIdx.x;
    float4 v = ((const float4*)y)[i];
    int d = (i * 4) & (kD - 1);
    float4 sc = *(const float4*)(scale + d);
    float4 sh = *(const float4*)(shift + d);
    v.x = v.x * sc.x + sh.x;
    v.y = v.y * sc.y + sh.y;
    v.z = v.z * sc.z + sh.z;
    v.w = v.w * sc.w + sh.w;
    ((float4*)out)[i] = v;
}

extern "C" void kernel_launch(void* const* d_in, const int* in_sizes, int n_in,
                              void* d_out, int out_size, void* d_ws, size_t ws_size,
                              hipStream_t stream) {
    const float* feats = (const float*)d_in[0];
    const float* Wgc   = (const float*)d_in[1];
    const float* bgc   = (const float*)d_in[2];
    const float* Wres  = (const float*)d_in[3];
    const float* bres  = (const float*)d_in[4];
    const float* Wg    = (const float*)d_in[5];
    const float* bg    = (const float*)d_in[6];
    const float* w1    = (const float*)d_in[7];
    const float* b1    = (const float*)d_in[8];
    const float* w2    = (const float*)d_in[9];
    const float* b2    = (const float*)d_in[10];
    const float* gamma = (const float*)d_in[11];
    const float* beta  = (const float*)d_in[12];
    const int*   src   = (const int*)d_in[13];
    const int*   dst   = (const int*)d_in[14];

    char* ws = (char*)d_ws;
    int*   dego    = (int*)(ws + OFF_DEGO);
    int*   degi    = (int*)(ws + OFF_DEGI);
    int*   cursor  = (int*)(ws + OFF_CURSOR);
    int*   ecount  = (int*)(ws + OFF_ECOUNT);
    int*   ecur    = (int*)(ws + OFF_ECUR);
    float* colsum  = (float*)(ws + OFF_COLSUM);
    float* colsum2 = (float*)(ws + OFF_COLSUM2);
    int*   eoffs   = (int*)(ws + OFF_EOFFS);
    int*   csroff  = (int*)(ws + OFF_CSROFF);
    int*   csrsrc  = (int*)(ws + OFF_CSRSRC);
    int*   plist   = (int*)(ws + OFF_PLIST);
    int*   eidx    = (int*)(ws + OFF_EIDX);
    float* egate   = (float*)(ws + OFF_EGATE);
    float* scale   = (float*)(ws + OFF_SCALE);
    float* shift   = (float*)(ws + OFF_SHIFT);
    float* mbuf    = (float*)(ws + OFF_M);       // m; xb alias; y alias
    unsigned short* xb = (unsigned short*)(ws + OFF_M);
    float* xbuf    = (float*)(ws + OFF_X);
    float* logits  = (float*)(ws + OFF_LOGITS);
    unsigned short* pout = (unsigned short*)(ws + OFF_POUT);
    unsigned short* w1t  = (unsigned short*)(ws + OFF_W1T);
    unsigned short* w2t  = (unsigned short*)(ws + OFF_W2T);
    unsigned short* h1b  = (unsigned short*)(ws + OFF_H1B);
    float* ybuf    = mbuf;

    hipMemsetAsync(ws, 0, ZERO_BYTES, stream);

    k_transpose_cast<<<dim3(kH / 64, kD / 64, kE), 256, 0, stream>>>(w1, w1t, kD, kH);
    k_transpose_cast<<<dim3(kD / 64, kH / 64, kE), 256, 0, stream>>>(w2, w2t, kH, kD);
    k_count_deg<<<kEdges / 256, 256, 0, stream>>>(src, dst, dego, degi);
    k_scan_nodes<<<1, 1024, 0, stream>>>(degi, csroff);
    k_build_csr<<<kEdges / 256, 256, 0, stream>>>(src, dst, csroff, cursor, csrsrc);
    k_aggregate<<<kN, 256, 0, stream>>>(feats, dego, degi, csroff, csrsrc, mbuf);
    k_xgemm<<<dim3(kD / 64, kN / 64), 256, 0, stream>>>(mbuf, feats, Wgc, Wres, bgc, bres, xbuf);
    k_cast_x<<<kN * kD / 8 / 256, 256, 0, stream>>>(xbuf, xb);
    k_gate<<<dim3(1, kN / 64), 256, 0, stream>>>(xbuf, Wg, bg, logits);
    k_topk<<<kN / 256, 256, 0, stream>>>(logits, eidx, egate, ecount);
    k_scan_experts<<<1, 64, 0, stream>>>(ecount, eoffs);
    k_scatter<<<kPairs / 256, 256, 0, stream>>>(eidx, eoffs, ecur, plist);
    k_moe1_mfma<<<dim3(kH / 128, kCap / 128, kE), 256, 0, stream>>>(xb, w1t, b1, plist, eoffs, ecount, h1b);
    k_moe2_mfma<<<dim3(kD / 128, kCap / 128, kE), 256, 0, stream>>>(h1b, w2t, b2, plist, eoffs, ecount, egate, pout);
    k_ybn<<<kN / 64, 256, 0, stream>>>(xbuf, pout, ybuf, colsum, colsum2);
    k_bnparams<<<1, 256, 0, stream>>>(colsum, colsum2, gamma, beta, scale, shift);
    k_apply<<<(kN * kD / 4) / 256, 256, 0, stream>>>(ybuf, scale, shift, (float*)d_out);
}

// Round 4
// 513.451 us; speedup vs baseline: 1.4225x; 1.1395x over previous
//
#include <hip/hip_runtime.h>
#include <math.h>

// ---- problem constants ----
static const int kN     = 16384;
static const int kEdges = 262144;
static const int kD     = 256;
static const int kH     = 512;
static const int kE     = 64;
static const int kCap   = 1024;
static const int kPairs = kN * 2;

// ---- workspace layout (bytes) ----
static const size_t OFF_DEGO    = 0;                        // int[16384]
static const size_t OFF_DEGI    = OFF_DEGO + 65536;
static const size_t OFF_CURSOR  = OFF_DEGI + 65536;
static const size_t OFF_ECOUNT  = OFF_CURSOR + 65536;       // int[64]
static const size_t OFF_ECUR    = OFF_ECOUNT + 256;
static const size_t OFF_COLSUM  = OFF_ECUR + 256;           // f32[256]
static const size_t OFF_COLSUM2 = OFF_COLSUM + 1024;
static const size_t ZERO_BYTES  = OFF_COLSUM2 + 1024;       // 199168
static const size_t OFF_EOFFS   = ZERO_BYTES;               // int[65]
static const size_t OFF_CSROFF  = OFF_EOFFS + 512;          // int[16385]
static const size_t OFF_CSRSRC  = OFF_CSROFF + 65792;       // int[262144]
static const size_t OFF_PLIST   = OFF_CSRSRC + 1048576;     // int[32768]
static const size_t OFF_EIDX    = OFF_PLIST + 131072;       // int[32768]
static const size_t OFF_EGATE   = OFF_EIDX + 131072;        // f32[32768]
static const size_t OFF_SCALE   = OFF_EGATE + 131072;       // f32[256]
static const size_t OFF_SHIFT   = OFF_SCALE + 1024;         // f32[256]
static const size_t OFF_OSC     = OFF_SHIFT + 1024;         // f32[16384]
static const size_t OFF_ISC     = OFF_OSC + 65536;          // f32[16384]
static const size_t OFF_M       = OFF_ISC + 65536;          // f32[16384*256]; xb bf16 aliases; y aliases
static const size_t OFF_X       = OFF_M + 16777216;         // f32[16384*256]
static const size_t OFF_XB      = OFF_X + 16777216;         // bf16[16384*256]
static const size_t OFF_LOGITS  = OFF_XB + 8388608;         // f32[16384*64]
static const size_t OFF_POUT    = OFF_LOGITS + 4194304;     // bf16[32768*256]
static const size_t OFF_W1T     = OFF_POUT + 16777216;      // bf16[64*512*256]  [e][n][k]
static const size_t OFF_W2T     = OFF_W1T + 16777216;       // bf16[64*256*512]  [e][n][k]
static const size_t OFF_H1B     = OFF_W2T + 16777216;       // bf16[32768*512]

typedef __bf16 bfrag __attribute__((ext_vector_type(8)));
typedef float f32x4 __attribute__((ext_vector_type(4)));

// tanh-form gelu: max |err| vs exact-erf gelu ~3e-4 (<< bf16 rounding of h1)
__device__ __forceinline__ float gelu_f(float v) {
    float u = v * (0.7978845608f + 0.0356774081f * v * v);
    float t = __expf(-2.0f * fabsf(u));
    float th = (1.0f - t) * __builtin_amdgcn_rcpf(1.0f + t);
    th = copysignf(th, u);
    return 0.5f * v * (1.0f + th);
}
__device__ __forceinline__ unsigned short f2bf(float f) {
    union { float f; unsigned int u; } v; v.f = f;
    unsigned int u = v.u;
    unsigned int r = (u + 0x7FFFu + ((u >> 16) & 1u)) >> 16;   // RNE
    return (unsigned short)r;
}
__device__ __forceinline__ float bf2f(unsigned short s) {
    union { unsigned int u; float f; } v; v.u = ((unsigned int)s) << 16;
    return v.f;
}

// ---------- graph preprocessing ----------
__global__ __launch_bounds__(256) void k_count_deg(const int* __restrict__ src,
                                                   const int* __restrict__ dst,
                                                   int* __restrict__ dego,
                                                   int* __restrict__ degi) {
    int i = blockIdx.x * 256 + threadIdx.x;
    if (i < kEdges) {
        atomicAdd(&dego[src[i]], 1);
        atomicAdd(&degi[dst[i]], 1);
    }
}

__global__ __launch_bounds__(256) void k_scales(const int* __restrict__ dego,
                                                const int* __restrict__ degi,
                                                float* __restrict__ osc,
                                                float* __restrict__ isc) {
    int i = blockIdx.x * 256 + threadIdx.x;
    int a = dego[i]; if (a < 1) a = 1;
    int b = degi[i]; if (b < 1) b = 1;
    osc[i] = rsqrtf((float)a);
    isc[i] = rsqrtf((float)b);
}

__global__ __launch_bounds__(1024) void k_scan_nodes(const int* __restrict__ degi,
                                                     int* __restrict__ offs) {
    __shared__ int sums[1024];
    int t = threadIdx.x;
    int base = t * 16;
    int loc[16];
    int s = 0;
#pragma unroll
    for (int i = 0; i < 16; ++i) { loc[i] = degi[base + i]; s += loc[i]; }
    sums[t] = s;
    __syncthreads();
    for (int off = 1; off < 1024; off <<= 1) {
        int v = (t >= off) ? sums[t - off] : 0;
        __syncthreads();
        sums[t] += v;
        __syncthreads();
    }
    int run = sums[t] - s;
#pragma unroll
    for (int i = 0; i < 16; ++i) { offs[base + i] = run; run += loc[i]; }
    if (t == 1023) offs[kN] = run;
}

__global__ __launch_bounds__(256) void k_build_csr(const int* __restrict__ src,
                                                   const int* __restrict__ dst,
                                                   const int* __restrict__ offs,
                                                   int* __restrict__ cursor,
                                                   int* __restrict__ csr_src) {
    int i = blockIdx.x * 256 + threadIdx.x;
    if (i < kEdges) {
        int d = dst[i];
        int pos = atomicAdd(&cursor[d], 1);
        csr_src[offs[d] + pos] = src[i];
    }
}

// one node per block; 4 waves process 4 edges concurrently, float4 cols
__global__ __launch_bounds__(256) void k_aggregate(const float* __restrict__ feats,
                                                   const float* __restrict__ osc,
                                                   const float* __restrict__ isc,
                                                   const int* __restrict__ offs,
                                                   const int* __restrict__ csr_src,
                                                   float* __restrict__ m) {
    __shared__ f32x4 red[256];
    int n = blockIdx.x;
    int t = threadIdx.x;
    int c4 = (t & 63) * 4;
    int es = t >> 6;
    int beg = offs[n], end = offs[n + 1];
    f32x4 acc = {0.f, 0.f, 0.f, 0.f};
    for (int i = beg + es; i < end; i += 4) {
        int s = csr_src[i];
        float sc = osc[s];
        const float4 v = *(const float4*)(feats + (size_t)s * kD + c4);
        acc[0] += v.x * sc; acc[1] += v.y * sc;
        acc[2] += v.z * sc; acc[3] += v.w * sc;
    }
    red[t] = acc;
    __syncthreads();
    if (t < 64) {
        f32x4 a = red[t], b = red[t + 64], c = red[t + 128], d = red[t + 192];
        float si = isc[n];
        float4 o;
        o.x = (a[0] + b[0] + c[0] + d[0]) * si;
        o.y = (a[1] + b[1] + c[1] + d[1]) * si;
        o.z = (a[2] + b[2] + c[2] + d[2]) * si;
        o.w = (a[3] + b[3] + c[3] + d[3]) * si;
        *(float4*)(m + (size_t)n * kD + c4) = o;
    }
}

// ---------- f32 tiled GEMM (precision-critical: feeds routing) ----------
#define FMA16()                                                                         \
    acc[0][0]=fmaf(a.x,b.x,acc[0][0]); acc[0][1]=fmaf(a.x,b.y,acc[0][1]);               \
    acc[0][2]=fmaf(a.x,b.z,acc[0][2]); acc[0][3]=fmaf(a.x,b.w,acc[0][3]);               \
    acc[1][0]=fmaf(a.y,b.x,acc[1][0]); acc[1][1]=fmaf(a.y,b.y,acc[1][1]);               \
    acc[1][2]=fmaf(a.y,b.z,acc[1][2]); acc[1][3]=fmaf(a.y,b.w,acc[1][3]);               \
    acc[2][0]=fmaf(a.z,b.x,acc[2][0]); acc[2][1]=fmaf(a.z,b.y,acc[2][1]);               \
    acc[2][2]=fmaf(a.z,b.z,acc[2][2]); acc[2][3]=fmaf(a.z,b.w,acc[2][3]);               \
    acc[3][0]=fmaf(a.w,b.x,acc[3][0]); acc[3][1]=fmaf(a.w,b.y,acc[3][1]);               \
    acc[3][2]=fmaf(a.w,b.z,acc[3][2]); acc[3][3]=fmaf(a.w,b.w,acc[3][3]);

__global__ __launch_bounds__(256) void k_xgemm(const float* __restrict__ m,
                                               const float* __restrict__ feats,
                                               const float* __restrict__ Wgc,
                                               const float* __restrict__ Wres,
                                               const float* __restrict__ bgc,
                                               const float* __restrict__ bres,
                                               float* __restrict__ x,
                                               unsigned short* __restrict__ xb) {
    __shared__ float As[32][68];
    __shared__ float Bs[32][68];
    const int t = threadIdx.x;
    const int tx = t & 15, ty = t >> 4;
    const int m0 = blockIdx.y * 64;
    const int n0 = blockIdx.x * 64;
    float acc[4][4] = {};
    for (int pass = 0; pass < 2; ++pass) {
        const float* A = pass ? feats : m;
        const float* B = pass ? Wres : Wgc;
        for (int kb = 0; kb < kD; kb += 32) {
            __syncthreads();
#pragma unroll
            for (int i = 0; i < 2; ++i) {
                int fidx = i * 256 + t;
                int r = fidx >> 3, k4 = fidx & 7;
                float4 v = *(const float4*)(A + (size_t)(m0 + r) * kD + kb + k4 * 4);
                As[k4 * 4 + 0][r] = v.x; As[k4 * 4 + 1][r] = v.y;
                As[k4 * 4 + 2][r] = v.z; As[k4 * 4 + 3][r] = v.w;
            }
#pragma unroll
            for (int i = 0; i < 2; ++i) {
                int fidx = i * 256 + t;
                int kk = fidx >> 4, c4 = fidx & 15;
                float4 v = *(const float4*)(B + (size_t)(kb + kk) * kD + n0 + c4 * 4);
                *(float4*)&Bs[kk][c4 * 4] = v;
            }
            __syncthreads();
#pragma unroll
            for (int kk = 0; kk < 32; ++kk) {
                float4 a = *(const float4*)&As[kk][ty * 4];
                float4 b = *(const float4*)&Bs[kk][tx * 4];
                FMA16();
            }
        }
    }
    int col0 = n0 + tx * 4;
    float4 bb1 = *(const float4*)(bgc + col0);
    float4 bb2 = *(const float4*)(bres + col0);
#pragma unroll
    for (int i = 0; i < 4; ++i) {
        int row = m0 + ty * 4 + i;
        float4 o;
        o.x = acc[i][0] + bb1.x + bb2.x;
        o.y = acc[i][1] + bb1.y + bb2.y;
        o.z = acc[i][2] + bb1.z + bb2.z;
        o.w = acc[i][3] + bb1.w + bb2.w;
        *(float4*)(x + (size_t)row * kD + col0) = o;
        ushort4 ob;
        ob.x = f2bf(o.x); ob.y = f2bf(o.y); ob.z = f2bf(o.z); ob.w = f2bf(o.w);
        *(ushort4*)(xb + (size_t)row * kD + col0) = ob;
    }
}

__global__ __launch_bounds__(256) void k_gate(const float* __restrict__ x,
                                              const float* __restrict__ Wg,
                                              const float* __restrict__ bg,
                                              float* __restrict__ logits) {
    __shared__ float As[32][68];
    __shared__ float Bs[32][68];
    const int t = threadIdx.x;
    const int tx = t & 15, ty = t >> 4;
    const int m0 = blockIdx.y * 64;
    float acc[4][4] = {};
    for (int kb = 0; kb < kD; kb += 32) {
        __syncthreads();
#pragma unroll
        for (int i = 0; i < 2; ++i) {
            int fidx = i * 256 + t;
            int r = fidx >> 3, k4 = fidx & 7;
            float4 v = *(const float4*)(x + (size_t)(m0 + r) * kD + kb + k4 * 4);
            As[k4 * 4 + 0][r] = v.x; As[k4 * 4 + 1][r] = v.y;
            As[k4 * 4 + 2][r] = v.z; As[k4 * 4 + 3][r] = v.w;
        }
#pragma unroll
        for (int i = 0; i < 2; ++i) {
            int fidx = i * 256 + t;
            int kk = fidx >> 4, c4 = fidx & 15;
            float4 v = *(const float4*)(Wg + (size_t)(kb + kk) * kE + c4 * 4);
            *(float4*)&Bs[kk][c4 * 4] = v;
        }
        __syncthreads();
#pragma unroll
        for (int kk = 0; kk < 32; ++kk) {
            float4 a = *(const float4*)&As[kk][ty * 4];
            float4 b = *(const float4*)&Bs[kk][tx * 4];
            FMA16();
        }
    }
    int col0 = tx * 4;
    float4 bb = *(const float4*)(bg + col0);
#pragma unroll
    for (int i = 0; i < 4; ++i) {
        int row = m0 + ty * 4 + i;
        float4 o;
        o.x = acc[i][0] + bb.x; o.y = acc[i][1] + bb.y;
        o.z = acc[i][2] + bb.z; o.w = acc[i][3] + bb.w;
        *(float4*)(logits + (size_t)row * kE + col0) = o;
    }
}

// ---------- gating ----------
__global__ __launch_bounds__(256) void k_topk(const float* __restrict__ logits,
                                              int* __restrict__ eidx,
                                              float* __restrict__ egate,
                                              int* __restrict__ ecount) {
    int n = blockIdx.x * 256 + threadIdx.x;
    if (n >= kN) return;
    const float* row = logits + (size_t)n * kE;
    float v0 = -3.4e38f, v1 = -3.4e38f;
    int i0 = 0, i1 = 0;
    for (int e = 0; e < kE; ++e) {
        float v = row[e];
        if (v > v0) { v1 = v0; i1 = i0; v0 = v; i0 = e; }
        else if (v > v1) { v1 = v; i1 = e; }
    }
    float ex = expf(v1 - v0);
    float g0 = 1.0f / (1.0f + ex);
    float g1 = ex * g0;
    eidx[2 * n] = i0; eidx[2 * n + 1] = i1;
    egate[2 * n] = g0; egate[2 * n + 1] = g1;
    atomicAdd(&ecount[i0], 1);
    atomicAdd(&ecount[i1], 1);
}

__global__ void k_scan_experts(const int* __restrict__ ecount, int* __restrict__ eoffs) {
    if (threadIdx.x == 0) {
        int s = 0;
        for (int e = 0; e < kE; ++e) { eoffs[e] = s; s += ecount[e]; }
        eoffs[kE] = s;
    }
}

__global__ __launch_bounds__(256) void k_scatter(const int* __restrict__ eidx,
                                                 const int* __restrict__ eoffs,
                                                 int* __restrict__ ecur,
                                                 int* __restrict__ plist) {
    int p = blockIdx.x * 256 + threadIdx.x;
    if (p < kPairs) {
        int e = eidx[p];
        int pos = atomicAdd(&ecur[e], 1);
        plist[eoffs[e] + pos] = p;
    }
}

// per-expert transpose+cast: w [e][R][C] f32 -> wt [e][C][R] bf16
__global__ __launch_bounds__(256) void k_transpose_cast(const float* __restrict__ w,
                                                        unsigned short* __restrict__ wt,
                                                        int R, int C) {
    __shared__ unsigned short tile[64][65];
    int e = blockIdx.z;
    const float* W = w + (size_t)e * R * C;
    unsigned short* WT = wt + (size_t)e * R * C;
    int r0 = blockIdx.y * 64, c0 = blockIdx.x * 64;
    int t = threadIdx.x;
#pragma unroll
    for (int i = 0; i < 4; ++i) {
        int idx = i * 256 + t;
        int r = idx >> 4, c4 = idx & 15;
        float4 v = *(const float4*)(W + (size_t)(r0 + r) * C + c0 + c4 * 4);
        tile[r][c4 * 4 + 0] = f2bf(v.x); tile[r][c4 * 4 + 1] = f2bf(v.y);
        tile[r][c4 * 4 + 2] = f2bf(v.z); tile[r][c4 * 4 + 3] = f2bf(v.w);
    }
    __syncthreads();
#pragma unroll
    for (int i = 0; i < 4; ++i) {
        int idx = i * 256 + t;
        int c = idx >> 4, r4 = idx & 15;
        ushort4 o;
        o.x = tile[r4 * 4 + 0][c]; o.y = tile[r4 * 4 + 1][c];
        o.z = tile[r4 * 4 + 2][c]; o.w = tile[r4 * 4 + 3][c];
        *(ushort4*)(WT + (size_t)(c0 + c) * R + r0 + r4 * 4) = o;
    }
}

// ---------- MoE MFMA GEMMs: 128x128, BK=32, 4 waves x (4x4) 16x16x32 ----------
__global__ __launch_bounds__(256) void k_moe1_mfma(const unsigned short* __restrict__ xb,
                                                   const unsigned short* __restrict__ w1t,
                                                   const float* __restrict__ b1,
                                                   const int* __restrict__ plist,
                                                   const int* __restrict__ eoffs,
                                                   const int* __restrict__ ecount,
                                                   unsigned short* __restrict__ h1b) {
    __shared__ unsigned short As[128 * 32];
    __shared__ unsigned short Bs[128 * 32];
    __shared__ int rowtok[128];
    const int e = blockIdx.z;
    int cnt = ecount[e]; if (cnt > kCap) cnt = kCap;
    const int m0 = blockIdx.y * 128;
    if (m0 >= cnt) return;
    const int n0 = blockIdx.x * 128;
    const int base = eoffs[e];
    const int t = threadIdx.x;
    if (t < 128) {
        int slot = m0 + t;
        rowtok[t] = (slot < cnt) ? (plist[base + slot] >> 1) : -1;
    }
    const int lane = t & 63, w = t >> 6;
    const int m_off = (w & 1) * 64, n_off = (w >> 1) * 64;
    const int quad = lane >> 4, lr = lane & 15;
    const unsigned short* Bbase = w1t + (size_t)e * kH * kD;   // [512][256]
    // hoisted bias (4 distinct cols per thread)
    float breg[4];
#pragma unroll
    for (int ni = 0; ni < 4; ++ni) breg[ni] = b1[e * kH + n0 + n_off + ni * 16 + lr];
    // precompute per-thread staging sources (2 A rows, 2 B rows; fixed across K)
    const int arow0 = t >> 2, arow1 = 64 + (t >> 2);
    const int kseg = (t & 3) * 8;
    __syncthreads();
    const int tok0 = rowtok[arow0], tok1 = rowtok[arow1];
    const unsigned short* pA0 = (tok0 >= 0) ? xb + (size_t)tok0 * kD + kseg : nullptr;
    const unsigned short* pA1 = (tok1 >= 0) ? xb + (size_t)tok1 * kD + kseg : nullptr;
    const unsigned short* pB0 = Bbase + (size_t)(n0 + arow0) * kD + kseg;
    const unsigned short* pB1 = Bbase + (size_t)(n0 + arow1) * kD + kseg;
    unsigned short* sA0 = &As[arow0 * 32 + kseg];
    unsigned short* sA1 = &As[arow1 * 32 + kseg];
    unsigned short* sB0 = &Bs[arow0 * 32 + kseg];
    unsigned short* sB1 = &Bs[arow1 * 32 + kseg];
    f32x4 acc[4][4] = {};
    for (int kb = 0; kb < kD; kb += 32) {
        uint4 a0 = pA0 ? *(const uint4*)(pA0 + kb) : make_uint4(0, 0, 0, 0);
        uint4 a1 = pA1 ? *(const uint4*)(pA1 + kb) : make_uint4(0, 0, 0, 0);
        uint4 bv0 = *(const uint4*)(pB0 + kb);
        uint4 bv1 = *(const uint4*)(pB1 + kb);
        __syncthreads();
        *(uint4*)sA0 = a0; *(uint4*)sA1 = a1;
        *(uint4*)sB0 = bv0; *(uint4*)sB1 = bv1;
        __syncthreads();
        bfrag af[4], bf[4];
#pragma unroll
        for (int mi = 0; mi < 4; ++mi)
            af[mi] = *(const bfrag*)&As[(m_off + mi * 16 + lr) * 32 + quad * 8];
#pragma unroll
        for (int ni = 0; ni < 4; ++ni)
            bf[ni] = *(const bfrag*)&Bs[(n_off + ni * 16 + lr) * 32 + quad * 8];
#pragma unroll
        for (int mi = 0; mi < 4; ++mi)
#pragma unroll
            for (int ni = 0; ni < 4; ++ni)
                acc[mi][ni] = __builtin_amdgcn_mfma_f32_16x16x32_bf16(af[mi], bf[ni], acc[mi][ni], 0, 0, 0);
    }
#pragma unroll
    for (int mi = 0; mi < 4; ++mi) {
#pragma unroll
        for (int r = 0; r < 4; ++r) {
            int slot = m0 + m_off + mi * 16 + quad * 4 + r;
            if (slot < cnt) {
                unsigned short* orow = h1b + (size_t)(base + slot) * kH + n0 + n_off + lr;
#pragma unroll
                for (int ni = 0; ni < 4; ++ni)
                    orow[ni * 16] = f2bf(gelu_f(acc[mi][ni][r] + breg[ni]));
            }
        }
    }
}

__global__ __launch_bounds__(256) void k_moe2_mfma(const unsigned short* __restrict__ h1b,
                                                   const unsigned short* __restrict__ w2t,
                                                   const float* __restrict__ b2,
                                                   const int* __restrict__ plist,
                                                   const int* __restrict__ eoffs,
                                                   const int* __restrict__ ecount,
                                                   const float* __restrict__ egate,
                                                   unsigned short* __restrict__ pout) {
    __shared__ unsigned short As[128 * 32];
    __shared__ unsigned short Bs[128 * 32];
    __shared__ int prow[128];
    __shared__ float sgate[128];
    const int e = blockIdx.z;
    int cnt = ecount[e]; if (cnt > kCap) cnt = kCap;
    const int m0 = blockIdx.y * 128;
    if (m0 >= cnt) return;
    const int n0 = blockIdx.x * 128;
    const int base = eoffs[e];
    const int t = threadIdx.x;
    if (t < 128) {
        int slot = m0 + t;
        int p = (slot < cnt) ? plist[base + slot] : -1;
        prow[t] = p;
        sgate[t] = (p >= 0) ? egate[p] : 0.f;
    }
    const int lane = t & 63, w = t >> 6;
    const int m_off = (w & 1) * 64, n_off = (w >> 1) * 64;
    const int quad = lane >> 4, lr = lane & 15;
    const unsigned short* Bbase = w2t + (size_t)e * kD * kH;   // [256][512]
    float breg[4];
#pragma unroll
    for (int ni = 0; ni < 4; ++ni) breg[ni] = b2[e * kD + n0 + n_off + ni * 16 + lr];
    const int arow0 = t >> 2, arow1 = 64 + (t >> 2);
    const int kseg = (t & 3) * 8;
    int aslot0 = m0 + arow0, aslot1 = m0 + arow1;
    const unsigned short* pA0 = (aslot0 < cnt) ? h1b + (size_t)(base + aslot0) * kH + kseg : nullptr;
    const unsigned short* pA1 = (aslot1 < cnt) ? h1b + (size_t)(base + aslot1) * kH + kseg : nullptr;
    const unsigned short* pB0 = Bbase + (size_t)(n0 + arow0) * kH + kseg;
    const unsigned short* pB1 = Bbase + (size_t)(n0 + arow1) * kH + kseg;
    unsigned short* sA0 = &As[arow0 * 32 + kseg];
    unsigned short* sA1 = &As[arow1 * 32 + kseg];
    unsigned short* sB0 = &Bs[arow0 * 32 + kseg];
    unsigned short* sB1 = &Bs[arow1 * 32 + kseg];
    f32x4 acc[4][4] = {};
    for (int kb = 0; kb < kH; kb += 32) {
        uint4 a0 = pA0 ? *(const uint4*)(pA0 + kb) : make_uint4(0, 0, 0, 0);
        uint4 a1 = pA1 ? *(const uint4*)(pA1 + kb) : make_uint4(0, 0, 0, 0);
        uint4 bv0 = *(const uint4*)(pB0 + kb);
        uint4 bv1 = *(const uint4*)(pB1 + kb);
        __syncthreads();
        *(uint4*)sA0 = a0; *(uint4*)sA1 = a1;
        *(uint4*)sB0 = bv0; *(uint4*)sB1 = bv1;
        __syncthreads();
        bfrag af[4], bf[4];
#pragma unroll
        for (int mi = 0; mi < 4; ++mi)
            af[mi] = *(const bfrag*)&As[(m_off + mi * 16 + lr) * 32 + quad * 8];
#pragma unroll
        for (int ni = 0; ni < 4; ++ni)
            bf[ni] = *(const bfrag*)&Bs[(n_off + ni * 16 + lr) * 32 + quad * 8];
#pragma unroll
        for (int mi = 0; mi < 4; ++mi)
#pragma unroll
            for (int ni = 0; ni < 4; ++ni)
                acc[mi][ni] = __builtin_amdgcn_mfma_f32_16x16x32_bf16(af[mi], bf[ni], acc[mi][ni], 0, 0, 0);
    }
#pragma unroll
    for (int mi = 0; mi < 4; ++mi) {
#pragma unroll
        for (int r = 0; r < 4; ++r) {
            int lslot = m_off + mi * 16 + quad * 4 + r;
            int p = prow[lslot];
            if (p >= 0) {
                float g = sgate[lslot];
                unsigned short* orow = pout + (size_t)p * kD + n0 + n_off + lr;
#pragma unroll
                for (int ni = 0; ni < 4; ++ni)
                    orow[ni * 16] = f2bf(g * (acc[mi][ni][r] + breg[ni]));
            }
        }
    }
}

// ---------- BN ----------
__global__ __launch_bounds__(256) void k_ybn(const float* __restrict__ x,
                                             const unsigned short* __restrict__ pout,
                                             float* __restrict__ y,
                                             float* __restrict__ colsum,
                                             float* __restrict__ colsum2) {
    int d = threadIdx.x;
    int r0 = blockIdx.x * 64;
    float s = 0.f, s2 = 0.f;
    for (int i = 0; i < 64; ++i) {
        int row = r0 + i;
        float v = x[(size_t)row * kD + d]
                + bf2f(pout[(size_t)(2 * row) * kD + d])
                + bf2f(pout[(size_t)(2 * row + 1) * kD + d]);
        y[(size_t)row * kD + d] = v;
        s += v; s2 += v * v;
    }
    atomicAdd(&colsum[d], s);
    atomicAdd(&colsum2[d], s2);
}

__global__ void k_bnparams(const float* __restrict__ colsum,
                           const float* __restrict__ colsum2,
                           const float* __restrict__ gamma,
                           const float* __restrict__ beta,
                           float* __restrict__ scale,
                           float* __restrict__ shift) {
    int d = threadIdx.x;
    float mean = colsum[d] * (1.0f / kN);
    float var = colsum2[d] * (1.0f / kN) - mean * mean;
    float inv = rsqrtf(var + 1e-5f);
    float sc = inv * gamma[d];
    scale[d] = sc;
    shift[d] = beta[d] - mean * sc;
}

__global__ __launch_bounds__(256) void k_apply(const float* __restrict__ y,
                                               const float* __restrict__ scale,
                                               const float* __restrict__ shift,
                                               float* __restrict__ out) {
    int i = blockIdx.x * 256 + threadIdx.x;
    float4 v = ((const float4*)y)[i];
    int d = (i * 4) & (kD - 1);
    float4 sc = *(const float4*)(scale + d);
    float4 sh = *(const float4*)(shift + d);
    v.x = v.x * sc.x + sh.x;
    v.y = v.y * sc.y + sh.y;
    v.z = v.z * sc.z + sh.z;
    v.w = v.w * sc.w + sh.w;
    ((float4*)out)[i] = v;
}

extern "C" void kernel_launch(void* const* d_in, const int* in_sizes, int n_in,
                              void* d_out, int out_size, void* d_ws, size_t ws_size,
                              hipStream_t stream) {
    const float* feats = (const float*)d_in[0];
    const float* Wgc   = (const float*)d_in[1];
    const float* bgc   = (const float*)d_in[2];
    const float* Wres  = (const float*)d_in[3];
    const float* bres  = (const float*)d_in[4];
    const float* Wg    = (const float*)d_in[5];
    const float* bg    = (const float*)d_in[6];
    const float* w1    = (const float*)d_in[7];
    const float* b1    = (const float*)d_in[8];
    const float* w2    = (const float*)d_in[9];
    const float* b2    = (const float*)d_in[10];
    const float* gamma = (const float*)d_in[11];
    const float* beta  = (const float*)d_in[12];
    const int*   src   = (const int*)d_in[13];
    const int*   dst   = (const int*)d_in[14];

    char* ws = (char*)d_ws;
    int*   dego    = (int*)(ws + OFF_DEGO);
    int*   degi    = (int*)(ws + OFF_DEGI);
    int*   cursor  = (int*)(ws + OFF_CURSOR);
    int*   ecount  = (int*)(ws + OFF_ECOUNT);
    int*   ecur    = (int*)(ws + OFF_ECUR);
    float* colsum  = (float*)(ws + OFF_COLSUM);
    float* colsum2 = (float*)(ws + OFF_COLSUM2);
    int*   eoffs   = (int*)(ws + OFF_EOFFS);
    int*   csroff  = (int*)(ws + OFF_CSROFF);
    int*   csrsrc  = (int*)(ws + OFF_CSRSRC);
    int*   plist   = (int*)(ws + OFF_PLIST);
    int*   eidx    = (int*)(ws + OFF_EIDX);
    float* egate   = (float*)(ws + OFF_EGATE);
    float* scale   = (float*)(ws + OFF_SCALE);
    float* shift   = (float*)(ws + OFF_SHIFT);
    float* osc     = (float*)(ws + OFF_OSC);
    float* iscv    = (float*)(ws + OFF_ISC);
    float* mbuf    = (float*)(ws + OFF_M);       // m; y alias
    float* xbuf    = (float*)(ws + OFF_X);
    unsigned short* xb = (unsigned short*)(ws + OFF_XB);
    float* logits  = (float*)(ws + OFF_LOGITS);
    unsigned short* pout = (unsigned short*)(ws + OFF_POUT);
    unsigned short* w1t  = (unsigned short*)(ws + OFF_W1T);
    unsigned short* w2t  = (unsigned short*)(ws + OFF_W2T);
    unsigned short* h1b  = (unsigned short*)(ws + OFF_H1B);
    float* ybuf    = mbuf;

    hipMemsetAsync(ws, 0, ZERO_BYTES, stream);

    k_transpose_cast<<<dim3(kH / 64, kD / 64, kE), 256, 0, stream>>>(w1, w1t, kD, kH);
    k_transpose_cast<<<dim3(kD / 64, kH / 64, kE), 256, 0, stream>>>(w2, w2t, kH, kD);
    k_count_deg<<<kEdges / 256, 256, 0, stream>>>(src, dst, dego, degi);
    k_scales<<<kN / 256, 256, 0, stream>>>(dego, degi, osc, iscv);
    k_scan_nodes<<<1, 1024, 0, stream>>>(degi, csroff);
    k_build_csr<<<kEdges / 256, 256, 0, stream>>>(src, dst, csroff, cursor, csrsrc);
    k_aggregate<<<kN, 256, 0, stream>>>(feats, osc, iscv, csroff, csrsrc, mbuf);
    k_xgemm<<<dim3(kD / 64, kN / 64), 256, 0, stream>>>(mbuf, feats, Wgc, Wres, bgc, bres, xbuf, xb);
    k_gate<<<dim3(1, kN / 64), 256, 0, stream>>>(xbuf, Wg, bg, logits);
    k_topk<<<kN / 256, 256, 0, stream>>>(logits, eidx, egate, ecount);
    k_scan_experts<<<1, 64, 0, stream>>>(ecount, eoffs);
    k_scatter<<<kPairs / 256, 256, 0, stream>>>(eidx, eoffs, ecur, plist);
    k_moe1_mfma<<<dim3(kH / 128, kCap / 128, kE), 256, 0, stream>>>(xb, w1t, b1, plist, eoffs, ecount, h1b);
    k_moe2_mfma<<<dim3(kD / 128, kCap / 128, kE), 256, 0, stream>>>(h1b, w2t, b2, plist, eoffs, ecount, egate, pout);
    k_ybn<<<kN / 64, 256, 0, stream>>>(xbuf, pout, ybuf, colsum, colsum2);
    k_bnparams<<<1, 256, 0, stream>>>(colsum, colsum2, gamma, beta, scale, shift);
    k_apply<<<(kN * kD / 4) / 256, 256, 0, stream>>>(ybuf, scale, shift, (float*)d_out);
}

// Round 5
// 504.617 us; speedup vs baseline: 1.4474x; 1.0175x over previous
//
#include <hip/hip_runtime.h>
#include <math.h>

// ---- problem constants ----
static const int kN     = 16384;
static const int kEdges = 262144;
static const int kD     = 256;
static const int kH     = 512;
static const int kE     = 64;
static const int kCap   = 1024;
static const int kPairs = kN * 2;

// ---- workspace layout (bytes) ----
static const size_t OFF_DEGO    = 0;                        // int[16384]
static const size_t OFF_DEGI    = OFF_DEGO + 65536;
static const size_t OFF_CURSOR  = OFF_DEGI + 65536;
static const size_t OFF_ECOUNT  = OFF_CURSOR + 65536;       // int[64]
static const size_t OFF_ECUR    = OFF_ECOUNT + 256;
static const size_t OFF_COLSUM  = OFF_ECUR + 256;           // f32[256]
static const size_t OFF_COLSUM2 = OFF_COLSUM + 1024;
static const size_t ZERO_BYTES  = OFF_COLSUM2 + 1024;       // 199168
static const size_t OFF_EOFFS   = ZERO_BYTES;               // int[65]
static const size_t OFF_CSROFF  = OFF_EOFFS + 512;          // int[16385]
static const size_t OFF_CSRSRC  = OFF_CSROFF + 65792;       // int[262144]
static const size_t OFF_PLIST   = OFF_CSRSRC + 1048576;     // int[32768]
static const size_t OFF_EIDX    = OFF_PLIST + 131072;       // int[32768]
static const size_t OFF_EGATE   = OFF_EIDX + 131072;        // f32[32768]
static const size_t OFF_SCALE   = OFF_EGATE + 131072;       // f32[256]
static const size_t OFF_SHIFT   = OFF_SCALE + 1024;         // f32[256]
static const size_t OFF_OSC     = OFF_SHIFT + 1024;         // f32[16384]
static const size_t OFF_ISC     = OFF_OSC + 65536;          // f32[16384]
static const size_t OFF_WQ1     = OFF_ISC + 65536;          // f32[256*64]   composed gate W for m
static const size_t OFF_WQ2     = OFF_WQ1 + 65536;          // f32[256*64]   composed gate W for feats
static const size_t OFF_BGE     = OFF_WQ2 + 65536;          // f32[64]
static const size_t OFF_WCAT    = OFF_BGE + 256;            // bf16[256][512]  [n][k] = [Wgc;Wres]^T
static const size_t OFF_M       = OFF_WCAT + 262144;        // f32[16384*256]
static const size_t OFF_X       = OFF_M + 16777216;         // f32[16384*256]
static const size_t OFF_XB      = OFF_X + 16777216;         // bf16[16384*256]
static const size_t OFF_LOGITS  = OFF_XB + 8388608;         // f32[16384*64]
static const size_t OFF_POUT    = OFF_LOGITS + 4194304;     // bf16[32768*256]; ACAT (bf16 16384*512) aliases (dead before moe2)
static const size_t OFF_W1T     = OFF_POUT + 16777216;      // bf16[64*512*256]  [e][n][k]
static const size_t OFF_W2T     = OFF_W1T + 16777216;       // bf16[64*256*512]  [e][n][k]
static const size_t OFF_H1B     = OFF_W2T + 16777216;       // bf16[32768*512]
// end ~132.3 MB (round-2 used ~134 MB successfully)

typedef __bf16 bfrag __attribute__((ext_vector_type(8)));
typedef float f32x4 __attribute__((ext_vector_type(4)));

// tanh-form gelu: max |err| vs exact-erf gelu ~3e-4 (<< bf16 rounding of h1)
__device__ __forceinline__ float gelu_f(float v) {
    float u = v * (0.7978845608f + 0.0356774081f * v * v);
    float t = __expf(-2.0f * fabsf(u));
    float th = (1.0f - t) * __builtin_amdgcn_rcpf(1.0f + t);
    th = copysignf(th, u);
    return 0.5f * v * (1.0f + th);
}
__device__ __forceinline__ unsigned short f2bf(float f) {
    union { float f; unsigned int u; } v; v.f = f;
    unsigned int u = v.u;
    unsigned int r = (u + 0x7FFFu + ((u >> 16) & 1u)) >> 16;   // RNE
    return (unsigned short)r;
}
__device__ __forceinline__ float bf2f(unsigned short s) {
    union { unsigned int u; float f; } v; v.u = ((unsigned int)s) << 16;
    return v.f;
}

// ---------- graph preprocessing ----------
__global__ __launch_bounds__(256) void k_count_deg(const int* __restrict__ src,
                                                   const int* __restrict__ dst,
                                                   int* __restrict__ dego,
                                                   int* __restrict__ degi) {
    int i = blockIdx.x * 256 + threadIdx.x;
    if (i < kEdges) {
        atomicAdd(&dego[src[i]], 1);
        atomicAdd(&degi[dst[i]], 1);
    }
}

__global__ __launch_bounds__(256) void k_scales(const int* __restrict__ dego,
                                                const int* __restrict__ degi,
                                                float* __restrict__ osc,
                                                float* __restrict__ isc) {
    int i = blockIdx.x * 256 + threadIdx.x;
    int a = dego[i]; if (a < 1) a = 1;
    int b = degi[i]; if (b < 1) b = 1;
    osc[i] = rsqrtf((float)a);
    isc[i] = rsqrtf((float)b);
}

__global__ __launch_bounds__(1024) void k_scan_nodes(const int* __restrict__ degi,
                                                     int* __restrict__ offs) {
    __shared__ int sums[1024];
    int t = threadIdx.x;
    int base = t * 16;
    int loc[16];
    int s = 0;
#pragma unroll
    for (int i = 0; i < 16; ++i) { loc[i] = degi[base + i]; s += loc[i]; }
    sums[t] = s;
    __syncthreads();
    for (int off = 1; off < 1024; off <<= 1) {
        int v = (t >= off) ? sums[t - off] : 0;
        __syncthreads();
        sums[t] += v;
        __syncthreads();
    }
    int run = sums[t] - s;
#pragma unroll
    for (int i = 0; i < 16; ++i) { offs[base + i] = run; run += loc[i]; }
    if (t == 1023) offs[kN] = run;
}

__global__ __launch_bounds__(256) void k_build_csr(const int* __restrict__ src,
                                                   const int* __restrict__ dst,
                                                   const int* __restrict__ offs,
                                                   int* __restrict__ cursor,
                                                   int* __restrict__ csr_src) {
    int i = blockIdx.x * 256 + threadIdx.x;
    if (i < kEdges) {
        int d = dst[i];
        int pos = atomicAdd(&cursor[d], 1);
        csr_src[offs[d] + pos] = src[i];
    }
}

// one node per block; 4 waves process 4 edges concurrently, float4 cols
__global__ __launch_bounds__(256) void k_aggregate(const float* __restrict__ feats,
                                                   const float* __restrict__ osc,
                                                   const float* __restrict__ isc,
                                                   const int* __restrict__ offs,
                                                   const int* __restrict__ csr_src,
                                                   float* __restrict__ m) {
    __shared__ f32x4 red[256];
    int n = blockIdx.x;
    int t = threadIdx.x;
    int c4 = (t & 63) * 4;
    int es = t >> 6;
    int beg = offs[n], end = offs[n + 1];
    f32x4 acc = {0.f, 0.f, 0.f, 0.f};
    for (int i = beg + es; i < end; i += 4) {
        int s = csr_src[i];
        float sc = osc[s];
        const float4 v = *(const float4*)(feats + (size_t)s * kD + c4);
        acc[0] += v.x * sc; acc[1] += v.y * sc;
        acc[2] += v.z * sc; acc[3] += v.w * sc;
    }
    red[t] = acc;
    __syncthreads();
    if (t < 64) {
        f32x4 a = red[t], b = red[t + 64], c = red[t + 128], d = red[t + 192];
        float si = isc[n];
        float4 o;
        o.x = (a[0] + b[0] + c[0] + d[0]) * si;
        o.y = (a[1] + b[1] + c[1] + d[1]) * si;
        o.z = (a[2] + b[2] + c[2] + d[2]) * si;
        o.w = (a[3] + b[3] + c[3] + d[3]) * si;
        *(float4*)(m + (size_t)n * kD + c4) = o;
    }
}

// ---------- composed gate weights (f32, tiny): Wq = Wsrc @ Wg; bge = bg + (bgc+bres)@Wg
__global__ __launch_bounds__(256) void k_compose(const float* __restrict__ Wgc,
                                                 const float* __restrict__ Wres,
                                                 const float* __restrict__ Wg,
                                                 const float* __restrict__ bgc,
                                                 const float* __restrict__ bres,
                                                 const float* __restrict__ bg,
                                                 float* __restrict__ Wq1,
                                                 float* __restrict__ Wq2,
                                                 float* __restrict__ bge) {
    int tid = blockIdx.x * 256 + threadIdx.x;
    if (tid < 2 * kD * kE) {
        int mat = tid >> 14;            // 0: Wgc, 1: Wres
        int rem = tid & 16383;
        int d = rem >> 6, e = rem & 63;
        const float* A = mat ? Wres : Wgc;
        float acc = 0.f;
        for (int c = 0; c < kD; ++c)
            acc = fmaf(A[d * kD + c], Wg[c * kE + e], acc);
        (mat ? Wq2 : Wq1)[d * kE + e] = acc;
    } else if (tid < 2 * kD * kE + kE) {
        int e = tid - 2 * kD * kE;
        float acc = bg[e];
        for (int d = 0; d < kD; ++d)
            acc = fmaf(bgc[d] + bres[d], Wg[d * kE + e], acc);
        bge[e] = acc;
    }
}

// logits = m@Wq1 + feats@Wq2 + bge  (f32 — routing-accuracy-critical)
#define FMA16()                                                                         \
    acc[0][0]=fmaf(a.x,b.x,acc[0][0]); acc[0][1]=fmaf(a.x,b.y,acc[0][1]);               \
    acc[0][2]=fmaf(a.x,b.z,acc[0][2]); acc[0][3]=fmaf(a.x,b.w,acc[0][3]);               \
    acc[1][0]=fmaf(a.y,b.x,acc[1][0]); acc[1][1]=fmaf(a.y,b.y,acc[1][1]);               \
    acc[1][2]=fmaf(a.y,b.z,acc[1][2]); acc[1][3]=fmaf(a.y,b.w,acc[1][3]);               \
    acc[2][0]=fmaf(a.z,b.x,acc[2][0]); acc[2][1]=fmaf(a.z,b.y,acc[2][1]);               \
    acc[2][2]=fmaf(a.z,b.z,acc[2][2]); acc[2][3]=fmaf(a.z,b.w,acc[2][3]);               \
    acc[3][0]=fmaf(a.w,b.x,acc[3][0]); acc[3][1]=fmaf(a.w,b.y,acc[3][1]);               \
    acc[3][2]=fmaf(a.w,b.z,acc[3][2]); acc[3][3]=fmaf(a.w,b.w,acc[3][3]);

__global__ __launch_bounds__(256) void k_gate_comp(const float* __restrict__ m,
                                                   const float* __restrict__ feats,
                                                   const float* __restrict__ Wq1,
                                                   const float* __restrict__ Wq2,
                                                   const float* __restrict__ bge,
                                                   float* __restrict__ logits) {
    __shared__ float As[32][68];
    __shared__ float Bs[32][68];
    const int t = threadIdx.x;
    const int tx = t & 15, ty = t >> 4;
    const int m0 = blockIdx.y * 64;
    float acc[4][4] = {};
    for (int pass = 0; pass < 2; ++pass) {
        const float* A = pass ? feats : m;
        const float* B = pass ? Wq2 : Wq1;
        for (int kb = 0; kb < kD; kb += 32) {
            __syncthreads();
#pragma unroll
            for (int i = 0; i < 2; ++i) {
                int fidx = i * 256 + t;
                int r = fidx >> 3, k4 = fidx & 7;
                float4 v = *(const float4*)(A + (size_t)(m0 + r) * kD + kb + k4 * 4);
                As[k4 * 4 + 0][r] = v.x; As[k4 * 4 + 1][r] = v.y;
                As[k4 * 4 + 2][r] = v.z; As[k4 * 4 + 3][r] = v.w;
            }
#pragma unroll
            for (int i = 0; i < 2; ++i) {
                int fidx = i * 256 + t;
                int kk = fidx >> 4, c4 = fidx & 15;
                float4 v = *(const float4*)(B + (size_t)(kb + kk) * kE + c4 * 4);
                *(float4*)&Bs[kk][c4 * 4] = v;
            }
            __syncthreads();
#pragma unroll
            for (int kk = 0; kk < 32; ++kk) {
                float4 a = *(const float4*)&As[kk][ty * 4];
                float4 b = *(const float4*)&Bs[kk][tx * 4];
                FMA16();
            }
        }
    }
    int col0 = tx * 4;
    float4 bb = *(const float4*)(bge + col0);
#pragma unroll
    for (int i = 0; i < 4; ++i) {
        int row = m0 + ty * 4 + i;
        float4 o;
        o.x = acc[i][0] + bb.x; o.y = acc[i][1] + bb.y;
        o.z = acc[i][2] + bb.z; o.w = acc[i][3] + bb.w;
        *(float4*)(logits + (size_t)row * kE + col0) = o;
    }
}

// Acat[t][0:256]=bf16(m[t]); Acat[t][256:512]=bf16(feats[t])
__global__ __launch_bounds__(256) void k_cast_cat(const float* __restrict__ m,
                                                  const float* __restrict__ feats,
                                                  unsigned short* __restrict__ acat) {
    int i = blockIdx.x * 256 + threadIdx.x;          // 8 elems
    const float* srcp = blockIdx.y ? feats : m;
    int doff = blockIdx.y ? 256 : 0;
    size_t g = (size_t)i * 8;
    int tok = (int)(g >> 8), d = (int)(g & 255);
    float4 a = *(const float4*)(srcp + g);
    float4 b = *(const float4*)(srcp + g + 4);
    ushort4 o0, o1;
    o0.x = f2bf(a.x); o0.y = f2bf(a.y); o0.z = f2bf(a.z); o0.w = f2bf(a.w);
    o1.x = f2bf(b.x); o1.y = f2bf(b.y); o1.z = f2bf(b.z); o1.w = f2bf(b.w);
    unsigned short* dstp = acat + (size_t)tok * 512 + doff + d;
    *(ushort4*)dstp = o0;
    *(ushort4*)(dstp + 4) = o1;
}

// transpose+cast: w [e][R][C] f32 -> wt[(c)*dstride + doff + r] bf16 (per e, step R*C both sides)
__global__ __launch_bounds__(256) void k_transpose_cast(const float* __restrict__ w,
                                                        unsigned short* __restrict__ wt,
                                                        int R, int C, int dstride, int doff) {
    __shared__ unsigned short tile[64][65];
    int e = blockIdx.z;
    const float* W = w + (size_t)e * R * C;
    unsigned short* WT = wt + (size_t)e * R * C;
    int r0 = blockIdx.y * 64, c0 = blockIdx.x * 64;
    int t = threadIdx.x;
#pragma unroll
    for (int i = 0; i < 4; ++i) {
        int idx = i * 256 + t;
        int r = idx >> 4, c4 = idx & 15;
        float4 v = *(const float4*)(W + (size_t)(r0 + r) * C + c0 + c4 * 4);
        tile[r][c4 * 4 + 0] = f2bf(v.x); tile[r][c4 * 4 + 1] = f2bf(v.y);
        tile[r][c4 * 4 + 2] = f2bf(v.z); tile[r][c4 * 4 + 3] = f2bf(v.w);
    }
    __syncthreads();
#pragma unroll
    for (int i = 0; i < 4; ++i) {
        int idx = i * 256 + t;
        int c = idx >> 4, r4 = idx & 15;
        ushort4 o;
        o.x = tile[r4 * 4 + 0][c]; o.y = tile[r4 * 4 + 1][c];
        o.z = tile[r4 * 4 + 2][c]; o.w = tile[r4 * 4 + 3][c];
        *(ushort4*)(WT + (size_t)(c0 + c) * dstride + doff + r0 + r4 * 4) = o;
    }
}

// ---------- x = [m|feats] @ [Wgc;Wres]^T + bgc + bres   (bf16 MFMA, K=512) ----------
__global__ __launch_bounds__(256) void k_xgemm_mfma(const unsigned short* __restrict__ acat,
                                                    const unsigned short* __restrict__ wcat,
                                                    const float* __restrict__ bgc,
                                                    const float* __restrict__ bres,
                                                    float* __restrict__ x,
                                                    unsigned short* __restrict__ xb) {
    __shared__ unsigned short As[128 * 32];
    __shared__ unsigned short Bs[128 * 32];
    const int t = threadIdx.x;
    const int m0 = blockIdx.y * 128;
    const int n0 = blockIdx.x * 128;
    const int lane = t & 63, w = t >> 6;
    const int m_off = (w & 1) * 64, n_off = (w >> 1) * 64;
    const int quad = lane >> 4, lr = lane & 15;
    float breg[4];
#pragma unroll
    for (int ni = 0; ni < 4; ++ni) {
        int col = n0 + n_off + ni * 16 + lr;
        breg[ni] = bgc[col] + bres[col];
    }
    const int arow0 = t >> 2, arow1 = 64 + (t >> 2);
    const int kseg = (t & 3) * 8;
    const unsigned short* pA0 = acat + (size_t)(m0 + arow0) * 512 + kseg;
    const unsigned short* pA1 = acat + (size_t)(m0 + arow1) * 512 + kseg;
    const unsigned short* pB0 = wcat + (size_t)(n0 + arow0) * 512 + kseg;
    const unsigned short* pB1 = wcat + (size_t)(n0 + arow1) * 512 + kseg;
    unsigned short* sA0 = &As[arow0 * 32 + kseg];
    unsigned short* sA1 = &As[arow1 * 32 + kseg];
    unsigned short* sB0 = &Bs[arow0 * 32 + kseg];
    unsigned short* sB1 = &Bs[arow1 * 32 + kseg];
    f32x4 acc[4][4] = {};
    for (int kb = 0; kb < 512; kb += 32) {
        uint4 a0 = *(const uint4*)(pA0 + kb);
        uint4 a1 = *(const uint4*)(pA1 + kb);
        uint4 bv0 = *(const uint4*)(pB0 + kb);
        uint4 bv1 = *(const uint4*)(pB1 + kb);
        __syncthreads();
        *(uint4*)sA0 = a0; *(uint4*)sA1 = a1;
        *(uint4*)sB0 = bv0; *(uint4*)sB1 = bv1;
        __syncthreads();
        bfrag af[4], bf[4];
#pragma unroll
        for (int mi = 0; mi < 4; ++mi)
            af[mi] = *(const bfrag*)&As[(m_off + mi * 16 + lr) * 32 + quad * 8];
#pragma unroll
        for (int ni = 0; ni < 4; ++ni)
            bf[ni] = *(const bfrag*)&Bs[(n_off + ni * 16 + lr) * 32 + quad * 8];
#pragma unroll
        for (int mi = 0; mi < 4; ++mi)
#pragma unroll
            for (int ni = 0; ni < 4; ++ni)
                acc[mi][ni] = __builtin_amdgcn_mfma_f32_16x16x32_bf16(af[mi], bf[ni], acc[mi][ni], 0, 0, 0);
    }
#pragma unroll
    for (int mi = 0; mi < 4; ++mi) {
#pragma unroll
        for (int r = 0; r < 4; ++r) {
            int row = m0 + m_off + mi * 16 + quad * 4 + r;
            float* xrow = x + (size_t)row * kD + n0 + n_off + lr;
            unsigned short* xbrow = xb + (size_t)row * kD + n0 + n_off + lr;
#pragma unroll
            for (int ni = 0; ni < 4; ++ni) {
                float v = acc[mi][ni][r] + breg[ni];
                xrow[ni * 16] = v;
                xbrow[ni * 16] = f2bf(v);
            }
        }
    }
}

// ---------- gating ----------
__global__ __launch_bounds__(256) void k_topk(const float* __restrict__ logits,
                                              int* __restrict__ eidx,
                                              float* __restrict__ egate,
                                              int* __restrict__ ecount) {
    int n = blockIdx.x * 256 + threadIdx.x;
    if (n >= kN) return;
    const float* row = logits + (size_t)n * kE;
    float v0 = -3.4e38f, v1 = -3.4e38f;
    int i0 = 0, i1 = 0;
    for (int e4 = 0; e4 < kE; e4 += 4) {
        float4 vv = *(const float4*)(row + e4);
        float vs[4] = {vv.x, vv.y, vv.z, vv.w};
#pragma unroll
        for (int j = 0; j < 4; ++j) {
            float v = vs[j];
            int e = e4 + j;
            if (v > v0) { v1 = v0; i1 = i0; v0 = v; i0 = e; }
            else if (v > v1) { v1 = v; i1 = e; }
        }
    }
    float ex = expf(v1 - v0);
    float g0 = 1.0f / (1.0f + ex);
    float g1 = ex * g0;
    eidx[2 * n] = i0; eidx[2 * n + 1] = i1;
    egate[2 * n] = g0; egate[2 * n + 1] = g1;
    atomicAdd(&ecount[i0], 1);
    atomicAdd(&ecount[i1], 1);
}

__global__ void k_scan_experts(const int* __restrict__ ecount, int* __restrict__ eoffs) {
    if (threadIdx.x == 0) {
        int s = 0;
        for (int e = 0; e < kE; ++e) { eoffs[e] = s; s += ecount[e]; }
        eoffs[kE] = s;
    }
}

__global__ __launch_bounds__(256) void k_scatter(const int* __restrict__ eidx,
                                                 const int* __restrict__ eoffs,
                                                 int* __restrict__ ecur,
                                                 int* __restrict__ plist) {
    int p = blockIdx.x * 256 + threadIdx.x;
    if (p < kPairs) {
        int e = eidx[p];
        int pos = atomicAdd(&ecur[e], 1);
        plist[eoffs[e] + pos] = p;
    }
}

// ---------- MoE MFMA GEMMs ----------
__global__ __launch_bounds__(256) void k_moe1_mfma(const unsigned short* __restrict__ xb,
                                                   const unsigned short* __restrict__ w1t,
                                                   const float* __restrict__ b1,
                                                   const int* __restrict__ plist,
                                                   const int* __restrict__ eoffs,
                                                   const int* __restrict__ ecount,
                                                   unsigned short* __restrict__ h1b) {
    __shared__ unsigned short As[128 * 32];
    __shared__ unsigned short Bs[128 * 32];
    __shared__ int rowtok[128];
    const int e = blockIdx.z;
    int cnt = ecount[e]; if (cnt > kCap) cnt = kCap;
    const int m0 = blockIdx.y * 128;
    if (m0 >= cnt) return;
    const int n0 = blockIdx.x * 128;
    const int base = eoffs[e];
    const int t = threadIdx.x;
    if (t < 128) {
        int slot = m0 + t;
        rowtok[t] = (slot < cnt) ? (plist[base + slot] >> 1) : -1;
    }
    const int lane = t & 63, w = t >> 6;
    const int m_off = (w & 1) * 64, n_off = (w >> 1) * 64;
    const int quad = lane >> 4, lr = lane & 15;
    const unsigned short* Bbase = w1t + (size_t)e * kH * kD;
    float breg[4];
#pragma unroll
    for (int ni = 0; ni < 4; ++ni) breg[ni] = b1[e * kH + n0 + n_off + ni * 16 + lr];
    const int arow0 = t >> 2, arow1 = 64 + (t >> 2);
    const int kseg = (t & 3) * 8;
    __syncthreads();
    const int tok0 = rowtok[arow0], tok1 = rowtok[arow1];
    const unsigned short* pA0 = (tok0 >= 0) ? xb + (size_t)tok0 * kD + kseg : nullptr;
    const unsigned short* pA1 = (tok1 >= 0) ? xb + (size_t)tok1 * kD + kseg : nullptr;
    const unsigned short* pB0 = Bbase + (size_t)(n0 + arow0) * kD + kseg;
    const unsigned short* pB1 = Bbase + (size_t)(n0 + arow1) * kD + kseg;
    unsigned short* sA0 = &As[arow0 * 32 + kseg];
    unsigned short* sA1 = &As[arow1 * 32 + kseg];
    unsigned short* sB0 = &Bs[arow0 * 32 + kseg];
    unsigned short* sB1 = &Bs[arow1 * 32 + kseg];
    f32x4 acc[4][4] = {};
    for (int kb = 0; kb < kD; kb += 32) {
        uint4 a0 = pA0 ? *(const uint4*)(pA0 + kb) : make_uint4(0, 0, 0, 0);
        uint4 a1 = pA1 ? *(const uint4*)(pA1 + kb) : make_uint4(0, 0, 0, 0);
        uint4 bv0 = *(const uint4*)(pB0 + kb);
        uint4 bv1 = *(const uint4*)(pB1 + kb);
        __syncthreads();
        *(uint4*)sA0 = a0; *(uint4*)sA1 = a1;
        *(uint4*)sB0 = bv0; *(uint4*)sB1 = bv1;
        __syncthreads();
        bfrag af[4], bf[4];
#pragma unroll
        for (int mi = 0; mi < 4; ++mi)
            af[mi] = *(const bfrag*)&As[(m_off + mi * 16 + lr) * 32 + quad * 8];
#pragma unroll
        for (int ni = 0; ni < 4; ++ni)
            bf[ni] = *(const bfrag*)&Bs[(n_off + ni * 16 + lr) * 32 + quad * 8];
#pragma unroll
        for (int mi = 0; mi < 4; ++mi)
#pragma unroll
            for (int ni = 0; ni < 4; ++ni)
                acc[mi][ni] = __builtin_amdgcn_mfma_f32_16x16x32_bf16(af[mi], bf[ni], acc[mi][ni], 0, 0, 0);
    }
#pragma unroll
    for (int mi = 0; mi < 4; ++mi) {
#pragma unroll
        for (int r = 0; r < 4; ++r) {
            int slot = m0 + m_off + mi * 16 + quad * 4 + r;
            if (slot < cnt) {
                unsigned short* orow = h1b + (size_t)(base + slot) * kH + n0 + n_off + lr;
#pragma unroll
                for (int ni = 0; ni < 4; ++ni)
                    orow[ni * 16] = f2bf(gelu_f(acc[mi][ni][r] + breg[ni]));
            }
        }
    }
}

__global__ __launch_bounds__(256) void k_moe2_mfma(const unsigned short* __restrict__ h1b,
                                                   const unsigned short* __restrict__ w2t,
                                                   const float* __restrict__ b2,
                                                   const int* __restrict__ plist,
                                                   const int* __restrict__ eoffs,
                                                   const int* __restrict__ ecount,
                                                   const float* __restrict__ egate,
                                                   unsigned short* __restrict__ pout) {
    __shared__ unsigned short As[128 * 32];
    __shared__ unsigned short Bs[128 * 32];
    __shared__ int prow[128];
    __shared__ float sgate[128];
    const int e = blockIdx.z;
    int cnt = ecount[e]; if (cnt > kCap) cnt = kCap;
    const int m0 = blockIdx.y * 128;
    if (m0 >= cnt) return;
    const int n0 = blockIdx.x * 128;
    const int base = eoffs[e];
    const int t = threadIdx.x;
    if (t < 128) {
        int slot = m0 + t;
        int p = (slot < cnt) ? plist[base + slot] : -1;
        prow[t] = p;
        sgate[t] = (p >= 0) ? egate[p] : 0.f;
    }
    const int lane = t & 63, w = t >> 6;
    const int m_off = (w & 1) * 64, n_off = (w >> 1) * 64;
    const int quad = lane >> 4, lr = lane & 15;
    const unsigned short* Bbase = w2t + (size_t)e * kD * kH;
    float breg[4];
#pragma unroll
    for (int ni = 0; ni < 4; ++ni) breg[ni] = b2[e * kD + n0 + n_off + ni * 16 + lr];
    const int arow0 = t >> 2, arow1 = 64 + (t >> 2);
    const int kseg = (t & 3) * 8;
    int aslot0 = m0 + arow0, aslot1 = m0 + arow1;
    const unsigned short* pA0 = (aslot0 < cnt) ? h1b + (size_t)(base + aslot0) * kH + kseg : nullptr;
    const unsigned short* pA1 = (aslot1 < cnt) ? h1b + (size_t)(base + aslot1) * kH + kseg : nullptr;
    const unsigned short* pB0 = Bbase + (size_t)(n0 + arow0) * kH + kseg;
    const unsigned short* pB1 = Bbase + (size_t)(n0 + arow1) * kH + kseg;
    unsigned short* sA0 = &As[arow0 * 32 + kseg];
    unsigned short* sA1 = &As[arow1 * 32 + kseg];
    unsigned short* sB0 = &Bs[arow0 * 32 + kseg];
    unsigned short* sB1 = &Bs[arow1 * 32 + kseg];
    f32x4 acc[4][4] = {};
    for (int kb = 0; kb < kH; kb += 32) {
        uint4 a0 = pA0 ? *(const uint4*)(pA0 + kb) : make_uint4(0, 0, 0, 0);
        uint4 a1 = pA1 ? *(const uint4*)(pA1 + kb) : make_uint4(0, 0, 0, 0);
        uint4 bv0 = *(const uint4*)(pB0 + kb);
        uint4 bv1 = *(const uint4*)(pB1 + kb);
        __syncthreads();
        *(uint4*)sA0 = a0; *(uint4*)sA1 = a1;
        *(uint4*)sB0 = bv0; *(uint4*)sB1 = bv1;
        __syncthreads();
        bfrag af[4], bf[4];
#pragma unroll
        for (int mi = 0; mi < 4; ++mi)
            af[mi] = *(const bfrag*)&As[(m_off + mi * 16 + lr) * 32 + quad * 8];
#pragma unroll
        for (int ni = 0; ni < 4; ++ni)
            bf[ni] = *(const bfrag*)&Bs[(n_off + ni * 16 + lr) * 32 + quad * 8];
#pragma unroll
        for (int mi = 0; mi < 4; ++mi)
#pragma unroll
            for (int ni = 0; ni < 4; ++ni)
                acc[mi][ni] = __builtin_amdgcn_mfma_f32_16x16x32_bf16(af[mi], bf[ni], acc[mi][ni], 0, 0, 0);
    }
#pragma unroll
    for (int mi = 0; mi < 4; ++mi) {
#pragma unroll
        for (int r = 0; r < 4; ++r) {
            int lslot = m_off + mi * 16 + quad * 4 + r;
            int p = prow[lslot];
            if (p >= 0) {
                float g = sgate[lslot];
                unsigned short* orow = pout + (size_t)p * kD + n0 + n_off + lr;
#pragma unroll
                for (int ni = 0; ni < 4; ++ni)
                    orow[ni * 16] = f2bf(g * (acc[mi][ni][r] + breg[ni]));
            }
        }
    }
}

// ---------- BN: stats without materializing y ----------
__global__ __launch_bounds__(256) void k_colsum(const float* __restrict__ x,
                                                const unsigned short* __restrict__ pout,
                                                float* __restrict__ colsum,
                                                float* __restrict__ colsum2) {
    int d = threadIdx.x;
    int r0 = blockIdx.x * 64;
    float s = 0.f, s2 = 0.f;
    for (int i = 0; i < 64; ++i) {
        int row = r0 + i;
        float v = x[(size_t)row * kD + d]
                + bf2f(pout[(size_t)(2 * row) * kD + d])
                + bf2f(pout[(size_t)(2 * row + 1) * kD + d]);
        s += v; s2 += v * v;
    }
    atomicAdd(&colsum[d], s);
    atomicAdd(&colsum2[d], s2);
}

__global__ void k_bnparams(const float* __restrict__ colsum,
                           const float* __restrict__ colsum2,
                           const float* __restrict__ gamma,
                           const float* __restrict__ beta,
                           float* __restrict__ scale,
                           float* __restrict__ shift) {
    int d = threadIdx.x;
    float mean = colsum[d] * (1.0f / kN);
    float var = colsum2[d] * (1.0f / kN) - mean * mean;
    float inv = rsqrtf(var + 1e-5f);
    float sc = inv * gamma[d];
    scale[d] = sc;
    shift[d] = beta[d] - mean * sc;
}

__global__ __launch_bounds__(256) void k_apply2(const float* __restrict__ x,
                                                const unsigned short* __restrict__ pout,
                                                const float* __restrict__ scale,
                                                const float* __restrict__ shift,
                                                float* __restrict__ out) {
    int i = blockIdx.x * 256 + threadIdx.x;   // float4 index
    size_t g = (size_t)i * 4;
    int row = (int)(g >> 8);
    int d = (int)(g & 255);
    float4 v = *(const float4*)(x + g);
    ushort4 p0 = *(const ushort4*)(pout + (size_t)(2 * row) * kD + d);
    ushort4 p1 = *(const ushort4*)(pout + (size_t)(2 * row + 1) * kD + d);
    v.x += bf2f(p0.x) + bf2f(p1.x);
    v.y += bf2f(p0.y) + bf2f(p1.y);
    v.z += bf2f(p0.z) + bf2f(p1.z);
    v.w += bf2f(p0.w) + bf2f(p1.w);
    float4 sc = *(const float4*)(scale + d);
    float4 sh = *(const float4*)(shift + d);
    v.x = v.x * sc.x + sh.x;
    v.y = v.y * sc.y + sh.y;
    v.z = v.z * sc.z + sh.z;
    v.w = v.w * sc.w + sh.w;
    *(float4*)(out + g) = v;
}

extern "C" void kernel_launch(void* const* d_in, const int* in_sizes, int n_in,
                              void* d_out, int out_size, void* d_ws, size_t ws_size,
                              hipStream_t stream) {
    const float* feats = (const float*)d_in[0];
    const float* Wgc   = (const float*)d_in[1];
    const float* bgc   = (const float*)d_in[2];
    const float* Wres  = (const float*)d_in[3];
    const float* bres  = (const float*)d_in[4];
    const float* Wg    = (const float*)d_in[5];
    const float* bg    = (const float*)d_in[6];
    const float* w1    = (const float*)d_in[7];
    const float* b1    = (const float*)d_in[8];
    const float* w2    = (const float*)d_in[9];
    const float* b2    = (const float*)d_in[10];
    const float* gamma = (const float*)d_in[11];
    const float* beta  = (const float*)d_in[12];
    const int*   src   = (const int*)d_in[13];
    const int*   dst   = (const int*)d_in[14];

    char* ws = (char*)d_ws;
    int*   dego    = (int*)(ws + OFF_DEGO);
    int*   degi    = (int*)(ws + OFF_DEGI);
    int*   cursor  = (int*)(ws + OFF_CURSOR);
    int*   ecount  = (int*)(ws + OFF_ECOUNT);
    int*   ecur    = (int*)(ws + OFF_ECUR);
    float* colsum  = (float*)(ws + OFF_COLSUM);
    float* colsum2 = (float*)(ws + OFF_COLSUM2);
    int*   eoffs   = (int*)(ws + OFF_EOFFS);
    int*   csroff  = (int*)(ws + OFF_CSROFF);
    int*   csrsrc  = (int*)(ws + OFF_CSRSRC);
    int*   plist   = (int*)(ws + OFF_PLIST);
    int*   eidx    = (int*)(ws + OFF_EIDX);
    float* egate   = (float*)(ws + OFF_EGATE);
    float* scale   = (float*)(ws + OFF_SCALE);
    float* shift   = (float*)(ws + OFF_SHIFT);
    float* osc     = (float*)(ws + OFF_OSC);
    float* iscv    = (float*)(ws + OFF_ISC);
    float* Wq1     = (float*)(ws + OFF_WQ1);
    float* Wq2     = (float*)(ws + OFF_WQ2);
    float* bge     = (float*)(ws + OFF_BGE);
    unsigned short* wcat = (unsigned short*)(ws + OFF_WCAT);
    float* mbuf    = (float*)(ws + OFF_M);
    float* xbuf    = (float*)(ws + OFF_X);
    unsigned short* xb   = (unsigned short*)(ws + OFF_XB);
    float* logits  = (float*)(ws + OFF_LOGITS);
    unsigned short* pout = (unsigned short*)(ws + OFF_POUT);
    unsigned short* acat = (unsigned short*)(ws + OFF_POUT);   // alias: dead before moe2 writes pout
    unsigned short* w1t  = (unsigned short*)(ws + OFF_W1T);
    unsigned short* w2t  = (unsigned short*)(ws + OFF_W2T);
    unsigned short* h1b  = (unsigned short*)(ws + OFF_H1B);

    hipMemsetAsync(ws, 0, ZERO_BYTES, stream);

    // weight prep
    k_transpose_cast<<<dim3(kH / 64, kD / 64, kE), 256, 0, stream>>>(w1, w1t, kD, kH, kD, 0);
    k_transpose_cast<<<dim3(kD / 64, kH / 64, kE), 256, 0, stream>>>(w2, w2t, kH, kD, kH, 0);
    k_transpose_cast<<<dim3(kD / 64, kD / 64, 1), 256, 0, stream>>>(Wgc, wcat, kD, kD, 512, 0);
    k_transpose_cast<<<dim3(kD / 64, kD / 64, 1), 256, 0, stream>>>(Wres, wcat, kD, kD, 512, 256);
    k_compose<<<129, 256, 0, stream>>>(Wgc, Wres, Wg, bgc, bres, bg, Wq1, Wq2, bge);
    // graph prep + aggregation
    k_count_deg<<<kEdges / 256, 256, 0, stream>>>(src, dst, dego, degi);
    k_scales<<<kN / 256, 256, 0, stream>>>(dego, degi, osc, iscv);
    k_scan_nodes<<<1, 1024, 0, stream>>>(degi, csroff);
    k_build_csr<<<kEdges / 256, 256, 0, stream>>>(src, dst, csroff, cursor, csrsrc);
    k_aggregate<<<kN, 256, 0, stream>>>(feats, osc, iscv, csroff, csrsrc, mbuf);
    // routing logits from f32 m/feats (composed weights) — precision-critical
    k_gate_comp<<<dim3(1, kN / 64), 256, 0, stream>>>(mbuf, feats, Wq1, Wq2, bge, logits);
    // x via bf16 MFMA
    k_cast_cat<<<dim3(kN * kD / 8 / 256, 2), 256, 0, stream>>>(mbuf, feats, acat);
    k_xgemm_mfma<<<dim3(kD / 128, kN / 128), 256, 0, stream>>>(acat, wcat, bgc, bres, xbuf, xb);
    // gating + MoE
    k_topk<<<kN / 256, 256, 0, stream>>>(logits, eidx, egate, ecount);
    k_scan_experts<<<1, 64, 0, stream>>>(ecount, eoffs);
    k_scatter<<<kPairs / 256, 256, 0, stream>>>(eidx, eoffs, ecur, plist);
    k_moe1_mfma<<<dim3(kH / 128, kCap / 128, kE), 256, 0, stream>>>(xb, w1t, b1, plist, eoffs, ecount, h1b);
    k_moe2_mfma<<<dim3(kD / 128, kCap / 128, kE), 256, 0, stream>>>(h1b, w2t, b2, plist, eoffs, ecount, egate, pout);
    // BN
    k_colsum<<<kN / 64, 256, 0, stream>>>(xbuf, pout, colsum, colsum2);
    k_bnparams<<<1, 256, 0, stream>>>(colsum, colsum2, gamma, beta, scale, shift);
    k_apply2<<<(kN * kD / 4) / 256, 256, 0, stream>>>(xbuf, pout, scale, shift, (float*)d_out);
}

// Round 6
// 414.227 us; speedup vs baseline: 1.7632x; 1.2182x over previous
//
#include <hip/hip_runtime.h>
#include <math.h>

// ---- problem constants ----
static const int kN     = 16384;
static const int kEdges = 262144;
static const int kD     = 256;
static const int kH     = 512;
static const int kE     = 64;
static const int kCap   = 1024;
static const int kPairs = kN * 2;

// ---- workspace layout (bytes) ----
static const size_t OFF_DEGO    = 0;                        // int[16384]
static const size_t OFF_DEGI    = OFF_DEGO + 65536;
static const size_t OFF_CURSOR  = OFF_DEGI + 65536;
static const size_t OFF_ECOUNT  = OFF_CURSOR + 65536;       // int[64]
static const size_t OFF_ECUR    = OFF_ECOUNT + 256;
static const size_t OFF_COLSUM  = OFF_ECUR + 256;           // (unused, kept for layout stability)
static const size_t OFF_COLSUM2 = OFF_COLSUM + 1024;
static const size_t ZERO_BYTES  = OFF_COLSUM2 + 1024;       // 199168
static const size_t OFF_EOFFS   = ZERO_BYTES;               // int[65]
static const size_t OFF_CSROFF  = OFF_EOFFS + 512;          // int[16385]
static const size_t OFF_CSRSRC  = OFF_CSROFF + 65792;       // int[262144]
static const size_t OFF_PLIST   = OFF_CSRSRC + 1048576;     // int[32768]
static const size_t OFF_EIDX    = OFF_PLIST + 131072;       // int[32768]
static const size_t OFF_EGATE   = OFF_EIDX + 131072;        // f32[32768]
static const size_t OFF_SCALE   = OFF_EGATE + 131072;       // f32[256]
static const size_t OFF_SHIFT   = OFF_SCALE + 1024;         // f32[256]
static const size_t OFF_OSC     = OFF_SHIFT + 1024;         // f32[16384]
static const size_t OFF_ISC     = OFF_OSC + 65536;          // f32[16384]
static const size_t OFF_WQ1     = OFF_ISC + 65536;          // f32[256*64]
static const size_t OFF_WQ2     = OFF_WQ1 + 65536;          // f32[256*64]
static const size_t OFF_BGE     = OFF_WQ2 + 65536;          // f32[64]
static const size_t OFF_WCAT    = OFF_BGE + 256;            // bf16[256][512]
static const size_t OFF_M       = OFF_WCAT + 262144;        // f32[16384*256]
static const size_t OFF_X       = OFF_M + 16777216;         // f32[16384*256]
static const size_t OFF_XB      = OFF_X + 16777216;         // bf16[16384*256]
static const size_t OFF_LOGITS  = OFF_XB + 8388608;         // f32[16384*64]
static const size_t OFF_POUT    = OFF_LOGITS + 4194304;     // bf16[32768*256]; ACAT aliases
static const size_t OFF_W1T     = OFF_POUT + 16777216;      // bf16[64*512*256]
static const size_t OFF_W2T     = OFF_W1T + 16777216;       // bf16[64*256*512]
static const size_t OFF_H1B     = OFF_W2T + 16777216;       // bf16[32768*512]
static const size_t OFF_PART1   = OFF_H1B + 33554432;       // f32[256*256] per-block col sums
static const size_t OFF_PART2   = OFF_PART1 + 262144;       // f32[256*256]
// end ~132.8 MB (≤ round-2's proven 137 MB)

typedef __bf16 bfrag __attribute__((ext_vector_type(8)));
typedef float f32x4 __attribute__((ext_vector_type(4)));

// tanh-form gelu: max |err| vs exact-erf gelu ~3e-4 (<< bf16 rounding of h1)
__device__ __forceinline__ float gelu_f(float v) {
    float u = v * (0.7978845608f + 0.0356774081f * v * v);
    float t = __expf(-2.0f * fabsf(u));
    float th = (1.0f - t) * __builtin_amdgcn_rcpf(1.0f + t);
    th = copysignf(th, u);
    return 0.5f * v * (1.0f + th);
}
__device__ __forceinline__ unsigned short f2bf(float f) {
    union { float f; unsigned int u; } v; v.f = f;
    unsigned int u = v.u;
    unsigned int r = (u + 0x7FFFu + ((u >> 16) & 1u)) >> 16;   // RNE
    return (unsigned short)r;
}
__device__ __forceinline__ float bf2f(unsigned short s) {
    union { unsigned int u; float f; } v; v.u = ((unsigned int)s) << 16;
    return v.f;
}

// ---------- graph preprocessing ----------
__global__ __launch_bounds__(256) void k_count_deg(const int* __restrict__ src,
                                                   const int* __restrict__ dst,
                                                   int* __restrict__ dego,
                                                   int* __restrict__ degi) {
    int i = blockIdx.x * 256 + threadIdx.x;
    if (i < kEdges) {
        atomicAdd(&dego[src[i]], 1);
        atomicAdd(&degi[dst[i]], 1);
    }
}

__global__ __launch_bounds__(256) void k_scales(const int* __restrict__ dego,
                                                const int* __restrict__ degi,
                                                float* __restrict__ osc,
                                                float* __restrict__ isc) {
    int i = blockIdx.x * 256 + threadIdx.x;
    int a = dego[i]; if (a < 1) a = 1;
    int b = degi[i]; if (b < 1) b = 1;
    osc[i] = rsqrtf((float)a);
    isc[i] = rsqrtf((float)b);
}

__global__ __launch_bounds__(1024) void k_scan_nodes(const int* __restrict__ degi,
                                                     int* __restrict__ offs) {
    __shared__ int sums[1024];
    int t = threadIdx.x;
    int base = t * 16;
    int loc[16];
    int s = 0;
#pragma unroll
    for (int i = 0; i < 16; ++i) { loc[i] = degi[base + i]; s += loc[i]; }
    sums[t] = s;
    __syncthreads();
    for (int off = 1; off < 1024; off <<= 1) {
        int v = (t >= off) ? sums[t - off] : 0;
        __syncthreads();
        sums[t] += v;
        __syncthreads();
    }
    int run = sums[t] - s;
#pragma unroll
    for (int i = 0; i < 16; ++i) { offs[base + i] = run; run += loc[i]; }
    if (t == 1023) offs[kN] = run;
}

__global__ __launch_bounds__(256) void k_build_csr(const int* __restrict__ src,
                                                   const int* __restrict__ dst,
                                                   const int* __restrict__ offs,
                                                   int* __restrict__ cursor,
                                                   int* __restrict__ csr_src) {
    int i = blockIdx.x * 256 + threadIdx.x;
    if (i < kEdges) {
        int d = dst[i];
        int pos = atomicAdd(&cursor[d], 1);
        csr_src[offs[d] + pos] = src[i];
    }
}

// one node per block; 4 waves process 4 edges concurrently, float4 cols
__global__ __launch_bounds__(256) void k_aggregate(const float* __restrict__ feats,
                                                   const float* __restrict__ osc,
                                                   const float* __restrict__ isc,
                                                   const int* __restrict__ offs,
                                                   const int* __restrict__ csr_src,
                                                   float* __restrict__ m) {
    __shared__ f32x4 red[256];
    int n = blockIdx.x;
    int t = threadIdx.x;
    int c4 = (t & 63) * 4;
    int es = t >> 6;
    int beg = offs[n], end = offs[n + 1];
    f32x4 acc = {0.f, 0.f, 0.f, 0.f};
    for (int i = beg + es; i < end; i += 4) {
        int s = csr_src[i];
        float sc = osc[s];
        const float4 v = *(const float4*)(feats + (size_t)s * kD + c4);
        acc[0] += v.x * sc; acc[1] += v.y * sc;
        acc[2] += v.z * sc; acc[3] += v.w * sc;
    }
    red[t] = acc;
    __syncthreads();
    if (t < 64) {
        f32x4 a = red[t], b = red[t + 64], c = red[t + 128], d = red[t + 192];
        float si = isc[n];
        float4 o;
        o.x = (a[0] + b[0] + c[0] + d[0]) * si;
        o.y = (a[1] + b[1] + c[1] + d[1]) * si;
        o.z = (a[2] + b[2] + c[2] + d[2]) * si;
        o.w = (a[3] + b[3] + c[3] + d[3]) * si;
        *(float4*)(m + (size_t)n * kD + c4) = o;
    }
}

// ---------- composed gate weights ----------
__global__ __launch_bounds__(256) void k_compose(const float* __restrict__ Wgc,
                                                 const float* __restrict__ Wres,
                                                 const float* __restrict__ Wg,
                                                 const float* __restrict__ bgc,
                                                 const float* __restrict__ bres,
                                                 const float* __restrict__ bg,
                                                 float* __restrict__ Wq1,
                                                 float* __restrict__ Wq2,
                                                 float* __restrict__ bge) {
    int tid = blockIdx.x * 256 + threadIdx.x;
    if (tid < 2 * kD * kE) {
        int mat = tid >> 14;
        int rem = tid & 16383;
        int d = rem >> 6, e = rem & 63;
        const float* A = mat ? Wres : Wgc;
        float acc = 0.f;
        for (int c = 0; c < kD; ++c)
            acc = fmaf(A[d * kD + c], Wg[c * kE + e], acc);
        (mat ? Wq2 : Wq1)[d * kE + e] = acc;
    } else if (tid < 2 * kD * kE + kE) {
        int e = tid - 2 * kD * kE;
        float acc = bg[e];
        for (int d = 0; d < kD; ++d)
            acc = fmaf(bgc[d] + bres[d], Wg[d * kE + e], acc);
        bge[e] = acc;
    }
}

// logits = m@Wq1 + feats@Wq2 + bge  (f32 — routing-accuracy-critical)
#define FMA16()                                                                         \
    acc[0][0]=fmaf(a.x,b.x,acc[0][0]); acc[0][1]=fmaf(a.x,b.y,acc[0][1]);               \
    acc[0][2]=fmaf(a.x,b.z,acc[0][2]); acc[0][3]=fmaf(a.x,b.w,acc[0][3]);               \
    acc[1][0]=fmaf(a.y,b.x,acc[1][0]); acc[1][1]=fmaf(a.y,b.y,acc[1][1]);               \
    acc[1][2]=fmaf(a.y,b.z,acc[1][2]); acc[1][3]=fmaf(a.y,b.w,acc[1][3]);               \
    acc[2][0]=fmaf(a.z,b.x,acc[2][0]); acc[2][1]=fmaf(a.z,b.y,acc[2][1]);               \
    acc[2][2]=fmaf(a.z,b.z,acc[2][2]); acc[2][3]=fmaf(a.z,b.w,acc[2][3]);               \
    acc[3][0]=fmaf(a.w,b.x,acc[3][0]); acc[3][1]=fmaf(a.w,b.y,acc[3][1]);               \
    acc[3][2]=fmaf(a.w,b.z,acc[3][2]); acc[3][3]=fmaf(a.w,b.w,acc[3][3]);

__global__ __launch_bounds__(256) void k_gate_comp(const float* __restrict__ m,
                                                   const float* __restrict__ feats,
                                                   const float* __restrict__ Wq1,
                                                   const float* __restrict__ Wq2,
                                                   const float* __restrict__ bge,
                                                   float* __restrict__ logits) {
    __shared__ float As[32][68];
    __shared__ float Bs[32][68];
    const int t = threadIdx.x;
    const int tx = t & 15, ty = t >> 4;
    const int m0 = blockIdx.y * 64;
    float acc[4][4] = {};
    for (int pass = 0; pass < 2; ++pass) {
        const float* A = pass ? feats : m;
        const float* B = pass ? Wq2 : Wq1;
        for (int kb = 0; kb < kD; kb += 32) {
            __syncthreads();
#pragma unroll
            for (int i = 0; i < 2; ++i) {
                int fidx = i * 256 + t;
                int r = fidx >> 3, k4 = fidx & 7;
                float4 v = *(const float4*)(A + (size_t)(m0 + r) * kD + kb + k4 * 4);
                As[k4 * 4 + 0][r] = v.x; As[k4 * 4 + 1][r] = v.y;
                As[k4 * 4 + 2][r] = v.z; As[k4 * 4 + 3][r] = v.w;
            }
#pragma unroll
            for (int i = 0; i < 2; ++i) {
                int fidx = i * 256 + t;
                int kk = fidx >> 4, c4 = fidx & 15;
                float4 v = *(const float4*)(B + (size_t)(kb + kk) * kE + c4 * 4);
                *(float4*)&Bs[kk][c4 * 4] = v;
            }
            __syncthreads();
#pragma unroll
            for (int kk = 0; kk < 32; ++kk) {
                float4 a = *(const float4*)&As[kk][ty * 4];
                float4 b = *(const float4*)&Bs[kk][tx * 4];
                FMA16();
            }
        }
    }
    int col0 = tx * 4;
    float4 bb = *(const float4*)(bge + col0);
#pragma unroll
    for (int i = 0; i < 4; ++i) {
        int row = m0 + ty * 4 + i;
        float4 o;
        o.x = acc[i][0] + bb.x; o.y = acc[i][1] + bb.y;
        o.z = acc[i][2] + bb.z; o.w = acc[i][3] + bb.w;
        *(float4*)(logits + (size_t)row * kE + col0) = o;
    }
}

// Acat[t][0:256]=bf16(m[t]); Acat[t][256:512]=bf16(feats[t])
__global__ __launch_bounds__(256) void k_cast_cat(const float* __restrict__ m,
                                                  const float* __restrict__ feats,
                                                  unsigned short* __restrict__ acat) {
    int i = blockIdx.x * 256 + threadIdx.x;
    const float* srcp = blockIdx.y ? feats : m;
    int doff = blockIdx.y ? 256 : 0;
    size_t g = (size_t)i * 8;
    int tok = (int)(g >> 8), d = (int)(g & 255);
    float4 a = *(const float4*)(srcp + g);
    float4 b = *(const float4*)(srcp + g + 4);
    ushort4 o0, o1;
    o0.x = f2bf(a.x); o0.y = f2bf(a.y); o0.z = f2bf(a.z); o0.w = f2bf(a.w);
    o1.x = f2bf(b.x); o1.y = f2bf(b.y); o1.z = f2bf(b.z); o1.w = f2bf(b.w);
    unsigned short* dstp = acat + (size_t)tok * 512 + doff + d;
    *(ushort4*)dstp = o0;
    *(ushort4*)(dstp + 4) = o1;
}

// transpose+cast: w [e][R][C] f32 -> wt[(c)*dstride + doff + r] bf16
__global__ __launch_bounds__(256) void k_transpose_cast(const float* __restrict__ w,
                                                        unsigned short* __restrict__ wt,
                                                        int R, int C, int dstride, int doff) {
    __shared__ unsigned short tile[64][65];
    int e = blockIdx.z;
    const float* W = w + (size_t)e * R * C;
    unsigned short* WT = wt + (size_t)e * R * C;
    int r0 = blockIdx.y * 64, c0 = blockIdx.x * 64;
    int t = threadIdx.x;
#pragma unroll
    for (int i = 0; i < 4; ++i) {
        int idx = i * 256 + t;
        int r = idx >> 4, c4 = idx & 15;
        float4 v = *(const float4*)(W + (size_t)(r0 + r) * C + c0 + c4 * 4);
        tile[r][c4 * 4 + 0] = f2bf(v.x); tile[r][c4 * 4 + 1] = f2bf(v.y);
        tile[r][c4 * 4 + 2] = f2bf(v.z); tile[r][c4 * 4 + 3] = f2bf(v.w);
    }
    __syncthreads();
#pragma unroll
    for (int i = 0; i < 4; ++i) {
        int idx = i * 256 + t;
        int c = idx >> 4, r4 = idx & 15;
        ushort4 o;
        o.x = tile[r4 * 4 + 0][c]; o.y = tile[r4 * 4 + 1][c];
        o.z = tile[r4 * 4 + 2][c]; o.w = tile[r4 * 4 + 3][c];
        *(ushort4*)(WT + (size_t)(c0 + c) * dstride + doff + r0 + r4 * 4) = o;
    }
}

// ---------- x = [m|feats] @ [Wgc;Wres]^T + bias (bf16 MFMA, K=512) ----------
__global__ __launch_bounds__(256) void k_xgemm_mfma(const unsigned short* __restrict__ acat,
                                                    const unsigned short* __restrict__ wcat,
                                                    const float* __restrict__ bgc,
                                                    const float* __restrict__ bres,
                                                    float* __restrict__ x,
                                                    unsigned short* __restrict__ xb) {
    __shared__ unsigned short As[128 * 32];
    __shared__ unsigned short Bs[128 * 32];
    const int t = threadIdx.x;
    const int m0 = blockIdx.y * 128;
    const int n0 = blockIdx.x * 128;
    const int lane = t & 63, w = t >> 6;
    const int m_off = (w & 1) * 64, n_off = (w >> 1) * 64;
    const int quad = lane >> 4, lr = lane & 15;
    float breg[4];
#pragma unroll
    for (int ni = 0; ni < 4; ++ni) {
        int col = n0 + n_off + ni * 16 + lr;
        breg[ni] = bgc[col] + bres[col];
    }
    const int arow0 = t >> 2, arow1 = 64 + (t >> 2);
    const int kseg = (t & 3) * 8;
    const unsigned short* pA0 = acat + (size_t)(m0 + arow0) * 512 + kseg;
    const unsigned short* pA1 = acat + (size_t)(m0 + arow1) * 512 + kseg;
    const unsigned short* pB0 = wcat + (size_t)(n0 + arow0) * 512 + kseg;
    const unsigned short* pB1 = wcat + (size_t)(n0 + arow1) * 512 + kseg;
    unsigned short* sA0 = &As[arow0 * 32 + kseg];
    unsigned short* sA1 = &As[arow1 * 32 + kseg];
    unsigned short* sB0 = &Bs[arow0 * 32 + kseg];
    unsigned short* sB1 = &Bs[arow1 * 32 + kseg];
    f32x4 acc[4][4] = {};
    for (int kb = 0; kb < 512; kb += 32) {
        uint4 a0 = *(const uint4*)(pA0 + kb);
        uint4 a1 = *(const uint4*)(pA1 + kb);
        uint4 bv0 = *(const uint4*)(pB0 + kb);
        uint4 bv1 = *(const uint4*)(pB1 + kb);
        __syncthreads();
        *(uint4*)sA0 = a0; *(uint4*)sA1 = a1;
        *(uint4*)sB0 = bv0; *(uint4*)sB1 = bv1;
        __syncthreads();
        bfrag af[4], bf[4];
#pragma unroll
        for (int mi = 0; mi < 4; ++mi)
            af[mi] = *(const bfrag*)&As[(m_off + mi * 16 + lr) * 32 + quad * 8];
#pragma unroll
        for (int ni = 0; ni < 4; ++ni)
            bf[ni] = *(const bfrag*)&Bs[(n_off + ni * 16 + lr) * 32 + quad * 8];
#pragma unroll
        for (int mi = 0; mi < 4; ++mi)
#pragma unroll
            for (int ni = 0; ni < 4; ++ni)
                acc[mi][ni] = __builtin_amdgcn_mfma_f32_16x16x32_bf16(af[mi], bf[ni], acc[mi][ni], 0, 0, 0);
    }
#pragma unroll
    for (int mi = 0; mi < 4; ++mi) {
#pragma unroll
        for (int r = 0; r < 4; ++r) {
            int row = m0 + m_off + mi * 16 + quad * 4 + r;
            float* xrow = x + (size_t)row * kD + n0 + n_off + lr;
            unsigned short* xbrow = xb + (size_t)row * kD + n0 + n_off + lr;
#pragma unroll
            for (int ni = 0; ni < 4; ++ni) {
                float v = acc[mi][ni][r] + breg[ni];
                xrow[ni * 16] = v;
                xbrow[ni * 16] = f2bf(v);
            }
        }
    }
}

// ---------- gating: top-2 + softmax; LDS histogram to kill atomic chains ----------
__global__ __launch_bounds__(256) void k_topk(const float* __restrict__ logits,
                                              int* __restrict__ eidx,
                                              float* __restrict__ egate,
                                              int* __restrict__ ecount) {
    __shared__ int hist[kE];
    int t = threadIdx.x;
    int n = blockIdx.x * 256 + t;
    if (t < kE) hist[t] = 0;
    __syncthreads();
    const float* row = logits + (size_t)n * kE;
    float v0 = -3.4e38f, v1 = -3.4e38f;
    int i0 = 0, i1 = 0;
    for (int e4 = 0; e4 < kE; e4 += 4) {
        float4 vv = *(const float4*)(row + e4);
        float vs[4] = {vv.x, vv.y, vv.z, vv.w};
#pragma unroll
        for (int j = 0; j < 4; ++j) {
            float v = vs[j];
            int e = e4 + j;
            if (v > v0) { v1 = v0; i1 = i0; v0 = v; i0 = e; }
            else if (v > v1) { v1 = v; i1 = e; }
        }
    }
    float ex = expf(v1 - v0);
    float g0 = 1.0f / (1.0f + ex);
    float g1 = ex * g0;
    eidx[2 * n] = i0; eidx[2 * n + 1] = i1;
    egate[2 * n] = g0; egate[2 * n + 1] = g1;
    atomicAdd(&hist[i0], 1);
    atomicAdd(&hist[i1], 1);
    __syncthreads();
    if (t < kE) {
        int c = hist[t];
        if (c > 0) atomicAdd(&ecount[t], c);
    }
}

__global__ void k_scan_experts(const int* __restrict__ ecount, int* __restrict__ eoffs) {
    if (threadIdx.x == 0) {
        int s = 0;
        for (int e = 0; e < kE; ++e) { eoffs[e] = s; s += ecount[e]; }
        eoffs[kE] = s;
    }
}

// hierarchical scatter: LDS count -> one reserving atomic per (block,expert) -> LDS-ranked write
__global__ __launch_bounds__(256) void k_scatter(const int* __restrict__ eidx,
                                                 const int* __restrict__ eoffs,
                                                 int* __restrict__ ecur,
                                                 int* __restrict__ plist) {
    __shared__ int lh[kE];
    __shared__ int gbase[kE];
    int t = threadIdx.x;
    int p0 = blockIdx.x * 512 + t;       // pairs p0 and p0+256
    if (t < kE) lh[t] = 0;
    __syncthreads();
    int e0 = eidx[p0], e1 = eidx[p0 + 256];
    atomicAdd(&lh[e0], 1);
    atomicAdd(&lh[e1], 1);
    __syncthreads();
    if (t < kE) {
        int c = lh[t];
        int b = (c > 0) ? atomicAdd(&ecur[t], c) : 0;
        gbase[t] = eoffs[t] + b;
        lh[t] = 0;
    }
    __syncthreads();
    int r0 = atomicAdd(&lh[e0], 1);
    int r1 = atomicAdd(&lh[e1], 1);
    plist[gbase[e0] + r0] = p0;
    plist[gbase[e1] + r1] = p0 + 256;
}

// ---------- MoE MFMA GEMMs ----------
__global__ __launch_bounds__(256) void k_moe1_mfma(const unsigned short* __restrict__ xb,
                                                   const unsigned short* __restrict__ w1t,
                                                   const float* __restrict__ b1,
                                                   const int* __restrict__ plist,
                                                   const int* __restrict__ eoffs,
                                                   const int* __restrict__ ecount,
                                                   unsigned short* __restrict__ h1b) {
    __shared__ unsigned short As[128 * 32];
    __shared__ unsigned short Bs[128 * 32];
    __shared__ int rowtok[128];
    const int e = blockIdx.z;
    int cnt = ecount[e]; if (cnt > kCap) cnt = kCap;
    const int m0 = blockIdx.y * 128;
    if (m0 >= cnt) return;
    const int n0 = blockIdx.x * 128;
    const int base = eoffs[e];
    const int t = threadIdx.x;
    if (t < 128) {
        int slot = m0 + t;
        rowtok[t] = (slot < cnt) ? (plist[base + slot] >> 1) : -1;
    }
    const int lane = t & 63, w = t >> 6;
    const int m_off = (w & 1) * 64, n_off = (w >> 1) * 64;
    const int quad = lane >> 4, lr = lane & 15;
    const unsigned short* Bbase = w1t + (size_t)e * kH * kD;
    float breg[4];
#pragma unroll
    for (int ni = 0; ni < 4; ++ni) breg[ni] = b1[e * kH + n0 + n_off + ni * 16 + lr];
    const int arow0 = t >> 2, arow1 = 64 + (t >> 2);
    const int kseg = (t & 3) * 8;
    __syncthreads();
    const int tok0 = rowtok[arow0], tok1 = rowtok[arow1];
    const unsigned short* pA0 = (tok0 >= 0) ? xb + (size_t)tok0 * kD + kseg : nullptr;
    const unsigned short* pA1 = (tok1 >= 0) ? xb + (size_t)tok1 * kD + kseg : nullptr;
    const unsigned short* pB0 = Bbase + (size_t)(n0 + arow0) * kD + kseg;
    const unsigned short* pB1 = Bbase + (size_t)(n0 + arow1) * kD + kseg;
    unsigned short* sA0 = &As[arow0 * 32 + kseg];
    unsigned short* sA1 = &As[arow1 * 32 + kseg];
    unsigned short* sB0 = &Bs[arow0 * 32 + kseg];
    unsigned short* sB1 = &Bs[arow1 * 32 + kseg];
    f32x4 acc[4][4] = {};
    for (int kb = 0; kb < kD; kb += 32) {
        uint4 a0 = pA0 ? *(const uint4*)(pA0 + kb) : make_uint4(0, 0, 0, 0);
        uint4 a1 = pA1 ? *(const uint4*)(pA1 + kb) : make_uint4(0, 0, 0, 0);
        uint4 bv0 = *(const uint4*)(pB0 + kb);
        uint4 bv1 = *(const uint4*)(pB1 + kb);
        __syncthreads();
        *(uint4*)sA0 = a0; *(uint4*)sA1 = a1;
        *(uint4*)sB0 = bv0; *(uint4*)sB1 = bv1;
        __syncthreads();
        bfrag af[4], bf[4];
#pragma unroll
        for (int mi = 0; mi < 4; ++mi)
            af[mi] = *(const bfrag*)&As[(m_off + mi * 16 + lr) * 32 + quad * 8];
#pragma unroll
        for (int ni = 0; ni < 4; ++ni)
            bf[ni] = *(const bfrag*)&Bs[(n_off + ni * 16 + lr) * 32 + quad * 8];
#pragma unroll
        for (int mi = 0; mi < 4; ++mi)
#pragma unroll
            for (int ni = 0; ni < 4; ++ni)
                acc[mi][ni] = __builtin_amdgcn_mfma_f32_16x16x32_bf16(af[mi], bf[ni], acc[mi][ni], 0, 0, 0);
    }
#pragma unroll
    for (int mi = 0; mi < 4; ++mi) {
#pragma unroll
        for (int r = 0; r < 4; ++r) {
            int slot = m0 + m_off + mi * 16 + quad * 4 + r;
            if (slot < cnt) {
                unsigned short* orow = h1b + (size_t)(base + slot) * kH + n0 + n_off + lr;
#pragma unroll
                for (int ni = 0; ni < 4; ++ni)
                    orow[ni * 16] = f2bf(gelu_f(acc[mi][ni][r] + breg[ni]));
            }
        }
    }
}

__global__ __launch_bounds__(256) void k_moe2_mfma(const unsigned short* __restrict__ h1b,
                                                   const unsigned short* __restrict__ w2t,
                                                   const float* __restrict__ b2,
                                                   const int* __restrict__ plist,
                                                   const int* __restrict__ eoffs,
                                                   const int* __restrict__ ecount,
                                                   const float* __restrict__ egate,
                                                   unsigned short* __restrict__ pout) {
    __shared__ unsigned short As[128 * 32];
    __shared__ unsigned short Bs[128 * 32];
    __shared__ int prow[128];
    __shared__ float sgate[128];
    const int e = blockIdx.z;
    int cnt = ecount[e]; if (cnt > kCap) cnt = kCap;
    const int m0 = blockIdx.y * 128;
    if (m0 >= cnt) return;
    const int n0 = blockIdx.x * 128;
    const int base = eoffs[e];
    const int t = threadIdx.x;
    if (t < 128) {
        int slot = m0 + t;
        int p = (slot < cnt) ? plist[base + slot] : -1;
        prow[t] = p;
        sgate[t] = (p >= 0) ? egate[p] : 0.f;
    }
    const int lane = t & 63, w = t >> 6;
    const int m_off = (w & 1) * 64, n_off = (w >> 1) * 64;
    const int quad = lane >> 4, lr = lane & 15;
    const unsigned short* Bbase = w2t + (size_t)e * kD * kH;
    float breg[4];
#pragma unroll
    for (int ni = 0; ni < 4; ++ni) breg[ni] = b2[e * kD + n0 + n_off + ni * 16 + lr];
    const int arow0 = t >> 2, arow1 = 64 + (t >> 2);
    const int kseg = (t & 3) * 8;
    int aslot0 = m0 + arow0, aslot1 = m0 + arow1;
    const unsigned short* pA0 = (aslot0 < cnt) ? h1b + (size_t)(base + aslot0) * kH + kseg : nullptr;
    const unsigned short* pA1 = (aslot1 < cnt) ? h1b + (size_t)(base + aslot1) * kH + kseg : nullptr;
    const unsigned short* pB0 = Bbase + (size_t)(n0 + arow0) * kH + kseg;
    const unsigned short* pB1 = Bbase + (size_t)(n0 + arow1) * kH + kseg;
    unsigned short* sA0 = &As[arow0 * 32 + kseg];
    unsigned short* sA1 = &As[arow1 * 32 + kseg];
    unsigned short* sB0 = &Bs[arow0 * 32 + kseg];
    unsigned short* sB1 = &Bs[arow1 * 32 + kseg];
    f32x4 acc[4][4] = {};
    for (int kb = 0; kb < kH; kb += 32) {
        uint4 a0 = pA0 ? *(const uint4*)(pA0 + kb) : make_uint4(0, 0, 0, 0);
        uint4 a1 = pA1 ? *(const uint4*)(pA1 + kb) : make_uint4(0, 0, 0, 0);
        uint4 bv0 = *(const uint4*)(pB0 + kb);
        uint4 bv1 = *(const uint4*)(pB1 + kb);
        __syncthreads();
        *(uint4*)sA0 = a0; *(uint4*)sA1 = a1;
        *(uint4*)sB0 = bv0; *(uint4*)sB1 = bv1;
        __syncthreads();
        bfrag af[4], bf[4];
#pragma unroll
        for (int mi = 0; mi < 4; ++mi)
            af[mi] = *(const bfrag*)&As[(m_off + mi * 16 + lr) * 32 + quad * 8];
#pragma unroll
        for (int ni = 0; ni < 4; ++ni)
            bf[ni] = *(const bfrag*)&Bs[(n_off + ni * 16 + lr) * 32 + quad * 8];
#pragma unroll
        for (int mi = 0; mi < 4; ++mi)
#pragma unroll
            for (int ni = 0; ni < 4; ++ni)
                acc[mi][ni] = __builtin_amdgcn_mfma_f32_16x16x32_bf16(af[mi], bf[ni], acc[mi][ni], 0, 0, 0);
    }
#pragma unroll
    for (int mi = 0; mi < 4; ++mi) {
#pragma unroll
        for (int r = 0; r < 4; ++r) {
            int lslot = m_off + mi * 16 + quad * 4 + r;
            int p = prow[lslot];
            if (p >= 0) {
                float g = sgate[lslot];
                unsigned short* orow = pout + (size_t)p * kD + n0 + n_off + lr;
#pragma unroll
                for (int ni = 0; ni < 4; ++ni)
                    orow[ni * 16] = f2bf(g * (acc[mi][ni][r] + breg[ni]));
            }
        }
    }
}

// ---------- BN: per-block partials (no atomics), reduce in k_bnparams ----------
__global__ __launch_bounds__(256) void k_colsum(const float* __restrict__ x,
                                                const unsigned short* __restrict__ pout,
                                                float* __restrict__ part1,
                                                float* __restrict__ part2) {
    int d = threadIdx.x;
    int r0 = blockIdx.x * 64;
    float s = 0.f, s2 = 0.f;
    for (int i = 0; i < 64; ++i) {
        int row = r0 + i;
        float v = x[(size_t)row * kD + d]
                + bf2f(pout[(size_t)(2 * row) * kD + d])
                + bf2f(pout[(size_t)(2 * row + 1) * kD + d]);
        s += v; s2 += v * v;
    }
    part1[blockIdx.x * kD + d] = s;
    part2[blockIdx.x * kD + d] = s2;
}

__global__ void k_bnparams(const float* __restrict__ part1,
                           const float* __restrict__ part2,
                           const float* __restrict__ gamma,
                           const float* __restrict__ beta,
                           float* __restrict__ scale,
                           float* __restrict__ shift) {
    int d = threadIdx.x;
    float s = 0.f, s2 = 0.f;
    for (int b = 0; b < 256; ++b) {
        s += part1[b * kD + d];
        s2 += part2[b * kD + d];
    }
    float mean = s * (1.0f / kN);
    float var = s2 * (1.0f / kN) - mean * mean;
    float inv = rsqrtf(var + 1e-5f);
    float sc = inv * gamma[d];
    scale[d] = sc;
    shift[d] = beta[d] - mean * sc;
}

__global__ __launch_bounds__(256) void k_apply2(const float* __restrict__ x,
                                                const unsigned short* __restrict__ pout,
                                                const float* __restrict__ scale,
                                                const float* __restrict__ shift,
                                                float* __restrict__ out) {
    int i = blockIdx.x * 256 + threadIdx.x;
    size_t g = (size_t)i * 4;
    int row = (int)(g >> 8);
    int d = (int)(g & 255);
    float4 v = *(const float4*)(x + g);
    ushort4 p0 = *(const ushort4*)(pout + (size_t)(2 * row) * kD + d);
    ushort4 p1 = *(const ushort4*)(pout + (size_t)(2 * row + 1) * kD + d);
    v.x += bf2f(p0.x) + bf2f(p1.x);
    v.y += bf2f(p0.y) + bf2f(p1.y);
    v.z += bf2f(p0.z) + bf2f(p1.z);
    v.w += bf2f(p0.w) + bf2f(p1.w);
    float4 sc = *(const float4*)(scale + d);
    float4 sh = *(const float4*)(shift + d);
    v.x = v.x * sc.x + sh.x;
    v.y = v.y * sc.y + sh.y;
    v.z = v.z * sc.z + sh.z;
    v.w = v.w * sc.w + sh.w;
    *(float4*)(out + g) = v;
}

extern "C" void kernel_launch(void* const* d_in, const int* in_sizes, int n_in,
                              void* d_out, int out_size, void* d_ws, size_t ws_size,
                              hipStream_t stream) {
    const float* feats = (const float*)d_in[0];
    const float* Wgc   = (const float*)d_in[1];
    const float* bgc   = (const float*)d_in[2];
    const float* Wres  = (const float*)d_in[3];
    const float* bres  = (const float*)d_in[4];
    const float* Wg    = (const float*)d_in[5];
    const float* bg    = (const float*)d_in[6];
    const float* w1    = (const float*)d_in[7];
    const float* b1    = (const float*)d_in[8];
    const float* w2    = (const float*)d_in[9];
    const float* b2    = (const float*)d_in[10];
    const float* gamma = (const float*)d_in[11];
    const float* beta  = (const float*)d_in[12];
    const int*   src   = (const int*)d_in[13];
    const int*   dst   = (const int*)d_in[14];

    char* ws = (char*)d_ws;
    int*   dego    = (int*)(ws + OFF_DEGO);
    int*   degi    = (int*)(ws + OFF_DEGI);
    int*   cursor  = (int*)(ws + OFF_CURSOR);
    int*   ecount  = (int*)(ws + OFF_ECOUNT);
    int*   ecur    = (int*)(ws + OFF_ECUR);
    int*   eoffs   = (int*)(ws + OFF_EOFFS);
    int*   csroff  = (int*)(ws + OFF_CSROFF);
    int*   csrsrc  = (int*)(ws + OFF_CSRSRC);
    int*   plist   = (int*)(ws + OFF_PLIST);
    int*   eidx    = (int*)(ws + OFF_EIDX);
    float* egate   = (float*)(ws + OFF_EGATE);
    float* scale   = (float*)(ws + OFF_SCALE);
    float* shift   = (float*)(ws + OFF_SHIFT);
    float* osc     = (float*)(ws + OFF_OSC);
    float* iscv    = (float*)(ws + OFF_ISC);
    float* Wq1     = (float*)(ws + OFF_WQ1);
    float* Wq2     = (float*)(ws + OFF_WQ2);
    float* bge     = (float*)(ws + OFF_BGE);
    unsigned short* wcat = (unsigned short*)(ws + OFF_WCAT);
    float* mbuf    = (float*)(ws + OFF_M);
    float* xbuf    = (float*)(ws + OFF_X);
    unsigned short* xb   = (unsigned short*)(ws + OFF_XB);
    float* logits  = (float*)(ws + OFF_LOGITS);
    unsigned short* pout = (unsigned short*)(ws + OFF_POUT);
    unsigned short* acat = (unsigned short*)(ws + OFF_POUT);   // alias: dead before moe2
    unsigned short* w1t  = (unsigned short*)(ws + OFF_W1T);
    unsigned short* w2t  = (unsigned short*)(ws + OFF_W2T);
    unsigned short* h1b  = (unsigned short*)(ws + OFF_H1B);
    float* part1   = (float*)(ws + OFF_PART1);
    float* part2   = (float*)(ws + OFF_PART2);

    hipMemsetAsync(ws, 0, ZERO_BYTES, stream);

    // weight prep
    k_transpose_cast<<<dim3(kH / 64, kD / 64, kE), 256, 0, stream>>>(w1, w1t, kD, kH, kD, 0);
    k_transpose_cast<<<dim3(kD / 64, kH / 64, kE), 256, 0, stream>>>(w2, w2t, kH, kD, kH, 0);
    k_transpose_cast<<<dim3(kD / 64, kD / 64, 1), 256, 0, stream>>>(Wgc, wcat, kD, kD, 512, 0);
    k_transpose_cast<<<dim3(kD / 64, kD / 64, 1), 256, 0, stream>>>(Wres, wcat, kD, kD, 512, 256);
    k_compose<<<129, 256, 0, stream>>>(Wgc, Wres, Wg, bgc, bres, bg, Wq1, Wq2, bge);
    // graph prep + aggregation
    k_count_deg<<<kEdges / 256, 256, 0, stream>>>(src, dst, dego, degi);
    k_scales<<<kN / 256, 256, 0, stream>>>(dego, degi, osc, iscv);
    k_scan_nodes<<<1, 1024, 0, stream>>>(degi, csroff);
    k_build_csr<<<kEdges / 256, 256, 0, stream>>>(src, dst, csroff, cursor, csrsrc);
    k_aggregate<<<kN, 256, 0, stream>>>(feats, osc, iscv, csroff, csrsrc, mbuf);
    // routing logits (f32, composed weights)
    k_gate_comp<<<dim3(1, kN / 64), 256, 0, stream>>>(mbuf, feats, Wq1, Wq2, bge, logits);
    // x via bf16 MFMA
    k_cast_cat<<<dim3(kN * kD / 8 / 256, 2), 256, 0, stream>>>(mbuf, feats, acat);
    k_xgemm_mfma<<<dim3(kD / 128, kN / 128), 256, 0, stream>>>(acat, wcat, bgc, bres, xbuf, xb);
    // gating + MoE
    k_topk<<<kN / 256, 256, 0, stream>>>(logits, eidx, egate, ecount);
    k_scan_experts<<<1, 64, 0, stream>>>(ecount, eoffs);
    k_scatter<<<kPairs / 512, 256, 0, stream>>>(eidx, eoffs, ecur, plist);
    k_moe1_mfma<<<dim3(kH / 128, kCap / 128, kE), 256, 0, stream>>>(xb, w1t, b1, plist, eoffs, ecount, h1b);
    k_moe2_mfma<<<dim3(kD / 128, kCap / 128, kE), 256, 0, stream>>>(h1b, w2t, b2, plist, eoffs, ecount, egate, pout);
    // BN
    k_colsum<<<kN / 64, 256, 0, stream>>>(xbuf, pout, part1, part2);
    k_bnparams<<<1, 256, 0, stream>>>(part1, part2, gamma, beta, scale, shift);
    k_apply2<<<(kN * kD / 4) / 256, 256, 0, stream>>>(xbuf, pout, scale, shift, (float*)d_out);
}

// Round 7
// 408.373 us; speedup vs baseline: 1.7885x; 1.0143x over previous
//
#include <hip/hip_runtime.h>
#include <math.h>

// ---- problem constants ----
static const int kN     = 16384;
static const int kEdges = 262144;
static const int kD     = 256;
static const int kH     = 512;
static const int kE     = 64;
static const int kCap   = 1024;
static const int kPairs = kN * 2;

// ---- workspace layout (bytes) ----
static const size_t OFF_DEGO    = 0;                        // int[16384]
static const size_t OFF_DEGI    = OFF_DEGO + 65536;
static const size_t OFF_CURSOR  = OFF_DEGI + 65536;
static const size_t OFF_ECOUNT  = OFF_CURSOR + 65536;       // int[64]
static const size_t OFF_ECUR    = OFF_ECOUNT + 256;
static const size_t OFF_ZROW    = OFF_ECUR + 256;           // 2KB zeroed dummy row (bf16 zeros)
static const size_t ZERO_BYTES  = OFF_ZROW + 2048;          // 199168+ -> zeroed each launch
static const size_t OFF_EOFFS   = ZERO_BYTES;               // int[65]
static const size_t OFF_CSROFF  = OFF_EOFFS + 512;          // int[16385]
static const size_t OFF_CSRSRC  = OFF_CSROFF + 65792;       // int[262144]
static const size_t OFF_PLIST   = OFF_CSRSRC + 1048576;     // int[32768]
static const size_t OFF_EIDX    = OFF_PLIST + 131072;       // int[32768]
static const size_t OFF_EGATE   = OFF_EIDX + 131072;        // f32[32768]
static const size_t OFF_SCALE   = OFF_EGATE + 131072;       // f32[256]
static const size_t OFF_SHIFT   = OFF_SCALE + 1024;         // f32[256]
static const size_t OFF_OSC     = OFF_SHIFT + 1024;         // f32[16384]
static const size_t OFF_ISC     = OFF_OSC + 65536;          // f32[16384]
static const size_t OFF_WQ1     = OFF_ISC + 65536;          // f32[256*64]
static const size_t OFF_WQ2     = OFF_WQ1 + 65536;          // f32[256*64]
static const size_t OFF_BGE     = OFF_WQ2 + 65536;          // f32[64]
static const size_t OFF_WCAT    = OFF_BGE + 256;            // bf16[256][512]
static const size_t OFF_M       = OFF_WCAT + 262144;        // f32[16384*256]
static const size_t OFF_X       = OFF_M + 16777216;         // f32[16384*256]
static const size_t OFF_XB      = OFF_X + 16777216;         // bf16[16384*256]
static const size_t OFF_LOGITS  = OFF_XB + 8388608;         // f32[16384*64]
static const size_t OFF_POUT    = OFF_LOGITS + 4194304;     // bf16[32768*256]; ACAT aliases
static const size_t OFF_W1T     = OFF_POUT + 16777216;      // bf16[64*512*256] [e][n][k]
static const size_t OFF_W2T     = OFF_W1T + 16777216;       // bf16[64*256*512] [e][n][k]
static const size_t OFF_H1B     = OFF_W2T + 16777216;       // bf16[32768*512]
static const size_t OFF_PART1   = OFF_H1B + 33554432;       // f32[256*256]
static const size_t OFF_PART2   = OFF_PART1 + 262144;       // f32[256*256]

typedef __bf16 bfrag __attribute__((ext_vector_type(8)));
typedef float f32x4 __attribute__((ext_vector_type(4)));

// async global->LDS 16B: LDS dest = wave-uniform base + lane*16
__device__ __forceinline__ void gll16(const void* g, void* l) {
    __builtin_amdgcn_global_load_lds(
        (const __attribute__((address_space(1))) unsigned int*)g,
        (__attribute__((address_space(3))) unsigned int*)l, 16, 0, 0);
}

// tanh-form gelu: max |err| vs exact-erf gelu ~3e-4 (<< bf16 rounding of h1)
__device__ __forceinline__ float gelu_f(float v) {
    float u = v * (0.7978845608f + 0.0356774081f * v * v);
    float t = __expf(-2.0f * fabsf(u));
    float th = (1.0f - t) * __builtin_amdgcn_rcpf(1.0f + t);
    th = copysignf(th, u);
    return 0.5f * v * (1.0f + th);
}
__device__ __forceinline__ unsigned short f2bf(float f) {
    union { float f; unsigned int u; } v; v.f = f;
    unsigned int u = v.u;
    unsigned int r = (u + 0x7FFFu + ((u >> 16) & 1u)) >> 16;   // RNE
    return (unsigned short)r;
}
__device__ __forceinline__ float bf2f(unsigned short s) {
    union { unsigned int u; float f; } v; v.u = ((unsigned int)s) << 16;
    return v.f;
}

// ---------- graph preprocessing ----------
__global__ __launch_bounds__(256) void k_count_deg(const int* __restrict__ src,
                                                   const int* __restrict__ dst,
                                                   int* __restrict__ dego,
                                                   int* __restrict__ degi) {
    int i = blockIdx.x * 256 + threadIdx.x;
    if (i < kEdges) {
        atomicAdd(&dego[src[i]], 1);
        atomicAdd(&degi[dst[i]], 1);
    }
}

__global__ __launch_bounds__(256) void k_scales(const int* __restrict__ dego,
                                                const int* __restrict__ degi,
                                                float* __restrict__ osc,
                                                float* __restrict__ isc) {
    int i = blockIdx.x * 256 + threadIdx.x;
    int a = dego[i]; if (a < 1) a = 1;
    int b = degi[i]; if (b < 1) b = 1;
    osc[i] = rsqrtf((float)a);
    isc[i] = rsqrtf((float)b);
}

__global__ __launch_bounds__(1024) void k_scan_nodes(const int* __restrict__ degi,
                                                     int* __restrict__ offs) {
    __shared__ int sums[1024];
    int t = threadIdx.x;
    int base = t * 16;
    int loc[16];
    int s = 0;
#pragma unroll
    for (int i = 0; i < 16; ++i) { loc[i] = degi[base + i]; s += loc[i]; }
    sums[t] = s;
    __syncthreads();
    for (int off = 1; off < 1024; off <<= 1) {
        int v = (t >= off) ? sums[t - off] : 0;
        __syncthreads();
        sums[t] += v;
        __syncthreads();
    }
    int run = sums[t] - s;
#pragma unroll
    for (int i = 0; i < 16; ++i) { offs[base + i] = run; run += loc[i]; }
    if (t == 1023) offs[kN] = run;
}

__global__ __launch_bounds__(256) void k_build_csr(const int* __restrict__ src,
                                                   const int* __restrict__ dst,
                                                   const int* __restrict__ offs,
                                                   int* __restrict__ cursor,
                                                   int* __restrict__ csr_src) {
    int i = blockIdx.x * 256 + threadIdx.x;
    if (i < kEdges) {
        int d = dst[i];
        int pos = atomicAdd(&cursor[d], 1);
        csr_src[offs[d] + pos] = src[i];
    }
}

// one node per block; 8 waves = 8 edges in flight; writes f32 m AND bf16 acat m-half
__global__ __launch_bounds__(512) void k_aggregate(const float* __restrict__ feats,
                                                   const float* __restrict__ osc,
                                                   const float* __restrict__ isc,
                                                   const int* __restrict__ offs,
                                                   const int* __restrict__ csr_src,
                                                   float* __restrict__ m,
                                                   unsigned short* __restrict__ acat) {
    __shared__ f32x4 red[512];
    int n = blockIdx.x;
    int t = threadIdx.x;
    int c4 = (t & 63) * 4;
    int es = t >> 6;
    int beg = offs[n], end = offs[n + 1];
    f32x4 acc = {0.f, 0.f, 0.f, 0.f};
    for (int i = beg + es; i < end; i += 8) {
        int s = csr_src[i];
        float sc = osc[s];
        const float4 v = *(const float4*)(feats + (size_t)s * kD + c4);
        acc[0] += v.x * sc; acc[1] += v.y * sc;
        acc[2] += v.z * sc; acc[3] += v.w * sc;
    }
    red[t] = acc;
    __syncthreads();
    if (t < 64) {
        f32x4 a = red[t];
#pragma unroll
        for (int j = 1; j < 8; ++j) {
            f32x4 b = red[t + 64 * j];
            a[0] += b[0]; a[1] += b[1]; a[2] += b[2]; a[3] += b[3];
        }
        float si = isc[n];
        float4 o;
        o.x = a[0] * si; o.y = a[1] * si; o.z = a[2] * si; o.w = a[3] * si;
        *(float4*)(m + (size_t)n * kD + c4) = o;
        ushort4 ob;
        ob.x = f2bf(o.x); ob.y = f2bf(o.y); ob.z = f2bf(o.z); ob.w = f2bf(o.w);
        *(ushort4*)(acat + (size_t)n * 512 + c4) = ob;
    }
}

// feats half of acat (bf16)
__global__ __launch_bounds__(256) void k_cast_feats(const float* __restrict__ feats,
                                                    unsigned short* __restrict__ acat) {
    int i = blockIdx.x * 256 + threadIdx.x;
    size_t g = (size_t)i * 8;
    int tok = (int)(g >> 8), d = (int)(g & 255);
    float4 a = *(const float4*)(feats + g);
    float4 b = *(const float4*)(feats + g + 4);
    ushort4 o0, o1;
    o0.x = f2bf(a.x); o0.y = f2bf(a.y); o0.z = f2bf(a.z); o0.w = f2bf(a.w);
    o1.x = f2bf(b.x); o1.y = f2bf(b.y); o1.z = f2bf(b.z); o1.w = f2bf(b.w);
    unsigned short* dstp = acat + (size_t)tok * 512 + 256 + d;
    *(ushort4*)dstp = o0;
    *(ushort4*)(dstp + 4) = o1;
}

// ---------- composed gate weights ----------
__global__ __launch_bounds__(256) void k_compose(const float* __restrict__ Wgc,
                                                 const float* __restrict__ Wres,
                                                 const float* __restrict__ Wg,
                                                 const float* __restrict__ bgc,
                                                 const float* __restrict__ bres,
                                                 const float* __restrict__ bg,
                                                 float* __restrict__ Wq1,
                                                 float* __restrict__ Wq2,
                                                 float* __restrict__ bge) {
    int tid = blockIdx.x * 256 + threadIdx.x;
    if (tid < 2 * kD * kE) {
        int mat = tid >> 14;
        int rem = tid & 16383;
        int d = rem >> 6, e = rem & 63;
        const float* A = mat ? Wres : Wgc;
        float acc = 0.f;
        for (int c = 0; c < kD; ++c)
            acc = fmaf(A[d * kD + c], Wg[c * kE + e], acc);
        (mat ? Wq2 : Wq1)[d * kE + e] = acc;
    } else if (tid < 2 * kD * kE + kE) {
        int e = tid - 2 * kD * kE;
        float acc = bg[e];
        for (int d = 0; d < kD; ++d)
            acc = fmaf(bgc[d] + bres[d], Wg[d * kE + e], acc);
        bge[e] = acc;
    }
}

// logits = m@Wq1 + feats@Wq2 + bge  (f32 — routing-accuracy-critical)
#define FMA16()                                                                         \
    acc[0][0]=fmaf(a.x,b.x,acc[0][0]); acc[0][1]=fmaf(a.x,b.y,acc[0][1]);               \
    acc[0][2]=fmaf(a.x,b.z,acc[0][2]); acc[0][3]=fmaf(a.x,b.w,acc[0][3]);               \
    acc[1][0]=fmaf(a.y,b.x,acc[1][0]); acc[1][1]=fmaf(a.y,b.y,acc[1][1]);               \
    acc[1][2]=fmaf(a.y,b.z,acc[1][2]); acc[1][3]=fmaf(a.y,b.w,acc[1][3]);               \
    acc[2][0]=fmaf(a.z,b.x,acc[2][0]); acc[2][1]=fmaf(a.z,b.y,acc[2][1]);               \
    acc[2][2]=fmaf(a.z,b.z,acc[2][2]); acc[2][3]=fmaf(a.z,b.w,acc[2][3]);               \
    acc[3][0]=fmaf(a.w,b.x,acc[3][0]); acc[3][1]=fmaf(a.w,b.y,acc[3][1]);               \
    acc[3][2]=fmaf(a.w,b.z,acc[3][2]); acc[3][3]=fmaf(a.w,b.w,acc[3][3]);

__global__ __launch_bounds__(256) void k_gate_comp(const float* __restrict__ m,
                                                   const float* __restrict__ feats,
                                                   const float* __restrict__ Wq1,
                                                   const float* __restrict__ Wq2,
                                                   const float* __restrict__ bge,
                                                   float* __restrict__ logits) {
    __shared__ float As[32][68];
    __shared__ float Bs[32][68];
    const int t = threadIdx.x;
    const int tx = t & 15, ty = t >> 4;
    const int m0 = blockIdx.y * 64;
    float acc[4][4] = {};
    for (int pass = 0; pass < 2; ++pass) {
        const float* A = pass ? feats : m;
        const float* B = pass ? Wq2 : Wq1;
        for (int kb = 0; kb < kD; kb += 32) {
            __syncthreads();
#pragma unroll
            for (int i = 0; i < 2; ++i) {
                int fidx = i * 256 + t;
                int r = fidx >> 3, k4 = fidx & 7;
                float4 v = *(const float4*)(A + (size_t)(m0 + r) * kD + kb + k4 * 4);
                As[k4 * 4 + 0][r] = v.x; As[k4 * 4 + 1][r] = v.y;
                As[k4 * 4 + 2][r] = v.z; As[k4 * 4 + 3][r] = v.w;
            }
#pragma unroll
            for (int i = 0; i < 2; ++i) {
                int fidx = i * 256 + t;
                int kk = fidx >> 4, c4 = fidx & 15;
                float4 v = *(const float4*)(B + (size_t)(kb + kk) * kE + c4 * 4);
                *(float4*)&Bs[kk][c4 * 4] = v;
            }
            __syncthreads();
#pragma unroll
            for (int kk = 0; kk < 32; ++kk) {
                float4 a = *(const float4*)&As[kk][ty * 4];
                float4 b = *(const float4*)&Bs[kk][tx * 4];
                FMA16();
            }
        }
    }
    int col0 = tx * 4;
    float4 bb = *(const float4*)(bge + col0);
#pragma unroll
    for (int i = 0; i < 4; ++i) {
        int row = m0 + ty * 4 + i;
        float4 o;
        o.x = acc[i][0] + bb.x; o.y = acc[i][1] + bb.y;
        o.z = acc[i][2] + bb.z; o.w = acc[i][3] + bb.w;
        *(float4*)(logits + (size_t)row * kE + col0) = o;
    }
}

// transpose+cast: w [e][R][C] f32 -> wt[(c)*dstride + doff + r] bf16
__global__ __launch_bounds__(256) void k_transpose_cast(const float* __restrict__ w,
                                                        unsigned short* __restrict__ wt,
                                                        int R, int C, int dstride, int doff) {
    __shared__ unsigned short tile[64][65];
    int e = blockIdx.z;
    const float* W = w + (size_t)e * R * C;
    unsigned short* WT = wt + (size_t)e * R * C;
    int r0 = blockIdx.y * 64, c0 = blockIdx.x * 64;
    int t = threadIdx.x;
#pragma unroll
    for (int i = 0; i < 4; ++i) {
        int idx = i * 256 + t;
        int r = idx >> 4, c4 = idx & 15;
        float4 v = *(const float4*)(W + (size_t)(r0 + r) * C + c0 + c4 * 4);
        tile[r][c4 * 4 + 0] = f2bf(v.x); tile[r][c4 * 4 + 1] = f2bf(v.y);
        tile[r][c4 * 4 + 2] = f2bf(v.z); tile[r][c4 * 4 + 3] = f2bf(v.w);
    }
    __syncthreads();
#pragma unroll
    for (int i = 0; i < 4; ++i) {
        int idx = i * 256 + t;
        int c = idx >> 4, r4 = idx & 15;
        ushort4 o;
        o.x = tile[r4 * 4 + 0][c]; o.y = tile[r4 * 4 + 1][c];
        o.z = tile[r4 * 4 + 2][c]; o.w = tile[r4 * 4 + 3][c];
        *(ushort4*)(WT + (size_t)(c0 + c) * dstride + doff + r0 + r4 * 4) = o;
    }
}

// ---------- x = [m|feats] @ [Wgc;Wres]^T + bias (bf16 MFMA, K=512, BK=64, async staging) ----------
__global__ __launch_bounds__(256) void k_xgemm_mfma(const unsigned short* __restrict__ acat,
                                                    const unsigned short* __restrict__ wcat,
                                                    const float* __restrict__ bgc,
                                                    const float* __restrict__ bres,
                                                    float* __restrict__ x,
                                                    unsigned short* __restrict__ xb) {
    __shared__ unsigned short As[128 * 64];
    __shared__ unsigned short Bs[128 * 64];
    const int t = threadIdx.x;
    const int m0 = blockIdx.y * 128, n0 = blockIdx.x * 128;
    const int lane = t & 63, w = t >> 6;
    const int m_off = (w & 1) * 64, n_off = (w >> 1) * 64;
    const int quad = lane >> 4, lr = lane & 15;
    float breg[4];
#pragma unroll
    for (int ni = 0; ni < 4; ++ni) {
        int col = n0 + n_off + ni * 16 + lr;
        breg[ni] = bgc[col] + bres[col];
    }
    const int lsub = lane >> 3, lslot = lane & 7;
    const int swz8 = (lslot ^ lsub) * 8;                       // source kseg swizzle
    const unsigned short* pAb = acat + (size_t)(m0 + w * 8 + lsub) * 512 + swz8;
    const unsigned short* pBb = wcat + (size_t)(n0 + w * 8 + lsub) * 512 + swz8;
    unsigned short* sA = As + w * 8 * 64;
    unsigned short* sB = Bs + w * 8 * 64;
    f32x4 acc[4][4] = {};
    for (int kb = 0; kb < 512; kb += 64) {
        __syncthreads();
#pragma unroll
        for (int j = 0; j < 4; ++j) {
            gll16(pAb + (size_t)j * 32 * 512 + kb, sA + j * 2048);
            gll16(pBb + (size_t)j * 32 * 512 + kb, sB + j * 2048);
        }
        __syncthreads();
#pragma unroll
        for (int h = 0; h < 2; ++h) {
            const int soff = ((h * 4 + quad) ^ (lr & 7)) * 8;
            bfrag af[4], bf[4];
#pragma unroll
            for (int mi = 0; mi < 4; ++mi)
                af[mi] = *(const bfrag*)&As[(m_off + mi * 16 + lr) * 64 + soff];
#pragma unroll
            for (int ni = 0; ni < 4; ++ni)
                bf[ni] = *(const bfrag*)&Bs[(n_off + ni * 16 + lr) * 64 + soff];
#pragma unroll
            for (int mi = 0; mi < 4; ++mi)
#pragma unroll
                for (int ni = 0; ni < 4; ++ni)
                    acc[mi][ni] = __builtin_amdgcn_mfma_f32_16x16x32_bf16(af[mi], bf[ni], acc[mi][ni], 0, 0, 0);
        }
    }
#pragma unroll
    for (int mi = 0; mi < 4; ++mi) {
#pragma unroll
        for (int r = 0; r < 4; ++r) {
            int row = m0 + m_off + mi * 16 + quad * 4 + r;
            float* xrow = x + (size_t)row * kD + n0 + n_off + lr;
            unsigned short* xbrow = xb + (size_t)row * kD + n0 + n_off + lr;
#pragma unroll
            for (int ni = 0; ni < 4; ++ni) {
                float v = acc[mi][ni][r] + breg[ni];
                xrow[ni * 16] = v;
                xbrow[ni * 16] = f2bf(v);
            }
        }
    }
}

// ---------- gating ----------
__global__ __launch_bounds__(256) void k_topk(const float* __restrict__ logits,
                                              int* __restrict__ eidx,
                                              float* __restrict__ egate,
                                              int* __restrict__ ecount) {
    __shared__ int hist[kE];
    int t = threadIdx.x;
    int n = blockIdx.x * 256 + t;
    if (t < kE) hist[t] = 0;
    __syncthreads();
    const float* row = logits + (size_t)n * kE;
    float v0 = -3.4e38f, v1 = -3.4e38f;
    int i0 = 0, i1 = 0;
    for (int e4 = 0; e4 < kE; e4 += 4) {
        float4 vv = *(const float4*)(row + e4);
        float vs[4] = {vv.x, vv.y, vv.z, vv.w};
#pragma unroll
        for (int j = 0; j < 4; ++j) {
            float v = vs[j];
            int e = e4 + j;
            if (v > v0) { v1 = v0; i1 = i0; v0 = v; i0 = e; }
            else if (v > v1) { v1 = v; i1 = e; }
        }
    }
    float ex = expf(v1 - v0);
    float g0 = 1.0f / (1.0f + ex);
    float g1 = ex * g0;
    eidx[2 * n] = i0; eidx[2 * n + 1] = i1;
    egate[2 * n] = g0; egate[2 * n + 1] = g1;
    atomicAdd(&hist[i0], 1);
    atomicAdd(&hist[i1], 1);
    __syncthreads();
    if (t < kE) {
        int c = hist[t];
        if (c > 0) atomicAdd(&ecount[t], c);
    }
}

__global__ void k_scan_experts(const int* __restrict__ ecount, int* __restrict__ eoffs) {
    if (threadIdx.x == 0) {
        int s = 0;
        for (int e = 0; e < kE; ++e) { eoffs[e] = s; s += ecount[e]; }
        eoffs[kE] = s;
    }
}

__global__ __launch_bounds__(256) void k_scatter(const int* __restrict__ eidx,
                                                 const int* __restrict__ eoffs,
                                                 int* __restrict__ ecur,
                                                 int* __restrict__ plist) {
    __shared__ int lh[kE];
    __shared__ int gbase[kE];
    int t = threadIdx.x;
    int p0 = blockIdx.x * 512 + t;
    if (t < kE) lh[t] = 0;
    __syncthreads();
    int e0 = eidx[p0], e1 = eidx[p0 + 256];
    atomicAdd(&lh[e0], 1);
    atomicAdd(&lh[e1], 1);
    __syncthreads();
    if (t < kE) {
        int c = lh[t];
        int b = (c > 0) ? atomicAdd(&ecur[t], c) : 0;
        gbase[t] = eoffs[t] + b;
        lh[t] = 0;
    }
    __syncthreads();
    int r0 = atomicAdd(&lh[e0], 1);
    int r1 = atomicAdd(&lh[e1], 1);
    plist[gbase[e0] + r0] = p0;
    plist[gbase[e1] + r1] = p0 + 256;
}

// ---------- MoE MFMA GEMMs (BK=64, async staging, swizzled) ----------
__global__ __launch_bounds__(256) void k_moe1_mfma(const unsigned short* __restrict__ xb,
                                                   const unsigned short* __restrict__ w1t,
                                                   const float* __restrict__ b1,
                                                   const int* __restrict__ plist,
                                                   const int* __restrict__ eoffs,
                                                   const int* __restrict__ ecount,
                                                   const unsigned short* __restrict__ zrow,
                                                   unsigned short* __restrict__ h1b) {
    __shared__ unsigned short As[128 * 64];
    __shared__ unsigned short Bs[128 * 64];
    __shared__ int rowtok[128];
    const int e = blockIdx.z;
    int cnt = ecount[e]; if (cnt > kCap) cnt = kCap;
    const int m0 = blockIdx.y * 128;
    if (m0 >= cnt) return;
    const int n0 = blockIdx.x * 128;
    const int base = eoffs[e];
    const int t = threadIdx.x;
    if (t < 128) {
        int slot = m0 + t;
        rowtok[t] = (slot < cnt) ? (plist[base + slot] >> 1) : -1;
    }
    const int lane = t & 63, w = t >> 6;
    const int m_off = (w & 1) * 64, n_off = (w >> 1) * 64;
    const int quad = lane >> 4, lr = lane & 15;
    const unsigned short* Bbase = w1t + (size_t)e * kH * kD;
    float breg[4];
#pragma unroll
    for (int ni = 0; ni < 4; ++ni) breg[ni] = b1[e * kH + n0 + n_off + ni * 16 + lr];
    const int lsub = lane >> 3, lslot = lane & 7;
    const int swz8 = (lslot ^ lsub) * 8;
    __syncthreads();   // rowtok ready
    const unsigned short* pA[4];
#pragma unroll
    for (int j = 0; j < 4; ++j) {
        int r = w * 8 + j * 32 + lsub;
        int tok = rowtok[r];
        pA[j] = (tok >= 0) ? (xb + (size_t)tok * kD + swz8) : (zrow + swz8);
    }
    const unsigned short* pBb = Bbase + (size_t)(n0 + w * 8 + lsub) * kD + swz8;
    unsigned short* sA = As + w * 8 * 64;
    unsigned short* sB = Bs + w * 8 * 64;
    f32x4 acc[4][4] = {};
    for (int kb = 0; kb < kD; kb += 64) {
        __syncthreads();
#pragma unroll
        for (int j = 0; j < 4; ++j) {
            gll16(pA[j] + kb, sA + j * 2048);
            gll16(pBb + (size_t)j * 32 * kD + kb, sB + j * 2048);
        }
        __syncthreads();
#pragma unroll
        for (int h = 0; h < 2; ++h) {
            const int soff = ((h * 4 + quad) ^ (lr & 7)) * 8;
            bfrag af[4], bf[4];
#pragma unroll
            for (int mi = 0; mi < 4; ++mi)
                af[mi] = *(const bfrag*)&As[(m_off + mi * 16 + lr) * 64 + soff];
#pragma unroll
            for (int ni = 0; ni < 4; ++ni)
                bf[ni] = *(const bfrag*)&Bs[(n_off + ni * 16 + lr) * 64 + soff];
#pragma unroll
            for (int mi = 0; mi < 4; ++mi)
#pragma unroll
                for (int ni = 0; ni < 4; ++ni)
                    acc[mi][ni] = __builtin_amdgcn_mfma_f32_16x16x32_bf16(af[mi], bf[ni], acc[mi][ni], 0, 0, 0);
        }
    }
#pragma unroll
    for (int mi = 0; mi < 4; ++mi) {
#pragma unroll
        for (int r = 0; r < 4; ++r) {
            int slot = m0 + m_off + mi * 16 + quad * 4 + r;
            if (slot < cnt) {
                unsigned short* orow = h1b + (size_t)(base + slot) * kH + n0 + n_off + lr;
#pragma unroll
                for (int ni = 0; ni < 4; ++ni)
                    orow[ni * 16] = f2bf(gelu_f(acc[mi][ni][r] + breg[ni]));
            }
        }
    }
}

__global__ __launch_bounds__(256) void k_moe2_mfma(const unsigned short* __restrict__ h1b,
                                                   const unsigned short* __restrict__ w2t,
                                                   const float* __restrict__ b2,
                                                   const int* __restrict__ plist,
                                                   const int* __restrict__ eoffs,
                                                   const int* __restrict__ ecount,
                                                   const float* __restrict__ egate,
                                                   const unsigned short* __restrict__ zrow,
                                                   unsigned short* __restrict__ pout) {
    __shared__ unsigned short As[128 * 64];
    __shared__ unsigned short Bs[128 * 64];
    __shared__ int prow[128];
    __shared__ float sgate[128];
    const int e = blockIdx.z;
    int cnt = ecount[e]; if (cnt > kCap) cnt = kCap;
    const int m0 = blockIdx.y * 128;
    if (m0 >= cnt) return;
    const int n0 = blockIdx.x * 128;
    const int base = eoffs[e];
    const int t = threadIdx.x;
    if (t < 128) {
        int slot = m0 + t;
        int p = (slot < cnt) ? plist[base + slot] : -1;
        prow[t] = p;
        sgate[t] = (p >= 0) ? egate[p] : 0.f;
    }
    const int lane = t & 63, w = t >> 6;
    const int m_off = (w & 1) * 64, n_off = (w >> 1) * 64;
    const int quad = lane >> 4, lr = lane & 15;
    const unsigned short* Bbase = w2t + (size_t)e * kD * kH;
    float breg[4];
#pragma unroll
    for (int ni = 0; ni < 4; ++ni) breg[ni] = b2[e * kD + n0 + n_off + ni * 16 + lr];
    const int lsub = lane >> 3, lslot = lane & 7;
    const int swz8 = (lslot ^ lsub) * 8;
    const unsigned short* pA[4];
#pragma unroll
    for (int j = 0; j < 4; ++j) {
        int r = w * 8 + j * 32 + lsub;
        int slot = m0 + r;
        pA[j] = (slot < cnt) ? (h1b + (size_t)(base + slot) * kH + swz8) : (zrow + swz8);
    }
    const unsigned short* pBb = Bbase + (size_t)(n0 + w * 8 + lsub) * kH + swz8;
    unsigned short* sA = As + w * 8 * 64;
    unsigned short* sB = Bs + w * 8 * 64;
    f32x4 acc[4][4] = {};
    for (int kb = 0; kb < kH; kb += 64) {
        __syncthreads();
#pragma unroll
        for (int j = 0; j < 4; ++j) {
            gll16(pA[j] + kb, sA + j * 2048);
            gll16(pBb + (size_t)j * 32 * kH + kb, sB + j * 2048);
        }
        __syncthreads();
#pragma unroll
        for (int h = 0; h < 2; ++h) {
            const int soff = ((h * 4 + quad) ^ (lr & 7)) * 8;
            bfrag af[4], bf[4];
#pragma unroll
            for (int mi = 0; mi < 4; ++mi)
                af[mi] = *(const bfrag*)&As[(m_off + mi * 16 + lr) * 64 + soff];
#pragma unroll
            for (int ni = 0; ni < 4; ++ni)
                bf[ni] = *(const bfrag*)&Bs[(n_off + ni * 16 + lr) * 64 + soff];
#pragma unroll
            for (int mi = 0; mi < 4; ++mi)
#pragma unroll
                for (int ni = 0; ni < 4; ++ni)
                    acc[mi][ni] = __builtin_amdgcn_mfma_f32_16x16x32_bf16(af[mi], bf[ni], acc[mi][ni], 0, 0, 0);
        }
    }
#pragma unroll
    for (int mi = 0; mi < 4; ++mi) {
#pragma unroll
        for (int r = 0; r < 4; ++r) {
            int lslot2 = m_off + mi * 16 + quad * 4 + r;
            int p = prow[lslot2];
            if (p >= 0) {
                float g = sgate[lslot2];
                unsigned short* orow = pout + (size_t)p * kD + n0 + n_off + lr;
#pragma unroll
                for (int ni = 0; ni < 4; ++ni)
                    orow[ni * 16] = f2bf(g * (acc[mi][ni][r] + breg[ni]));
            }
        }
    }
}

// ---------- BN ----------
__global__ __launch_bounds__(256) void k_colsum(const float* __restrict__ x,
                                                const unsigned short* __restrict__ pout,
                                                float* __restrict__ part1,
                                                float* __restrict__ part2) {
    int d = threadIdx.x;
    int r0 = blockIdx.x * 64;
    float s = 0.f, s2 = 0.f;
    for (int i = 0; i < 64; ++i) {
        int row = r0 + i;
        float v = x[(size_t)row * kD + d]
                + bf2f(pout[(size_t)(2 * row) * kD + d])
                + bf2f(pout[(size_t)(2 * row + 1) * kD + d]);
        s += v; s2 += v * v;
    }
    part1[blockIdx.x * kD + d] = s;
    part2[blockIdx.x * kD + d] = s2;
}

__global__ void k_bnparams(const float* __restrict__ part1,
                           const float* __restrict__ part2,
                           const float* __restrict__ gamma,
                           const float* __restrict__ beta,
                           float* __restrict__ scale,
                           float* __restrict__ shift) {
    int d = threadIdx.x;
    float s = 0.f, s2 = 0.f;
    for (int b = 0; b < 256; ++b) {
        s += part1[b * kD + d];
        s2 += part2[b * kD + d];
    }
    float mean = s * (1.0f / kN);
    float var = s2 * (1.0f / kN) - mean * mean;
    float inv = rsqrtf(var + 1e-5f);
    float sc = inv * gamma[d];
    scale[d] = sc;
    shift[d] = beta[d] - mean * sc;
}

__global__ __launch_bounds__(256) void k_apply2(const float* __restrict__ x,
                                                const unsigned short* __restrict__ pout,
                                                const float* __restrict__ scale,
                                                const float* __restrict__ shift,
                                                float* __restrict__ out) {
    int i = blockIdx.x * 256 + threadIdx.x;
    size_t g = (size_t)i * 4;
    int row = (int)(g >> 8);
    int d = (int)(g & 255);
    float4 v = *(const float4*)(x + g);
    ushort4 p0 = *(const ushort4*)(pout + (size_t)(2 * row) * kD + d);
    ushort4 p1 = *(const ushort4*)(pout + (size_t)(2 * row + 1) * kD + d);
    v.x += bf2f(p0.x) + bf2f(p1.x);
    v.y += bf2f(p0.y) + bf2f(p1.y);
    v.z += bf2f(p0.z) + bf2f(p1.z);
    v.w += bf2f(p0.w) + bf2f(p1.w);
    float4 sc = *(const float4*)(scale + d);
    float4 sh = *(const float4*)(shift + d);
    v.x = v.x * sc.x + sh.x;
    v.y = v.y * sc.y + sh.y;
    v.z = v.z * sc.z + sh.z;
    v.w = v.w * sc.w + sh.w;
    *(float4*)(out + g) = v;
}

extern "C" void kernel_launch(void* const* d_in, const int* in_sizes, int n_in,
                              void* d_out, int out_size, void* d_ws, size_t ws_size,
                              hipStream_t stream) {
    const float* feats = (const float*)d_in[0];
    const float* Wgc   = (const float*)d_in[1];
    const float* bgc   = (const float*)d_in[2];
    const float* Wres  = (const float*)d_in[3];
    const float* bres  = (const float*)d_in[4];
    const float* Wg    = (const float*)d_in[5];
    const float* bg    = (const float*)d_in[6];
    const float* w1    = (const float*)d_in[7];
    const float* b1    = (const float*)d_in[8];
    const float* w2    = (const float*)d_in[9];
    const float* b2    = (const float*)d_in[10];
    const float* gamma = (const float*)d_in[11];
    const float* beta  = (const float*)d_in[12];
    const int*   src   = (const int*)d_in[13];
    const int*   dst   = (const int*)d_in[14];

    char* ws = (char*)d_ws;
    int*   dego    = (int*)(ws + OFF_DEGO);
    int*   degi    = (int*)(ws + OFF_DEGI);
    int*   cursor  = (int*)(ws + OFF_CURSOR);
    int*   ecount  = (int*)(ws + OFF_ECOUNT);
    int*   ecur    = (int*)(ws + OFF_ECUR);
    const unsigned short* zrow = (const unsigned short*)(ws + OFF_ZROW);
    int*   eoffs   = (int*)(ws + OFF_EOFFS);
    int*   csroff  = (int*)(ws + OFF_CSROFF);
    int*   csrsrc  = (int*)(ws + OFF_CSRSRC);
    int*   plist   = (int*)(ws + OFF_PLIST);
    int*   eidx    = (int*)(ws + OFF_EIDX);
    float* egate   = (float*)(ws + OFF_EGATE);
    float* scale   = (float*)(ws + OFF_SCALE);
    float* shift   = (float*)(ws + OFF_SHIFT);
    float* osc     = (float*)(ws + OFF_OSC);
    float* iscv    = (float*)(ws + OFF_ISC);
    float* Wq1     = (float*)(ws + OFF_WQ1);
    float* Wq2     = (float*)(ws + OFF_WQ2);
    float* bge     = (float*)(ws + OFF_BGE);
    unsigned short* wcat = (unsigned short*)(ws + OFF_WCAT);
    float* mbuf    = (float*)(ws + OFF_M);
    float* xbuf    = (float*)(ws + OFF_X);
    unsigned short* xb   = (unsigned short*)(ws + OFF_XB);
    float* logits  = (float*)(ws + OFF_LOGITS);
    unsigned short* pout = (unsigned short*)(ws + OFF_POUT);
    unsigned short* acat = (unsigned short*)(ws + OFF_POUT);   // alias: dead before moe2
    unsigned short* w1t  = (unsigned short*)(ws + OFF_W1T);
    unsigned short* w2t  = (unsigned short*)(ws + OFF_W2T);
    unsigned short* h1b  = (unsigned short*)(ws + OFF_H1B);
    float* part1   = (float*)(ws + OFF_PART1);
    float* part2   = (float*)(ws + OFF_PART2);

    hipMemsetAsync(ws, 0, ZERO_BYTES, stream);

    // weight prep
    k_transpose_cast<<<dim3(kH / 64, kD / 64, kE), 256, 0, stream>>>(w1, w1t, kD, kH, kD, 0);
    k_transpose_cast<<<dim3(kD / 64, kH / 64, kE), 256, 0, stream>>>(w2, w2t, kH, kD, kH, 0);
    k_transpose_cast<<<dim3(kD / 64, kD / 64, 1), 256, 0, stream>>>(Wgc, wcat, kD, kD, 512, 0);
    k_transpose_cast<<<dim3(kD / 64, kD / 64, 1), 256, 0, stream>>>(Wres, wcat, kD, kD, 512, 256);
    k_compose<<<129, 256, 0, stream>>>(Wgc, Wres, Wg, bgc, bres, bg, Wq1, Wq2, bge);
    // graph prep + aggregation
    k_count_deg<<<kEdges / 256, 256, 0, stream>>>(src, dst, dego, degi);
    k_scales<<<kN / 256, 256, 0, stream>>>(dego, degi, osc, iscv);
    k_scan_nodes<<<1, 1024, 0, stream>>>(degi, csroff);
    k_build_csr<<<kEdges / 256, 256, 0, stream>>>(src, dst, csroff, cursor, csrsrc);
    k_cast_feats<<<kN * kD / 8 / 256, 256, 0, stream>>>(feats, acat);
    k_aggregate<<<kN, 512, 0, stream>>>(feats, osc, iscv, csroff, csrsrc, mbuf, acat);
    // routing logits (f32, composed weights)
    k_gate_comp<<<dim3(1, kN / 64), 256, 0, stream>>>(mbuf, feats, Wq1, Wq2, bge, logits);
    // x via bf16 MFMA
    k_xgemm_mfma<<<dim3(kD / 128, kN / 128), 256, 0, stream>>>(acat, wcat, bgc, bres, xbuf, xb);
    // gating + MoE
    k_topk<<<kN / 256, 256, 0, stream>>>(logits, eidx, egate, ecount);
    k_scan_experts<<<1, 64, 0, stream>>>(ecount, eoffs);
    k_scatter<<<kPairs / 512, 256, 0, stream>>>(eidx, eoffs, ecur, plist);
    k_moe1_mfma<<<dim3(kH / 128, kCap / 128, kE), 256, 0, stream>>>(xb, w1t, b1, plist, eoffs, ecount, zrow, h1b);
    k_moe2_mfma<<<dim3(kD / 128, kCap / 128, kE), 256, 0, stream>>>(h1b, w2t, b2, plist, eoffs, ecount, egate, zrow, pout);
    // BN
    k_colsum<<<kN / 64, 256, 0, stream>>>(xbuf, pout, part1, part2);
    k_bnparams<<<1, 256, 0, stream>>>(part1, part2, gamma, beta, scale, shift);
    k_apply2<<<(kN * kD / 4) / 256, 256, 0, stream>>>(xbuf, pout, scale, shift, (float*)d_out);
}